// Round 1
// baseline (2308.695 us; speedup 1.0000x reference)
//
#include <hip/hip_runtime.h>
#include <cstdint>
#include <cstddef>

// Problem constants (BiMambaRefinerBlock)
#define BB 2
#define TT 4
#define NN 196
#define LL (TT*NN)        // 784
#define BLr (BB*LL)       // 1568 rows total per direction
#define CM 768            // d_model
#define DI 1536           // d_inner
#define DS 16             // d_state
#define DTR 48            // dt_rank
#define XD 80             // dt_rank + 2*d_state

static __device__ __forceinline__ float sigmoidf_(float x) {
  return 1.f / (1.f + __expf(-x));
}

// ---------------- RMSNorm (both directions; dir1 reads flipped-t source) ----
__global__ __launch_bounds__(256) void rmsnorm_k(const float* __restrict__ x,
    const float* __restrict__ nw, float* __restrict__ xn)
{
  int blk = blockIdx.x;               // dir*BLr + b*LL + l
  int l   = blk % LL;
  int b   = (blk / LL) % BB;
  int dir = blk / (BB*LL);
  int lsrc = l;
  if (dir == 1) { int t = l / NN, n = l % NN; lsrc = (TT-1-t)*NN + n; }
  const float* xp = x + ((size_t)b*LL + lsrc)*CM;
  float s = 0.f;
  for (int c = threadIdx.x; c < CM; c += 256) { float v = xp[c]; s += v*v; }
  #pragma unroll
  for (int off = 32; off > 0; off >>= 1) s += __shfl_down(s, off);
  __shared__ float red[4];
  if ((threadIdx.x & 63) == 0) red[threadIdx.x >> 6] = s;
  __syncthreads();
  float tot = red[0] + red[1] + red[2] + red[3];
  float r = rsqrtf(tot * (1.f/CM) + 1e-5f);
  const float* w = nw + dir*CM;
  float* o = xn + (size_t)blk*CM;
  for (int c = threadIdx.x; c < CM; c += 256) o[c] = xp[c] * r * w[c];
}

// ---------------- Generic fp32 GEMM: C[m,n] = sum_k A[m,k]*W[n,k] (+bias[n])
// 64x64 tile, K-tile 16 (requires K % 16 == 0), 4x4 per thread.
__global__ __launch_bounds__(256) void gemm_bt(const float* __restrict__ A, int lda,
    const float* __restrict__ W, int ldw, float* __restrict__ C, int ldc,
    int M, int N, int K, const float* __restrict__ bias)
{
  __shared__ float As[16][64];
  __shared__ float Ws[16][64];
  const int tx = threadIdx.x, ty = threadIdx.y;
  const int tid = ty*16 + tx;
  const int n0 = blockIdx.x*64, m0 = blockIdx.y*64;
  float acc[4][4] = {};
  for (int k0 = 0; k0 < K; k0 += 16) {
    #pragma unroll
    for (int e = 0; e < 4; ++e) {
      int lin = tid + 256*e;        // 0..1023
      int kl = lin & 15, rl = lin >> 4;
      int m = m0 + rl, n = n0 + rl;
      As[kl][rl] = (m < M) ? A[(size_t)m*lda + k0 + kl] : 0.f;
      Ws[kl][rl] = (n < N) ? W[(size_t)n*ldw + k0 + kl] : 0.f;
    }
    __syncthreads();
    #pragma unroll
    for (int k = 0; k < 16; ++k) {
      float a[4], w[4];
      #pragma unroll
      for (int i = 0; i < 4; ++i) a[i] = As[k][ty + 16*i];
      #pragma unroll
      for (int j = 0; j < 4; ++j) w[j] = Ws[k][tx + 16*j];
      #pragma unroll
      for (int i = 0; i < 4; ++i)
        #pragma unroll
        for (int j = 0; j < 4; ++j) acc[i][j] = fmaf(a[i], w[j], acc[i][j]);
    }
    __syncthreads();
  }
  #pragma unroll
  for (int i = 0; i < 4; ++i) {
    int m = m0 + ty + 16*i;
    if (m >= M) continue;
    #pragma unroll
    for (int j = 0; j < 4; ++j) {
      int n = n0 + tx + 16*j;
      if (n >= N) continue;
      float v = acc[i][j];
      if (bias) v += bias[n];
      C[(size_t)m*ldc + n] = v;
    }
  }
}

// ---------------- Causal depthwise conv (k=4) + SiLU --------------------
__global__ __launch_bounds__(256) void conv_silu_k(const float* __restrict__ xz,
    const float* __restrict__ cw, const float* __restrict__ cb,
    float* __restrict__ xbc)
{
  size_t idx = (size_t)blockIdx.x*256 + threadIdx.x;
  if (idx >= (size_t)2*BLr*DI) return;
  int di  = (int)(idx % DI);
  size_t r = idx / DI;               // dir*BLr + b*LL + l
  int l   = (int)(r % LL);
  int dir = (int)(r / (BB*LL));
  size_t rowbase = r - l;
  const float* w = cw + ((size_t)dir*DI + di)*4;
  float acc = cb[dir*DI + di];
  #pragma unroll
  for (int k = 0; k < 4; ++k) {
    int lp = l - 3 + k;
    if (lp >= 0) acc = fmaf(w[k], xz[(rowbase + lp)*(2*DI) + di], acc);
  }
  xbc[idx] = acc * sigmoidf_(acc);
}

// ---------------- softplus in place -------------------------------------
__global__ void softplus_k(float* __restrict__ p, size_t n)
{
  size_t i = (size_t)blockIdx.x*256 + threadIdx.x;
  if (i >= n) return;
  float v = p[i];
  p[i] = (v > 20.f) ? v : log1pf(__expf(v));
}

// ---------------- Selective scan: thread = (d, n) state ------------------
// block = 256 threads = 16 d-channels x 16 states; loops over L sequentially.
__global__ __launch_bounds__(256) void scan_k(const float* __restrict__ xz,
    const float* __restrict__ u, const float* __restrict__ dt,
    const float* __restrict__ xdbl, const float* __restrict__ A_log,
    const float* __restrict__ Dp, float* __restrict__ y)
{
  int bx = blockIdx.x;
  int dchunk = bx % (DI/16);
  int b   = (bx / (DI/16)) % BB;
  int dir = bx / ((DI/16)*BB);
  int tid = threadIdx.x;
  int dl = tid >> 4, n = tid & 15;   // 16-aligned lane groups per d
  int d = dchunk*16 + dl;
  size_t rb = ((size_t)dir*BB + b) * LL;
  const float* dtp = dt + rb*DI + d;
  const float* up  = u  + rb*DI + d;
  const float* zp  = xz + rb*(2*DI) + DI + d;
  const float* Bp  = xdbl + rb*XD + DTR + n;
  float* yp = y + rb*DI + d;
  float Av = -__expf(A_log[((size_t)dir*DI + d)*DS + n]);
  float Dd = Dp[dir*DI + d];
  float h = 0.f;
  // software-pipelined loads
  float dtv = dtp[0], uv = up[0], Bv = Bp[0], Cv = Bp[DS], zv = zp[0];
  for (int l = 0; l < LL; ++l) {
    float dtn = 0.f, un = 0.f, Bn = 0.f, Cn = 0.f, zn = 0.f;
    if (l + 1 < LL) {
      size_t r1 = (size_t)(l+1)*DI, r8 = (size_t)(l+1)*XD;
      dtn = dtp[r1]; un = up[r1]; Bn = Bp[r8]; Cn = Bp[r8 + DS];
      zn = zp[(size_t)(l+1)*(2*DI)];
    }
    float dA = __expf(dtv * Av);
    h = fmaf(dA, h, dtv * uv * Bv);
    float acc = h * Cv;
    #pragma unroll
    for (int off = 1; off < 16; off <<= 1) acc += __shfl_xor(acc, off);
    if (n == 0) {
      float yv = (acc + uv * Dd) * (zv * sigmoidf_(zv));
      yp[(size_t)l*DI] = yv;
    }
    dtv = dtn; uv = un; Bv = Bn; Cv = Cn; zv = zn;
  }
}

// ---------------- residual add + flip for backward dir -------------------
__global__ void addperm_k(const float* __restrict__ x, const float* __restrict__ mo,
    float* __restrict__ out_f, float* __restrict__ out_b)
{
  size_t idx = (size_t)blockIdx.x*256 + threadIdx.x;
  if (idx >= (size_t)BLr*CM) return;
  int c = (int)(idx % CM);
  size_t r = idx / CM;               // b*LL + l
  int l = (int)(r % LL);
  int b = (int)(r / LL);
  int t = l / NN, nn = l % NN;
  int lp = (TT-1-t)*NN + nn;
  float xv = x[idx];
  out_f[idx] = xv + mo[idx];                                          // dir0
  out_b[idx] = xv + mo[((size_t)BLr + (size_t)b*LL + lp)*CM + c];     // dir1 flipped
}

// ---------------- concat [out_f, out_b] ----------------------------------
__global__ void cat_k(const float* __restrict__ f, const float* __restrict__ bb,
    float* __restrict__ cat)
{
  size_t idx = (size_t)blockIdx.x*256 + threadIdx.x;
  if (idx >= (size_t)BLr*2*CM) return;
  int c = (int)(idx % (2*CM));
  size_t r = idx / (2*CM);
  cat[idx] = (c < CM) ? f[r*CM + c] : bb[r*CM + c - CM];
}

// ---------------- gated mix ----------------------------------------------
__global__ void mix_k(const float* __restrict__ g, const float* __restrict__ f,
    const float* __restrict__ bo, float* __restrict__ m)
{
  size_t idx = (size_t)blockIdx.x*256 + threadIdx.x;
  if (idx >= (size_t)BLr*CM) return;
  float gg = sigmoidf_(g[idx]);
  m[idx] = gg * f[idx] + (1.f - gg) * bo[idx];
}

extern "C" void kernel_launch(void* const* d_in, const int* in_sizes, int n_in,
                              void* d_out, int out_size, void* d_ws, size_t ws_size,
                              hipStream_t stream)
{
  (void)in_sizes; (void)n_in; (void)out_size; (void)ws_size;
  const float* x      = (const float*)d_in[0];
  const float* norm_w = (const float*)d_in[1];
  const float* in_w   = (const float*)d_in[2];
  const float* conv_w = (const float*)d_in[3];
  const float* conv_b = (const float*)d_in[4];
  const float* xp_w   = (const float*)d_in[5];
  const float* dt_w   = (const float*)d_in[6];
  const float* dt_b   = (const float*)d_in[7];
  const float* A_log  = (const float*)d_in[8];
  const float* Dp     = (const float*)d_in[9];
  const float* out_w  = (const float*)d_in[10];
  const float* gate_w = (const float*)d_in[11];
  const float* gate_b = (const float*)d_in[12];
  const float* proj_w = (const float*)d_in[13];
  const float* proj_b = (const float*)d_in[14];
  float* out = (float*)d_out;
  float* ws  = (float*)d_ws;

  // workspace layout (float offsets); peak ~126.2 MB
  const size_t o_xn   = 0;                                   // 2*BLr*CM
  const size_t o_xz   = o_xn   + (size_t)2*BLr*CM;           // 2*BLr*2*DI
  const size_t o_xbc  = o_xz   + (size_t)2*BLr*2*DI;         // 2*BLr*DI
  const size_t o_xdbl = o_xbc  + (size_t)2*BLr*DI;           // 2*BLr*XD
  const size_t o_dt   = o_xdbl + (size_t)2*BLr*XD;           // 2*BLr*DI
  const size_t o_y    = o_dt   + (size_t)2*BLr*DI;           // 2*BLr*DI
  const size_t o_mo   = o_y    + (size_t)2*BLr*DI;           // 2*BLr*CM
  const size_t o_f    = o_mo   + (size_t)2*BLr*CM;           // BLr*CM
  const size_t o_b    = o_f    + (size_t)BLr*CM;             // BLr*CM
  const size_t o_cat  = o_xn;                 // reuse (xn dead after in_proj)
  const size_t o_gate = o_xz;                 // reuse (xz dead after scan)
  const size_t o_mix  = o_xz + (size_t)BLr*CM;

  // 1. rmsnorm (both dirs)
  rmsnorm_k<<<2*BLr, 256, 0, stream>>>(x, norm_w, ws + o_xn);

  // 2. in_proj: (BLr,768) @ (3072,768)^T -> (BLr,3072)
  for (int dir = 0; dir < 2; ++dir)
    gemm_bt<<<dim3(2*DI/64, (BLr+63)/64), dim3(16,16), 0, stream>>>(
        ws + o_xn + (size_t)dir*BLr*CM, CM,
        in_w + (size_t)dir*2*DI*CM, CM,
        ws + o_xz + (size_t)dir*BLr*2*DI, 2*DI,
        BLr, 2*DI, CM, nullptr);

  // 3. causal dwconv + silu on xb half
  conv_silu_k<<<(int)(((size_t)2*BLr*DI + 255)/256), 256, 0, stream>>>(
      ws + o_xz, conv_w, conv_b, ws + o_xbc);

  // 4. x_proj: (BLr,1536) @ (80,1536)^T -> (BLr,80)
  for (int dir = 0; dir < 2; ++dir)
    gemm_bt<<<dim3((XD+63)/64, (BLr+63)/64), dim3(16,16), 0, stream>>>(
        ws + o_xbc + (size_t)dir*BLr*DI, DI,
        xp_w + (size_t)dir*XD*DI, DI,
        ws + o_xdbl + (size_t)dir*BLr*XD, XD,
        BLr, XD, DI, nullptr);

  // 5. dt_proj: (BLr,48) @ (1536,48)^T + dt_b -> (BLr,1536)
  for (int dir = 0; dir < 2; ++dir)
    gemm_bt<<<dim3(DI/64, (BLr+63)/64), dim3(16,16), 0, stream>>>(
        ws + o_xdbl + (size_t)dir*BLr*XD, XD,
        dt_w + (size_t)dir*DI*DTR, DTR,
        ws + o_dt + (size_t)dir*BLr*DI, DI,
        BLr, DI, DTR, dt_b + (size_t)dir*DI);

  // 6. softplus
  softplus_k<<<(int)(((size_t)2*BLr*DI + 255)/256), 256, 0, stream>>>(
      ws + o_dt, (size_t)2*BLr*DI);

  // 7. selective scan (+ u*D, * silu(z) epilogue)
  scan_k<<<2*BB*(DI/16), 256, 0, stream>>>(
      ws + o_xz, ws + o_xbc, ws + o_dt, ws + o_xdbl, A_log, Dp, ws + o_y);

  // 8. out_proj: (BLr,1536) @ (768,1536)^T -> (BLr,768)
  for (int dir = 0; dir < 2; ++dir)
    gemm_bt<<<dim3(CM/64, (BLr+63)/64), dim3(16,16), 0, stream>>>(
        ws + o_y + (size_t)dir*BLr*DI, DI,
        out_w + (size_t)dir*CM*DI, DI,
        ws + o_mo + (size_t)dir*BLr*CM, CM,
        BLr, CM, DI, nullptr);

  // 9. residual + flip -> out_f, out_b
  addperm_k<<<(int)(((size_t)BLr*CM + 255)/256), 256, 0, stream>>>(
      x, ws + o_mo, ws + o_f, ws + o_b);

  // 10. concat
  cat_k<<<(int)(((size_t)BLr*2*CM + 255)/256), 256, 0, stream>>>(
      ws + o_f, ws + o_b, ws + o_cat);

  // 11. gate linear: (BLr,1536) @ (768,1536)^T + gate_b
  gemm_bt<<<dim3(CM/64, (BLr+63)/64), dim3(16,16), 0, stream>>>(
      ws + o_cat, 2*CM, gate_w, 2*CM, ws + o_gate, CM,
      BLr, CM, 2*CM, gate_b);

  // 12. sigmoid mix
  mix_k<<<(int)(((size_t)BLr*CM + 255)/256), 256, 0, stream>>>(
      ws + o_gate, ws + o_f, ws + o_b, ws + o_mix);

  // 13. final proj -> d_out
  gemm_bt<<<dim3(CM/64, (BLr+63)/64), dim3(16,16), 0, stream>>>(
      ws + o_mix, CM, proj_w, CM, out, CM,
      BLr, CM, CM, proj_b);
}

// Round 2
// 1142.605 us; speedup vs baseline: 2.0206x; 2.0206x over previous
//
#include <hip/hip_runtime.h>
#include <cstdint>
#include <cstddef>

// Problem constants (BiMambaRefinerBlock)
#define BB 2
#define TT 4
#define NN 196
#define LL (TT*NN)        // 784
#define BLr (BB*LL)       // 1568 rows per direction
#define CM 768            // d_model
#define DI 1536           // d_inner
#define DS 16             // d_state
#define DTR 48            // dt_rank
#define XD 80             // dt_rank + 2*d_state

typedef short s16x8 __attribute__((ext_vector_type(8)));
typedef float f32x4 __attribute__((ext_vector_type(4)));

static __device__ __forceinline__ float sigmoidf_(float x) {
  return 1.f / (1.f + __expf(-x));
}
// fp32 -> bf16 (RNE)
static __device__ __forceinline__ unsigned short f2bf(float f) {
  unsigned int u = __float_as_uint(f);
  unsigned int r = (u + 0x7fffu + ((u >> 16) & 1u)) >> 16;
  return (unsigned short)r;
}

// ---------------- RMSNorm -> bf16 (dir1 reads flipped-t source) ----------
__global__ __launch_bounds__(256) void rmsnorm_k(const float* __restrict__ x,
    const float* __restrict__ nw, unsigned short* __restrict__ xn)
{
  int blk = blockIdx.x;               // dir*BLr + b*LL + l
  int l   = blk % LL;
  int b   = (blk / LL) % BB;
  int dir = blk / (BB*LL);
  int lsrc = l;
  if (dir == 1) { int t = l / NN, n = l % NN; lsrc = (TT-1-t)*NN + n; }
  const float* xp = x + ((size_t)b*LL + lsrc)*CM;
  float s = 0.f;
  for (int c = threadIdx.x; c < CM; c += 256) { float v = xp[c]; s += v*v; }
  #pragma unroll
  for (int off = 32; off > 0; off >>= 1) s += __shfl_down(s, off);
  __shared__ float red[4];
  if ((threadIdx.x & 63) == 0) red[threadIdx.x >> 6] = s;
  __syncthreads();
  float tot = red[0] + red[1] + red[2] + red[3];
  float r = rsqrtf(tot * (1.f/CM) + 1e-5f);
  const float* w = nw + dir*CM;
  unsigned short* o = xn + (size_t)blk*CM;
  for (int c = threadIdx.x; c < CM; c += 256) o[c] = f2bf(xp[c] * r * w[c]);
}

// ---------------- weight casts (one dispatch, hardcoded segment map) ------
#define S_INW  4718592        // 2*3072*768
#define S_OUTW 2359296        // 2*768*1536
#define S_GATW 1179648        // 768*1536
#define S_PRJW 589824         // 768*768
#define S_XPW  245760         // 2*80*1536
#define S_DTW  196608         // 2*1536*64 (padded from 48)
#define E0 S_INW
#define E1 (E0 + S_OUTW)      // 7077888
#define E2 (E1 + S_GATW)      // 8257536
#define E3 (E2 + S_PRJW)      // 8847360
#define E4 (E3 + S_XPW)       // 9093120
#define E5 (E4 + S_DTW)       // 9289728
__global__ void multicast_k(const float* __restrict__ in_w,
    const float* __restrict__ out_w, const float* __restrict__ gate_w,
    const float* __restrict__ proj_w, const float* __restrict__ xp_w,
    const float* __restrict__ dt_w, unsigned short* __restrict__ dst)
{
  int i = blockIdx.x*256 + threadIdx.x;
  if (i >= E5) return;
  float v;
  if (i < E0)       v = in_w[i];
  else if (i < E1)  v = out_w[i - E0];
  else if (i < E2)  v = gate_w[i - E1];
  else if (i < E3)  v = proj_w[i - E2];
  else if (i < E4)  v = xp_w[i - E3];
  else {            // dt_w: pad K 48 -> 64
    int j = i - E4, r = j >> 6, c = j & 63;
    v = (c < 48) ? dt_w[r*48 + c] : 0.f;
  }
  dst[i] = f2bf(v);
}

// ---------------- bf16 MFMA GEMM: C[m,n] = sum_k A[m,k]*W[n,k] (+bias[n])
// 128x128 tile, BK=32, 4 waves (2x2), each wave 64x64 via 4x4 mfma 16x16x32.
// LDS layout: slab per k-group c (8 bf16), slab stride 1040 shorts (2080 B)
// -> staging writes 2-way (free), fragment reads sequential (free).
__global__ __launch_bounds__(256, 2) void gemm_mfma(
    const unsigned short* __restrict__ A, int lda, long long sA,
    const unsigned short* __restrict__ W, int ldw, long long sW,
    float* __restrict__ C, int ldc, long long sC,
    int M, int N, int K, const float* __restrict__ bias, long long sBias)
{
  __shared__ short As[4*1040];
  __shared__ short Ws[4*1040];
  const int tid = threadIdx.x;
  const int z = blockIdx.z;
  A += (size_t)z * sA; W += (size_t)z * sW; C += (size_t)z * sC;
  if (bias) bias += (size_t)z * sBias;
  const int m0 = blockIdx.y*128, n0 = blockIdx.x*128;
  const int wv = tid >> 6, lane = tid & 63;
  const int wm = wv >> 1, wn = wv & 1;
  const int lm = lane & 15, g = lane >> 4;
  const s16x8 zero8 = {0,0,0,0,0,0,0,0};
  const f32x4 zero4 = {0.f,0.f,0.f,0.f};
  f32x4 acc[4][4];
  #pragma unroll
  for (int i = 0; i < 4; ++i)
    #pragma unroll
    for (int j = 0; j < 4; ++j) acc[i][j] = zero4;

  for (int k0 = 0; k0 < K; k0 += 32) {
    #pragma unroll
    for (int e = 0; e < 2; ++e) {
      int cid = tid + 256*e;
      int c = cid & 3, m = cid >> 2;   // lanes 0..3 read 64 contiguous bytes
      int gm = m0 + m, gn = n0 + m;
      s16x8 va = zero8, vb = zero8;
      if (gm < M) va = *(const s16x8*)(A + (size_t)gm*lda + k0 + 8*c);
      if (gn < N) vb = *(const s16x8*)(W + (size_t)gn*ldw + k0 + 8*c);
      *(s16x8*)(&As[c*1040 + m*8]) = va;
      *(s16x8*)(&Ws[c*1040 + m*8]) = vb;
    }
    __syncthreads();
    s16x8 af[4], bf[4];
    #pragma unroll
    for (int i = 0; i < 4; ++i)
      af[i] = *(const s16x8*)(&As[g*1040 + (wm*64 + i*16 + lm)*8]);
    #pragma unroll
    for (int j = 0; j < 4; ++j)
      bf[j] = *(const s16x8*)(&Ws[g*1040 + (wn*64 + j*16 + lm)*8]);
    #pragma unroll
    for (int i = 0; i < 4; ++i)
      #pragma unroll
      for (int j = 0; j < 4; ++j)
        acc[i][j] = __builtin_amdgcn_mfma_f32_16x16x32_bf16(af[i], bf[j], acc[i][j], 0, 0, 0);
    __syncthreads();
  }
  // epilogue: C/D layout col=lane&15, row=(lane>>4)*4+reg
  #pragma unroll
  for (int i = 0; i < 4; ++i) {
    int row = m0 + wm*64 + i*16 + g*4;
    #pragma unroll
    for (int j = 0; j < 4; ++j) {
      int col = n0 + wn*64 + j*16 + lm;
      if (col >= N) continue;
      float bv = bias ? bias[col] : 0.f;
      #pragma unroll
      for (int r = 0; r < 4; ++r)
        if (row + r < M) C[(size_t)(row + r)*ldc + col] = acc[i][j][r] + bv;
    }
  }
}

// ---------------- Causal depthwise conv (k=4) + SiLU -> fp32 u + bf16 ub --
__global__ __launch_bounds__(256) void conv_silu_k(const float* __restrict__ xz,
    const float* __restrict__ cw, const float* __restrict__ cb,
    float* __restrict__ u, unsigned short* __restrict__ ub)
{
  size_t idx = (size_t)blockIdx.x*256 + threadIdx.x;
  if (idx >= (size_t)2*BLr*DI) return;
  int di  = (int)(idx % DI);
  size_t r = idx / DI;               // dir*BLr + b*LL + l
  int l   = (int)(r % LL);
  int dir = (int)(r / (BB*LL));
  size_t rowbase = r - l;
  const float* w = cw + ((size_t)dir*DI + di)*4;
  float acc = cb[dir*DI + di];
  #pragma unroll
  for (int k = 0; k < 4; ++k) {
    int lp = l - 3 + k;
    if (lp >= 0) acc = fmaf(w[k], xz[(rowbase + lp)*(2*DI) + di], acc);
  }
  float v = acc * sigmoidf_(acc);
  u[idx]  = v;
  ub[idx] = f2bf(v);
}

// ---------------- cast dt-part of xdbl (80 cols) -> bf16 padded 64 cols ---
__global__ void dtcast_k(const float* __restrict__ xdbl,
    unsigned short* __restrict__ xdbl_b)
{
  int i = blockIdx.x*256 + threadIdx.x;
  if (i >= 2*BLr*64) return;
  int r = i >> 6, c = i & 63;
  xdbl_b[i] = (c < DTR) ? f2bf(xdbl[(size_t)r*XD + c]) : (unsigned short)0;
}

// ---------------- Selective scan, softplus fused, 8-deep prefetch ---------
// thread = (d, n); block = 16 d x 16 n; 784-step sequential scan.
#define PF 8
__global__ __launch_bounds__(256) void scan_k(const float* __restrict__ xz,
    const float* __restrict__ u, const float* __restrict__ dtraw,
    const float* __restrict__ xdbl, const float* __restrict__ A_log,
    const float* __restrict__ Dp, unsigned short* __restrict__ y)
{
  int bx = blockIdx.x;
  int dchunk = bx % (DI/16);
  int b   = (bx / (DI/16)) % BB;
  int dir = bx / ((DI/16)*BB);
  int tid = threadIdx.x;
  int dl = tid >> 4, n = tid & 15;
  int d = dchunk*16 + dl;
  size_t rb = ((size_t)dir*BB + b) * LL;
  const float* dtp = dtraw + rb*DI + d;
  const float* up  = u  + rb*DI + d;
  const float* zp  = xz + rb*(2*DI) + DI + d;
  const float* Bp  = xdbl + rb*XD + DTR + n;
  unsigned short* yp = y + rb*DI + d;
  float Av = -__expf(A_log[((size_t)dir*DI + d)*DS + n]);
  float Dd = Dp[dir*DI + d];
  float bdt[PF], bu[PF], bBv[PF], bCv[PF], bz[PF];
  #pragma unroll
  for (int j = 0; j < PF; ++j) {
    bdt[j] = dtp[(size_t)j*DI];
    bu[j]  = up[(size_t)j*DI];
    bBv[j] = Bp[(size_t)j*XD];
    bCv[j] = Bp[(size_t)j*XD + DS];
    bz[j]  = zp[(size_t)j*(2*DI)];
  }
  float h = 0.f;
  for (int l0 = 0; l0 < LL; l0 += PF) {
    #pragma unroll
    for (int j = 0; j < PF; ++j) {
      int l = l0 + j;
      float dtr = bdt[j], uv = bu[j], Bv = bBv[j], Cv = bCv[j], zv = bz[j];
      int lp = l + PF;
      if (lp < LL) {                 // uniform branch; issues loads 8 ahead
        bdt[j] = dtp[(size_t)lp*DI];
        bu[j]  = up[(size_t)lp*DI];
        bBv[j] = Bp[(size_t)lp*XD];
        bCv[j] = Bp[(size_t)lp*XD + DS];
        bz[j]  = zp[(size_t)lp*(2*DI)];
      }
      float dtv = (dtr > 20.f) ? dtr : log1pf(__expf(dtr));
      float dA = __expf(dtv * Av);
      h = fmaf(dA, h, dtv * uv * Bv);
      float acc = h * Cv;
      #pragma unroll
      for (int off = 1; off < 16; off <<= 1) acc += __shfl_xor(acc, off);
      if (n == 0) {
        float yv = (acc + uv * Dd) * (zv * sigmoidf_(zv));
        yp[(size_t)l*DI] = f2bf(yv);
      }
    }
  }
}

// ---------------- residual add + flip -> f32 f, f32 b, bf16 cat ----------
__global__ void addperm_k(const float* __restrict__ x, const float* __restrict__ mo,
    float* __restrict__ out_f, float* __restrict__ out_b,
    unsigned short* __restrict__ cat)
{
  size_t idx = (size_t)blockIdx.x*256 + threadIdx.x;
  if (idx >= (size_t)BLr*CM) return;
  int c = (int)(idx % CM);
  size_t r = idx / CM;               // b*LL + l
  int l = (int)(r % LL);
  int b = (int)(r / LL);
  int t = l / NN, nn = l % NN;
  int lpos = (TT-1-t)*NN + nn;
  float xv = x[idx];
  float fv = xv + mo[idx];
  float bv = xv + mo[((size_t)BLr + (size_t)b*LL + lpos)*CM + c];
  out_f[idx] = fv;
  out_b[idx] = bv;
  cat[r*(2*CM) + c]      = f2bf(fv);
  cat[r*(2*CM) + CM + c] = f2bf(bv);
}

// ---------------- gated mix -> bf16 --------------------------------------
__global__ void mix_k(const float* __restrict__ g, const float* __restrict__ f,
    const float* __restrict__ bo, unsigned short* __restrict__ m)
{
  size_t idx = (size_t)blockIdx.x*256 + threadIdx.x;
  if (idx >= (size_t)BLr*CM) return;
  float gg = sigmoidf_(g[idx]);
  m[idx] = f2bf(gg * f[idx] + (1.f - gg) * bo[idx]);
}

extern "C" void kernel_launch(void* const* d_in, const int* in_sizes, int n_in,
                              void* d_out, int out_size, void* d_ws, size_t ws_size,
                              hipStream_t stream)
{
  (void)in_sizes; (void)n_in; (void)out_size; (void)ws_size;
  const float* x      = (const float*)d_in[0];
  const float* norm_w = (const float*)d_in[1];
  const float* in_w   = (const float*)d_in[2];
  const float* conv_w = (const float*)d_in[3];
  const float* conv_b = (const float*)d_in[4];
  const float* xp_w   = (const float*)d_in[5];
  const float* dt_w   = (const float*)d_in[6];
  const float* dt_b   = (const float*)d_in[7];
  const float* A_log  = (const float*)d_in[8];
  const float* Dp     = (const float*)d_in[9];
  const float* out_w  = (const float*)d_in[10];
  const float* gate_w = (const float*)d_in[11];
  const float* gate_b = (const float*)d_in[12];
  const float* proj_w = (const float*)d_in[13];
  const float* proj_b = (const float*)d_in[14];
  float* out = (float*)d_out;
  char* wsb  = (char*)d_ws;

  // ---- workspace layout (byte offsets; peak ~115.9 MB) ----
  unsigned short* w_all   = (unsigned short*)(wsb + 0);          // 18,579,456 B
  unsigned short* in_w_b  = w_all;
  unsigned short* out_w_b = w_all + E0;
  unsigned short* gate_w_b= w_all + E1;
  unsigned short* proj_w_b= w_all + E2;
  unsigned short* xp_w_b  = w_all + E3;
  unsigned short* dt_w_b  = w_all + E4;
  float* xz    = (float*)(wsb + 18579456);    // 2*BLr*3072 fl (38.5 MB)
  float* ubuf  = (float*)(wsb + 57114624);    // 2*BLr*1536 fl (19.3 MB)
  float* xdbl  = (float*)(wsb + 76382208);    // 2*BLr*80 fl
  float* dtb   = (float*)(wsb + 77385728);    // 2*BLr*1536 fl (19.3 MB)
  unsigned short* y_b = (unsigned short*)(wsb + 96653312);  // 2*BLr*1536 bf16
  unsigned short* tmp = (unsigned short*)(wsb + 106287104); // xn_b / ub / xdbl_b
  // post-scan reuse of xz region:
  float* mo    = (float*)(wsb + 18579456);    // 2*BLr*768 fl
  float* fbuf  = (float*)(wsb + 28213248);    // BLr*768 fl
  float* bbuf  = (float*)(wsb + 33030144);    // BLr*768 fl
  unsigned short* cat_b = (unsigned short*)(wsb + 37847040); // BLr*1536 bf16
  float* gbuf  = (float*)(wsb + 42663936);    // BLr*768 fl
  unsigned short* mix_b = (unsigned short*)(wsb + 47480832); // BLr*768 bf16

  unsigned short* xn_b   = tmp;   // 2*BLr*768, live until in_proj
  unsigned short* ub     = tmp;   // 2*BLr*1536, live conv->x_proj
  unsigned short* xdbl_b = tmp;   // 2*BLr*64, live dtcast->dt_proj

  // 1. rmsnorm (both dirs) -> bf16
  rmsnorm_k<<<2*BLr, 256, 0, stream>>>(x, norm_w, xn_b);
  // 2. weight casts (one dispatch)
  multicast_k<<<(E5 + 255)/256, 256, 0, stream>>>(
      in_w, out_w, gate_w, proj_w, xp_w, dt_w, w_all);
  // 3. in_proj: (BLr,768)x(3072,768)^T -> xz, both dirs via grid.z
  gemm_mfma<<<dim3(3072/128, (BLr+127)/128, 2), 256, 0, stream>>>(
      xn_b, CM, (long long)BLr*CM, in_w_b, CM, (long long)2*DI*CM,
      xz, 2*DI, (long long)BLr*2*DI, BLr, 2*DI, CM, nullptr, 0);
  // 4. causal dwconv + silu -> u (fp32) + ub (bf16)
  conv_silu_k<<<(int)(((size_t)2*BLr*DI + 255)/256), 256, 0, stream>>>(
      xz, conv_w, conv_b, ubuf, ub);
  // 5. x_proj: (BLr,1536)x(80,1536)^T -> xdbl fp32
  gemm_mfma<<<dim3(1, (BLr+127)/128, 2), 256, 0, stream>>>(
      ub, DI, (long long)BLr*DI, xp_w_b, DI, (long long)XD*DI,
      xdbl, XD, (long long)BLr*XD, BLr, XD, DI, nullptr, 0);
  // 6. cast dt cols of xdbl -> bf16 padded to 64
  dtcast_k<<<(2*BLr*64 + 255)/256, 256, 0, stream>>>(xdbl, xdbl_b);
  // 7. dt_proj: (BLr,64)x(1536,64)^T + dt_b -> dtb (pre-softplus)
  gemm_mfma<<<dim3(DI/128, (BLr+127)/128, 2), 256, 0, stream>>>(
      xdbl_b, 64, (long long)BLr*64, dt_w_b, 64, (long long)DI*64,
      dtb, DI, (long long)BLr*DI, BLr, DI, 64, dt_b, DI);
  // 8. selective scan (softplus + u*D + silu(z) fused) -> y bf16
  scan_k<<<2*BB*(DI/16), 256, 0, stream>>>(
      xz, ubuf, dtb, xdbl, A_log, Dp, y_b);
  // 9. out_proj: (BLr,1536)x(768,1536)^T -> mo fp32
  gemm_mfma<<<dim3(CM/128, (BLr+127)/128, 2), 256, 0, stream>>>(
      y_b, DI, (long long)BLr*DI, out_w_b, DI, (long long)CM*DI,
      mo, CM, (long long)BLr*CM, BLr, CM, DI, nullptr, 0);
  // 10. residual + flip -> f, b (fp32), cat (bf16)
  addperm_k<<<(int)(((size_t)BLr*CM + 255)/256), 256, 0, stream>>>(
      x, mo, fbuf, bbuf, cat_b);
  // 11. gate linear: (BLr,1536)x(768,1536)^T + gate_b -> gbuf
  gemm_mfma<<<dim3(CM/128, (BLr+127)/128, 1), 256, 0, stream>>>(
      cat_b, 2*CM, 0, gate_w_b, 2*CM, 0,
      gbuf, CM, 0, BLr, CM, 2*CM, gate_b, 0);
  // 12. sigmoid mix -> bf16
  mix_k<<<(int)(((size_t)BLr*CM + 255)/256), 256, 0, stream>>>(
      gbuf, fbuf, bbuf, mix_b);
  // 13. final proj -> d_out (fp32 + bias)
  gemm_mfma<<<dim3(CM/128, (BLr+127)/128, 1), 256, 0, stream>>>(
      mix_b, CM, 0, proj_w_b, CM, 0,
      out, CM, 0, BLr, CM, CM, proj_b, 0);
}

// Round 3
// 573.197 us; speedup vs baseline: 4.0278x; 1.9934x over previous
//
#include <hip/hip_runtime.h>
#include <cstdint>
#include <cstddef>

// Problem constants (BiMambaRefinerBlock)
#define BB 2
#define TT 4
#define NN 196
#define LL (TT*NN)        // 784
#define BLr (BB*LL)       // 1568 rows per direction
#define CM 768            // d_model
#define DI 1536           // d_inner
#define DS 16             // d_state
#define DTR 48            // dt_rank
#define XD 80             // dt_rank + 2*d_state
// chunked scan
#define GCH 8
#define LC (LL/GCH)       // 98
#define NST (2*BB*DI*DS)  // 98304 states

typedef short s16x8 __attribute__((ext_vector_type(8)));
typedef float f32x4 __attribute__((ext_vector_type(4)));

static __device__ __forceinline__ float sigmoidf_(float x) {
  return 1.f / (1.f + __expf(-x));
}
// fp32 -> bf16 (RNE)
static __device__ __forceinline__ unsigned short f2bf(float f) {
  unsigned int u = __float_as_uint(f);
  unsigned int r = (u + 0x7fffu + ((u >> 16) & 1u)) >> 16;
  return (unsigned short)r;
}

// ---------------- RMSNorm -> bf16 (dir1 reads flipped-t source) ----------
__global__ __launch_bounds__(256) void rmsnorm_k(const float* __restrict__ x,
    const float* __restrict__ nw, unsigned short* __restrict__ xn)
{
  int blk = blockIdx.x;               // dir*BLr + b*LL + l
  int l   = blk % LL;
  int b   = (blk / LL) % BB;
  int dir = blk / (BB*LL);
  int lsrc = l;
  if (dir == 1) { int t = l / NN, n = l % NN; lsrc = (TT-1-t)*NN + n; }
  const float* xp = x + ((size_t)b*LL + lsrc)*CM;
  float s = 0.f;
  for (int c = threadIdx.x; c < CM; c += 256) { float v = xp[c]; s += v*v; }
  #pragma unroll
  for (int off = 32; off > 0; off >>= 1) s += __shfl_down(s, off);
  __shared__ float red[4];
  if ((threadIdx.x & 63) == 0) red[threadIdx.x >> 6] = s;
  __syncthreads();
  float tot = red[0] + red[1] + red[2] + red[3];
  float r = rsqrtf(tot * (1.f/CM) + 1e-5f);
  const float* w = nw + dir*CM;
  unsigned short* o = xn + (size_t)blk*CM;
  for (int c = threadIdx.x; c < CM; c += 256) o[c] = f2bf(xp[c] * r * w[c]);
}

// ---------------- weight casts (one dispatch, hardcoded segment map) ------
#define S_INW  4718592        // 2*3072*768
#define S_OUTW 2359296        // 2*768*1536
#define S_GATW 1179648        // 768*1536
#define S_PRJW 589824         // 768*768
#define S_XPW  245760         // 2*80*1536
#define S_DTW  196608         // 2*1536*64 (padded from 48)
#define E0 S_INW
#define E1 (E0 + S_OUTW)      // 7077888
#define E2 (E1 + S_GATW)      // 8257536
#define E3 (E2 + S_PRJW)      // 8847360
#define E4 (E3 + S_XPW)       // 9093120
#define E5 (E4 + S_DTW)       // 9289728
__global__ void multicast_k(const float* __restrict__ in_w,
    const float* __restrict__ out_w, const float* __restrict__ gate_w,
    const float* __restrict__ proj_w, const float* __restrict__ xp_w,
    const float* __restrict__ dt_w, unsigned short* __restrict__ dst)
{
  int i = blockIdx.x*256 + threadIdx.x;
  if (i >= E5) return;
  float v;
  if (i < E0)       v = in_w[i];
  else if (i < E1)  v = out_w[i - E0];
  else if (i < E2)  v = gate_w[i - E1];
  else if (i < E3)  v = proj_w[i - E2];
  else if (i < E4)  v = xp_w[i - E3];
  else {            // dt_w: pad K 48 -> 64
    int j = i - E4, r = j >> 6, c = j & 63;
    v = (c < 48) ? dt_w[r*48 + c] : 0.f;
  }
  dst[i] = f2bf(v);
}

// ---------------- bf16 MFMA GEMM: C[m,n] = sum_k A[m,k]*W[n,k] (+bias[n])
// 128x128 tile, BK=32, 4 waves (2x2), each wave 64x64 via 4x4 mfma 16x16x32.
// act==1: softplus epilogue (for dt_proj).
__global__ __launch_bounds__(256, 2) void gemm_mfma(
    const unsigned short* __restrict__ A, int lda, long long sA,
    const unsigned short* __restrict__ W, int ldw, long long sW,
    float* __restrict__ C, int ldc, long long sC,
    int M, int N, int K, const float* __restrict__ bias, long long sBias,
    int act)
{
  __shared__ short As[4*1040];
  __shared__ short Ws[4*1040];
  const int tid = threadIdx.x;
  const int z = blockIdx.z;
  A += (size_t)z * sA; W += (size_t)z * sW; C += (size_t)z * sC;
  if (bias) bias += (size_t)z * sBias;
  const int m0 = blockIdx.y*128, n0 = blockIdx.x*128;
  const int wv = tid >> 6, lane = tid & 63;
  const int wm = wv >> 1, wn = wv & 1;
  const int lm = lane & 15, g = lane >> 4;
  const s16x8 zero8 = {0,0,0,0,0,0,0,0};
  const f32x4 zero4 = {0.f,0.f,0.f,0.f};
  f32x4 acc[4][4];
  #pragma unroll
  for (int i = 0; i < 4; ++i)
    #pragma unroll
    for (int j = 0; j < 4; ++j) acc[i][j] = zero4;

  for (int k0 = 0; k0 < K; k0 += 32) {
    #pragma unroll
    for (int e = 0; e < 2; ++e) {
      int cid = tid + 256*e;
      int c = cid & 3, m = cid >> 2;
      int gm = m0 + m, gn = n0 + m;
      s16x8 va = zero8, vb = zero8;
      if (gm < M) va = *(const s16x8*)(A + (size_t)gm*lda + k0 + 8*c);
      if (gn < N) vb = *(const s16x8*)(W + (size_t)gn*ldw + k0 + 8*c);
      *(s16x8*)(&As[c*1040 + m*8]) = va;
      *(s16x8*)(&Ws[c*1040 + m*8]) = vb;
    }
    __syncthreads();
    s16x8 af[4], bf[4];
    #pragma unroll
    for (int i = 0; i < 4; ++i)
      af[i] = *(const s16x8*)(&As[g*1040 + (wm*64 + i*16 + lm)*8]);
    #pragma unroll
    for (int j = 0; j < 4; ++j)
      bf[j] = *(const s16x8*)(&Ws[g*1040 + (wn*64 + j*16 + lm)*8]);
    #pragma unroll
    for (int i = 0; i < 4; ++i)
      #pragma unroll
      for (int j = 0; j < 4; ++j)
        acc[i][j] = __builtin_amdgcn_mfma_f32_16x16x32_bf16(af[i], bf[j], acc[i][j], 0, 0, 0);
    __syncthreads();
  }
  // epilogue: C/D layout col=lane&15, row=(lane>>4)*4+reg
  #pragma unroll
  for (int i = 0; i < 4; ++i) {
    int row = m0 + wm*64 + i*16 + g*4;
    #pragma unroll
    for (int j = 0; j < 4; ++j) {
      int col = n0 + wn*64 + j*16 + lm;
      if (col >= N) continue;
      float bv = bias ? bias[col] : 0.f;
      #pragma unroll
      for (int r = 0; r < 4; ++r) {
        if (row + r >= M) continue;
        float v = acc[i][j][r] + bv;
        if (act) v = (v > 20.f) ? v : log1pf(__expf(v));
        C[(size_t)(row + r)*ldc + col] = v;
      }
    }
  }
}

// ---------------- Causal depthwise conv (k=4) + SiLU -> fp32 u + bf16 ub --
__global__ __launch_bounds__(256) void conv_silu_k(const float* __restrict__ xz,
    const float* __restrict__ cw, const float* __restrict__ cb,
    float* __restrict__ u, unsigned short* __restrict__ ub)
{
  size_t idx = (size_t)blockIdx.x*256 + threadIdx.x;
  if (idx >= (size_t)2*BLr*DI) return;
  int di  = (int)(idx % DI);
  size_t r = idx / DI;               // dir*BLr + b*LL + l
  int l   = (int)(r % LL);
  int dir = (int)(r / (BB*LL));
  size_t rowbase = r - l;
  const float* w = cw + ((size_t)dir*DI + di)*4;
  float acc = cb[dir*DI + di];
  #pragma unroll
  for (int k = 0; k < 4; ++k) {
    int lp = l - 3 + k;
    if (lp >= 0) acc = fmaf(w[k], xz[(rowbase + lp)*(2*DI) + di], acc);
  }
  float v = acc * sigmoidf_(acc);
  u[idx]  = v;
  ub[idx] = f2bf(v);
}

// ---------------- cast dt-part of xdbl (80 cols) -> bf16 padded 64 cols ---
__global__ void dtcast_k(const float* __restrict__ xdbl,
    unsigned short* __restrict__ xdbl_b)
{
  int i = blockIdx.x*256 + threadIdx.x;
  if (i >= 2*BLr*64) return;
  int r = i >> 6, c = i & 63;
  xdbl_b[i] = (c < DTR) ? f2bf(xdbl[(size_t)r*XD + c]) : (unsigned short)0;
}

// ---------------- chunked selective scan ---------------------------------
// state id: sid = ((dir*BB+b)*DI + d)*DS + n
// Phase A: per chunk g, local scan from h=0 -> carry c_g; P_g = exp(Av*sum dtv)
__global__ __launch_bounds__(256) void scanA_k(const float* __restrict__ dtv,
    const float* __restrict__ u, const float* __restrict__ xdbl,
    const float* __restrict__ A_log, float* __restrict__ carry,
    float* __restrict__ Pm)
{
  int bx = blockIdx.x;                 // dir*2*96*8 + b*96*8 + dchunk*8 + g
  int g = bx & 7;
  int rest = bx >> 3;
  int dchunk = rest % (DI/16);
  int b   = (rest / (DI/16)) % BB;
  int dir = rest / ((DI/16)*BB);
  int tid = threadIdx.x;
  int dl = tid >> 4, n = tid & 15;
  int d = dchunk*16 + dl;
  size_t rb = ((size_t)dir*BB + b) * LL + (size_t)g*LC;
  const float* dtp = dtv + rb*DI + d;
  const float* up  = u   + rb*DI + d;
  const float* Bp  = xdbl + rb*XD + DTR + n;
  float Av = -__expf(A_log[((size_t)dir*DI + d)*DS + n]);
  float h = 0.f, S = 0.f;
  float ndt = dtp[0], nu = up[0], nB = Bp[0];
  for (int j = 0; j < LC; ++j) {
    float cdt = ndt, cu = nu, cB = nB;
    if (j + 1 < LC) {
      ndt = dtp[(size_t)(j+1)*DI];
      nu  = up[(size_t)(j+1)*DI];
      nB  = Bp[(size_t)(j+1)*XD];
    }
    float dA = __expf(cdt * Av);
    h = fmaf(dA, h, cdt * cu * cB);
    S += cdt;
  }
  int sid = ((dir*BB + b)*DI + d)*DS + n;
  carry[(size_t)g*NST + sid] = h;
  Pm[(size_t)g*NST + sid]    = __expf(Av * S);
}

// Phase B: sequential combine over chunks (tiny)
__global__ __launch_bounds__(256) void scanB_k(const float* __restrict__ carry,
    const float* __restrict__ Pm, float* __restrict__ h_in)
{
  int sid = blockIdx.x*256 + threadIdx.x;   // < NST
  float h = 0.f;
  #pragma unroll
  for (int g = 0; g < GCH; ++g) {
    h_in[(size_t)g*NST + sid] = h;
    h = fmaf(Pm[(size_t)g*NST + sid], h, carry[(size_t)g*NST + sid]);
  }
}

// Phase C: re-scan chunk from h_in, reduce over n, epilogue -> y bf16
__global__ __launch_bounds__(256) void scanC_k(const float* __restrict__ dtv,
    const float* __restrict__ u, const float* __restrict__ xz,
    const float* __restrict__ xdbl, const float* __restrict__ A_log,
    const float* __restrict__ Dp, const float* __restrict__ h_in,
    unsigned short* __restrict__ y)
{
  int bx = blockIdx.x;
  int g = bx & 7;
  int rest = bx >> 3;
  int dchunk = rest % (DI/16);
  int b   = (rest / (DI/16)) % BB;
  int dir = rest / ((DI/16)*BB);
  int tid = threadIdx.x;
  int dl = tid >> 4, n = tid & 15;
  int d = dchunk*16 + dl;
  size_t rb = ((size_t)dir*BB + b) * LL + (size_t)g*LC;
  const float* dtp = dtv + rb*DI + d;
  const float* up  = u   + rb*DI + d;
  const float* zp  = xz  + rb*(2*DI) + DI + d;
  const float* Bp  = xdbl + rb*XD + DTR + n;
  unsigned short* yp = y + rb*DI + d;
  float Av = -__expf(A_log[((size_t)dir*DI + d)*DS + n]);
  float Dd = Dp[dir*DI + d];
  int sid = ((dir*BB + b)*DI + d)*DS + n;
  float h = h_in[(size_t)g*NST + sid];
  float ndt = dtp[0], nu = up[0], nB = Bp[0], nC = Bp[DS], nz = zp[0];
  for (int j = 0; j < LC; ++j) {
    float cdt = ndt, cu = nu, cB = nB, cC = nC, cz = nz;
    if (j + 1 < LC) {
      ndt = dtp[(size_t)(j+1)*DI];
      nu  = up[(size_t)(j+1)*DI];
      nB  = Bp[(size_t)(j+1)*XD];
      nC  = Bp[(size_t)(j+1)*XD + DS];
      nz  = zp[(size_t)(j+1)*(2*DI)];
    }
    float dA = __expf(cdt * Av);
    h = fmaf(dA, h, cdt * cu * cB);
    float acc = h * cC;
    #pragma unroll
    for (int off = 1; off < 16; off <<= 1) acc += __shfl_xor(acc, off);
    if (n == 0) {
      float yv = (acc + cu * Dd) * (cz * sigmoidf_(cz));
      yp[(size_t)j*DI] = f2bf(yv);
    }
  }
}

// ---------------- residual add + flip -> f32 f, f32 b, bf16 cat ----------
__global__ void addperm_k(const float* __restrict__ x, const float* __restrict__ mo,
    float* __restrict__ out_f, float* __restrict__ out_b,
    unsigned short* __restrict__ cat)
{
  size_t idx = (size_t)blockIdx.x*256 + threadIdx.x;
  if (idx >= (size_t)BLr*CM) return;
  int c = (int)(idx % CM);
  size_t r = idx / CM;               // b*LL + l
  int l = (int)(r % LL);
  int b = (int)(r / LL);
  int t = l / NN, nn = l % NN;
  int lpos = (TT-1-t)*NN + nn;
  float xv = x[idx];
  float fv = xv + mo[idx];
  float bv = xv + mo[((size_t)BLr + (size_t)b*LL + lpos)*CM + c];
  out_f[idx] = fv;
  out_b[idx] = bv;
  cat[r*(2*CM) + c]      = f2bf(fv);
  cat[r*(2*CM) + CM + c] = f2bf(bv);
}

// ---------------- gated mix -> bf16 --------------------------------------
__global__ void mix_k(const float* __restrict__ g, const float* __restrict__ f,
    const float* __restrict__ bo, unsigned short* __restrict__ m)
{
  size_t idx = (size_t)blockIdx.x*256 + threadIdx.x;
  if (idx >= (size_t)BLr*CM) return;
  float gg = sigmoidf_(g[idx]);
  m[idx] = f2bf(gg * f[idx] + (1.f - gg) * bo[idx]);
}

extern "C" void kernel_launch(void* const* d_in, const int* in_sizes, int n_in,
                              void* d_out, int out_size, void* d_ws, size_t ws_size,
                              hipStream_t stream)
{
  (void)in_sizes; (void)n_in; (void)out_size; (void)ws_size;
  const float* x      = (const float*)d_in[0];
  const float* norm_w = (const float*)d_in[1];
  const float* in_w   = (const float*)d_in[2];
  const float* conv_w = (const float*)d_in[3];
  const float* conv_b = (const float*)d_in[4];
  const float* xp_w   = (const float*)d_in[5];
  const float* dt_w   = (const float*)d_in[6];
  const float* dt_b   = (const float*)d_in[7];
  const float* A_log  = (const float*)d_in[8];
  const float* Dp     = (const float*)d_in[9];
  const float* out_w  = (const float*)d_in[10];
  const float* gate_w = (const float*)d_in[11];
  const float* gate_b = (const float*)d_in[12];
  const float* proj_w = (const float*)d_in[13];
  const float* proj_b = (const float*)d_in[14];
  float* out = (float*)d_out;
  char* wsb  = (char*)d_ws;

  // ---- workspace layout (byte offsets; peak ~115.9 MB, same as R2) ----
  unsigned short* w_all   = (unsigned short*)(wsb + 0);          // 18,579,456 B
  unsigned short* in_w_b  = w_all;
  unsigned short* out_w_b = w_all + E0;
  unsigned short* gate_w_b= w_all + E1;
  unsigned short* proj_w_b= w_all + E2;
  unsigned short* xp_w_b  = w_all + E3;
  unsigned short* dt_w_b  = w_all + E4;
  float* xz    = (float*)(wsb + 18579456);    // 2*BLr*3072 fl (38.5 MB)
  float* ubuf  = (float*)(wsb + 57114624);    // 2*BLr*1536 fl (19.3 MB)
  float* xdbl  = (float*)(wsb + 76382208);    // 2*BLr*80 fl
  float* dtvb  = (float*)(wsb + 77385728);    // 2*BLr*1536 fl (19.3 MB), post-softplus
  unsigned short* y_b = (unsigned short*)(wsb + 96653312);  // 2*BLr*1536 bf16
  unsigned short* tmp = (unsigned short*)(wsb + 106287104); // 9,633,792 B scratch
  // post-scan reuse of xz region:
  float* mo    = (float*)(wsb + 18579456);    // 2*BLr*768 fl
  float* fbuf  = (float*)(wsb + 28213248);    // BLr*768 fl
  float* bbuf  = (float*)(wsb + 33030144);    // BLr*768 fl
  unsigned short* cat_b = (unsigned short*)(wsb + 37847040); // BLr*1536 bf16
  float* gbuf  = (float*)(wsb + 42663936);    // BLr*768 fl
  unsigned short* mix_b = (unsigned short*)(wsb + 47480832); // BLr*768 bf16

  unsigned short* xn_b   = tmp;   // 2*BLr*768 bf16, live until in_proj
  unsigned short* ub     = tmp;   // 2*BLr*1536 bf16, live conv->x_proj
  unsigned short* xdbl_b = tmp;   // 2*BLr*64 bf16, live dtcast->dt_proj
  // scan-phase reuse of tmp (xdbl_b dead after dt_proj): 3 x 3,145,728 B
  float* carry = (float*)(wsb + 106287104);
  float* Pmat  = (float*)(wsb + 106287104 + 3145728);
  float* h_in  = (float*)(wsb + 106287104 + 2*3145728);

  // 1. rmsnorm (both dirs) -> bf16
  rmsnorm_k<<<2*BLr, 256, 0, stream>>>(x, norm_w, xn_b);
  // 2. weight casts
  multicast_k<<<(E5 + 255)/256, 256, 0, stream>>>(
      in_w, out_w, gate_w, proj_w, xp_w, dt_w, w_all);
  // 3. in_proj
  gemm_mfma<<<dim3(3072/128, (BLr+127)/128, 2), 256, 0, stream>>>(
      xn_b, CM, (long long)BLr*CM, in_w_b, CM, (long long)2*DI*CM,
      xz, 2*DI, (long long)BLr*2*DI, BLr, 2*DI, CM, nullptr, 0, 0);
  // 4. causal dwconv + silu -> u (fp32) + ub (bf16)
  conv_silu_k<<<(int)(((size_t)2*BLr*DI + 255)/256), 256, 0, stream>>>(
      xz, conv_w, conv_b, ubuf, ub);
  // 5. x_proj -> xdbl fp32
  gemm_mfma<<<dim3(1, (BLr+127)/128, 2), 256, 0, stream>>>(
      ub, DI, (long long)BLr*DI, xp_w_b, DI, (long long)XD*DI,
      xdbl, XD, (long long)BLr*XD, BLr, XD, DI, nullptr, 0, 0);
  // 6. cast dt cols of xdbl -> bf16 padded to 64
  dtcast_k<<<(2*BLr*64 + 255)/256, 256, 0, stream>>>(xdbl, xdbl_b);
  // 7. dt_proj + bias + SOFTPLUS fused -> dtvb
  gemm_mfma<<<dim3(DI/128, (BLr+127)/128, 2), 256, 0, stream>>>(
      xdbl_b, 64, (long long)BLr*64, dt_w_b, 64, (long long)DI*64,
      dtvb, DI, (long long)BLr*DI, BLr, DI, 64, dt_b, DI, 1);
  // 8. chunked scan: A (carries) -> B (combine) -> C (outputs)
  scanA_k<<<2*BB*(DI/16)*GCH, 256, 0, stream>>>(
      dtvb, ubuf, xdbl, A_log, carry, Pmat);
  scanB_k<<<NST/256, 256, 0, stream>>>(carry, Pmat, h_in);
  scanC_k<<<2*BB*(DI/16)*GCH, 256, 0, stream>>>(
      dtvb, ubuf, xz, xdbl, A_log, Dp, h_in, y_b);
  // 9. out_proj -> mo fp32
  gemm_mfma<<<dim3(CM/128, (BLr+127)/128, 2), 256, 0, stream>>>(
      y_b, DI, (long long)BLr*DI, out_w_b, DI, (long long)CM*DI,
      mo, CM, (long long)BLr*CM, BLr, CM, DI, nullptr, 0, 0);
  // 10. residual + flip -> f, b (fp32), cat (bf16)
  addperm_k<<<(int)(((size_t)BLr*CM + 255)/256), 256, 0, stream>>>(
      x, mo, fbuf, bbuf, cat_b);
  // 11. gate linear
  gemm_mfma<<<dim3(CM/128, (BLr+127)/128, 1), 256, 0, stream>>>(
      cat_b, 2*CM, 0, gate_w_b, 2*CM, 0,
      gbuf, CM, 0, BLr, CM, 2*CM, gate_b, 0, 0);
  // 12. sigmoid mix -> bf16
  mix_k<<<(int)(((size_t)BLr*CM + 255)/256), 256, 0, stream>>>(
      gbuf, fbuf, bbuf, mix_b);
  // 13. final proj -> d_out (fp32 + bias)
  gemm_mfma<<<dim3(CM/128, (BLr+127)/128, 1), 256, 0, stream>>>(
      mix_b, CM, 0, proj_w_b, CM, 0,
      out, CM, 0, BLr, CM, CM, proj_b, 0, 0);
}

// Round 4
// 508.231 us; speedup vs baseline: 4.5426x; 1.1278x over previous
//
#include <hip/hip_runtime.h>
#include <cstdint>
#include <cstddef>

// Problem constants (BiMambaRefinerBlock)
#define BB 2
#define TT 4
#define NN 196
#define LL (TT*NN)        // 784
#define BLr (BB*LL)       // 1568 rows per direction
#define CM 768            // d_model
#define DI 1536           // d_inner
#define DS 16             // d_state
#define DTR 48            // dt_rank
#define XD 80             // dt_rank + 2*d_state
// chunked scan
#define GCH 8
#define LC (LL/GCH)       // 98
#define NST (2*BB*DI*DS)  // 98304 states

typedef short s16x8 __attribute__((ext_vector_type(8)));
typedef float f32x4 __attribute__((ext_vector_type(4)));

static __device__ __forceinline__ float sigmoidf_(float x) {
  return 1.f / (1.f + __expf(-x));
}
// fp32 -> bf16 (RNE)
static __device__ __forceinline__ unsigned short f2bf(float f) {
  unsigned int u = __float_as_uint(f);
  unsigned int r = (u + 0x7fffu + ((u >> 16) & 1u)) >> 16;
  return (unsigned short)r;
}

// ---------------- RMSNorm -> bf16 (dir1 reads flipped-t source) ----------
__global__ __launch_bounds__(256) void rmsnorm_k(const float* __restrict__ x,
    const float* __restrict__ nw, unsigned short* __restrict__ xn)
{
  int blk = blockIdx.x;               // dir*BLr + b*LL + l
  int l   = blk % LL;
  int b   = (blk / LL) % BB;
  int dir = blk / (BB*LL);
  int lsrc = l;
  if (dir == 1) { int t = l / NN, n = l % NN; lsrc = (TT-1-t)*NN + n; }
  const float* xp = x + ((size_t)b*LL + lsrc)*CM;
  float s = 0.f;
  for (int c = threadIdx.x; c < CM; c += 256) { float v = xp[c]; s += v*v; }
  #pragma unroll
  for (int off = 32; off > 0; off >>= 1) s += __shfl_down(s, off);
  __shared__ float red[4];
  if ((threadIdx.x & 63) == 0) red[threadIdx.x >> 6] = s;
  __syncthreads();
  float tot = red[0] + red[1] + red[2] + red[3];
  float r = rsqrtf(tot * (1.f/CM) + 1e-5f);
  const float* w = nw + dir*CM;
  unsigned short* o = xn + (size_t)blk*CM;
  for (int c = threadIdx.x; c < CM; c += 256) o[c] = f2bf(xp[c] * r * w[c]);
}

// ---------------- weight casts (one dispatch, hardcoded segment map) ------
#define S_INW  4718592        // 2*3072*768
#define S_OUTW 2359296        // 2*768*1536
#define S_GATW 1179648        // 768*1536
#define S_PRJW 589824         // 768*768
#define S_XPW  245760         // 2*80*1536
#define S_DTW  196608         // 2*1536*64 (padded from 48)
#define E0 S_INW
#define E1 (E0 + S_OUTW)      // 7077888
#define E2 (E1 + S_GATW)      // 8257536
#define E3 (E2 + S_PRJW)      // 8847360
#define E4 (E3 + S_XPW)       // 9093120
#define E5 (E4 + S_DTW)       // 9289728
__global__ void multicast_k(const float* __restrict__ in_w,
    const float* __restrict__ out_w, const float* __restrict__ gate_w,
    const float* __restrict__ proj_w, const float* __restrict__ xp_w,
    const float* __restrict__ dt_w, unsigned short* __restrict__ dst)
{
  int i = blockIdx.x*256 + threadIdx.x;
  if (i >= E5) return;
  float v;
  if (i < E0)       v = in_w[i];
  else if (i < E1)  v = out_w[i - E0];
  else if (i < E2)  v = gate_w[i - E1];
  else if (i < E3)  v = proj_w[i - E2];
  else if (i < E4)  v = xp_w[i - E3];
  else {            // dt_w: pad K 48 -> 64
    int j = i - E4, r = j >> 6, c = j & 63;
    v = (c < 48) ? dt_w[r*48 + c] : 0.f;
  }
  dst[i] = f2bf(v);
}

// ---------------- bf16 MFMA GEMM: C[m,n] = sum_k A[m,k]*W[n,k] (+bias[n])
// 128x128 tile, BK=32, 4 waves (2x2), each wave 64x64 via 4x4 mfma 16x16x32.
// act==1: softplus epilogue (for dt_proj).
__global__ __launch_bounds__(256, 2) void gemm_mfma(
    const unsigned short* __restrict__ A, int lda, long long sA,
    const unsigned short* __restrict__ W, int ldw, long long sW,
    float* __restrict__ C, int ldc, long long sC,
    int M, int N, int K, const float* __restrict__ bias, long long sBias,
    int act)
{
  __shared__ short As[4*1040];
  __shared__ short Ws[4*1040];
  const int tid = threadIdx.x;
  const int z = blockIdx.z;
  A += (size_t)z * sA; W += (size_t)z * sW; C += (size_t)z * sC;
  if (bias) bias += (size_t)z * sBias;
  const int m0 = blockIdx.y*128, n0 = blockIdx.x*128;
  const int wv = tid >> 6, lane = tid & 63;
  const int wm = wv >> 1, wn = wv & 1;
  const int lm = lane & 15, g = lane >> 4;
  const s16x8 zero8 = {0,0,0,0,0,0,0,0};
  const f32x4 zero4 = {0.f,0.f,0.f,0.f};
  f32x4 acc[4][4];
  #pragma unroll
  for (int i = 0; i < 4; ++i)
    #pragma unroll
    for (int j = 0; j < 4; ++j) acc[i][j] = zero4;

  for (int k0 = 0; k0 < K; k0 += 32) {
    #pragma unroll
    for (int e = 0; e < 2; ++e) {
      int cid = tid + 256*e;
      int c = cid & 3, m = cid >> 2;
      int gm = m0 + m, gn = n0 + m;
      s16x8 va = zero8, vb = zero8;
      if (gm < M) va = *(const s16x8*)(A + (size_t)gm*lda + k0 + 8*c);
      if (gn < N) vb = *(const s16x8*)(W + (size_t)gn*ldw + k0 + 8*c);
      *(s16x8*)(&As[c*1040 + m*8]) = va;
      *(s16x8*)(&Ws[c*1040 + m*8]) = vb;
    }
    __syncthreads();
    s16x8 af[4], bf[4];
    #pragma unroll
    for (int i = 0; i < 4; ++i)
      af[i] = *(const s16x8*)(&As[g*1040 + (wm*64 + i*16 + lm)*8]);
    #pragma unroll
    for (int j = 0; j < 4; ++j)
      bf[j] = *(const s16x8*)(&Ws[g*1040 + (wn*64 + j*16 + lm)*8]);
    #pragma unroll
    for (int i = 0; i < 4; ++i)
      #pragma unroll
      for (int j = 0; j < 4; ++j)
        acc[i][j] = __builtin_amdgcn_mfma_f32_16x16x32_bf16(af[i], bf[j], acc[i][j], 0, 0, 0);
    __syncthreads();
  }
  // epilogue: C/D layout col=lane&15, row=(lane>>4)*4+reg
  #pragma unroll
  for (int i = 0; i < 4; ++i) {
    int row = m0 + wm*64 + i*16 + g*4;
    #pragma unroll
    for (int j = 0; j < 4; ++j) {
      int col = n0 + wn*64 + j*16 + lm;
      if (col >= N) continue;
      float bv = bias ? bias[col] : 0.f;
      #pragma unroll
      for (int r = 0; r < 4; ++r) {
        if (row + r >= M) continue;
        float v = acc[i][j][r] + bv;
        if (act) v = (v > 20.f) ? v : log1pf(__expf(v));
        C[(size_t)(row + r)*ldc + col] = v;
      }
    }
  }
}

// ---------------- Causal depthwise conv (k=4) + SiLU -> fp32 u + bf16 ub --
__global__ __launch_bounds__(256) void conv_silu_k(const float* __restrict__ xz,
    const float* __restrict__ cw, const float* __restrict__ cb,
    float* __restrict__ u, unsigned short* __restrict__ ub)
{
  size_t idx = (size_t)blockIdx.x*256 + threadIdx.x;
  if (idx >= (size_t)2*BLr*DI) return;
  int di  = (int)(idx % DI);
  size_t r = idx / DI;               // dir*BLr + b*LL + l
  int l   = (int)(r % LL);
  int dir = (int)(r / (BB*LL));
  size_t rowbase = r - l;
  const float* w = cw + ((size_t)dir*DI + di)*4;
  float acc = cb[dir*DI + di];
  #pragma unroll
  for (int k = 0; k < 4; ++k) {
    int lp = l - 3 + k;
    if (lp >= 0) acc = fmaf(w[k], xz[(rowbase + lp)*(2*DI) + di], acc);
  }
  float v = acc * sigmoidf_(acc);
  u[idx]  = v;
  ub[idx] = f2bf(v);
}

// ---------------- cast dt-part of xdbl (80 cols) -> bf16 padded 64 cols ---
__global__ void dtcast_k(const float* __restrict__ xdbl,
    unsigned short* __restrict__ xdbl_b)
{
  int i = blockIdx.x*256 + threadIdx.x;
  if (i >= 2*BLr*64) return;
  int r = i >> 6, c = i & 63;
  xdbl_b[i] = (c < DTR) ? f2bf(xdbl[(size_t)r*XD + c]) : (unsigned short)0;
}

// ---------------- chunked selective scan, 4 states (n-quad) per lane ------
// lane layout: tid = dl*4 + q; d = dchunk*64 + dl; states n = 4q..4q+3
// block = 256 threads = 64 d-channels; grid = 2*BB*(DI/64)*GCH = 768
// Phase A: local scan from h=0 -> carry, P = exp(Av*sum dt)
__global__ __launch_bounds__(256) void scanA_k(const float* __restrict__ dtv,
    const float* __restrict__ u, const float* __restrict__ xdbl,
    const float* __restrict__ A_log, float* __restrict__ carry,
    float* __restrict__ Pm)
{
  int bx = blockIdx.x;
  int g = bx & 7;
  int rest = bx >> 3;
  int dchunk = rest % (DI/64);
  int b   = (rest / (DI/64)) % BB;
  int dir = rest / ((DI/64)*BB);
  int tid = threadIdx.x;
  int dl = tid >> 2, q = tid & 3;
  int d = dchunk*64 + dl;
  size_t rb = ((size_t)dir*BB + b) * LL + (size_t)g*LC;
  const float* dtp = dtv + rb*DI + d;
  const float* up  = u   + rb*DI + d;
  const float* xB  = xdbl + rb*XD + DTR + 4*q;
  f32x4 al = *(const f32x4*)(A_log + ((size_t)dir*DI + d)*DS + 4*q);
  float Av[4];
  #pragma unroll
  for (int i = 0; i < 4; ++i) Av[i] = -__expf(al[i]);
  float h[4] = {0.f,0.f,0.f,0.f};
  float S = 0.f;
  float ndt = dtp[0], nu = up[0];
  f32x4 nB = *(const f32x4*)(xB);
  for (int j = 0; j < LC; ++j) {
    float cdt = ndt, cu = nu;
    f32x4 cB = nB;
    if (j + 1 < LC) {
      ndt = dtp[(size_t)(j+1)*DI];
      nu  = up[(size_t)(j+1)*DI];
      nB  = *(const f32x4*)(xB + (size_t)(j+1)*XD);
    }
    float du = cdt * cu;
    S += cdt;
    #pragma unroll
    for (int i = 0; i < 4; ++i) {
      float dA = __expf(cdt * Av[i]);
      h[i] = fmaf(dA, h[i], du * cB[i]);
    }
  }
  size_t sid = (((size_t)(dir*BB + b)*DI + d)*DS + 4*q);
  f32x4 hc = {h[0], h[1], h[2], h[3]};
  f32x4 pc = {__expf(Av[0]*S), __expf(Av[1]*S), __expf(Av[2]*S), __expf(Av[3]*S)};
  *(f32x4*)(carry + (size_t)g*NST + sid) = hc;
  *(f32x4*)(Pm    + (size_t)g*NST + sid) = pc;
}

// Phase B: sequential combine over chunks (tiny)
__global__ __launch_bounds__(256) void scanB_k(const float* __restrict__ carry,
    const float* __restrict__ Pm, float* __restrict__ h_in)
{
  int sid = blockIdx.x*256 + threadIdx.x;   // < NST
  float h = 0.f;
  #pragma unroll
  for (int g = 0; g < GCH; ++g) {
    h_in[(size_t)g*NST + sid] = h;
    h = fmaf(Pm[(size_t)g*NST + sid], h, carry[(size_t)g*NST + sid]);
  }
}

// Phase C: re-scan chunk from h_in, reduce over n (quad + 2 shfl), -> y bf16
__global__ __launch_bounds__(256) void scanC_k(const float* __restrict__ dtv,
    const float* __restrict__ u, const float* __restrict__ xz,
    const float* __restrict__ xdbl, const float* __restrict__ A_log,
    const float* __restrict__ Dp, const float* __restrict__ h_in,
    unsigned short* __restrict__ y)
{
  int bx = blockIdx.x;
  int g = bx & 7;
  int rest = bx >> 3;
  int dchunk = rest % (DI/64);
  int b   = (rest / (DI/64)) % BB;
  int dir = rest / ((DI/64)*BB);
  int tid = threadIdx.x;
  int dl = tid >> 2, q = tid & 3;
  int d = dchunk*64 + dl;
  size_t rb = ((size_t)dir*BB + b) * LL + (size_t)g*LC;
  const float* dtp = dtv + rb*DI + d;
  const float* up  = u   + rb*DI + d;
  const float* zp  = xz  + rb*(2*DI) + DI + d;
  const float* xB  = xdbl + rb*XD + DTR + 4*q;
  const float* xC  = xB + DS;
  unsigned short* yp = y + rb*DI + d;
  f32x4 al = *(const f32x4*)(A_log + ((size_t)dir*DI + d)*DS + 4*q);
  float Av[4];
  #pragma unroll
  for (int i = 0; i < 4; ++i) Av[i] = -__expf(al[i]);
  float Dd = Dp[dir*DI + d];
  size_t sid = (((size_t)(dir*BB + b)*DI + d)*DS + 4*q);
  f32x4 h4 = *(const f32x4*)(h_in + (size_t)g*NST + sid);
  float h[4] = {h4[0], h4[1], h4[2], h4[3]};
  float ndt = dtp[0], nu = up[0], nz = zp[0];
  f32x4 nB = *(const f32x4*)(xB);
  f32x4 nC = *(const f32x4*)(xC);
  for (int j = 0; j < LC; ++j) {
    float cdt = ndt, cu = nu, cz = nz;
    f32x4 cB = nB, cC = nC;
    if (j + 1 < LC) {
      ndt = dtp[(size_t)(j+1)*DI];
      nu  = up[(size_t)(j+1)*DI];
      nz  = zp[(size_t)(j+1)*(2*DI)];
      nB  = *(const f32x4*)(xB + (size_t)(j+1)*XD);
      nC  = *(const f32x4*)(xC + (size_t)(j+1)*XD);
    }
    float du = cdt * cu;
    float acc = 0.f;
    #pragma unroll
    for (int i = 0; i < 4; ++i) {
      float dA = __expf(cdt * Av[i]);
      h[i] = fmaf(dA, h[i], du * cB[i]);
      acc = fmaf(h[i], cC[i], acc);
    }
    acc += __shfl_xor(acc, 1);
    acc += __shfl_xor(acc, 2);
    if (q == 0) {
      float yv = (acc + cu * Dd) * (cz * sigmoidf_(cz));
      yp[(size_t)j*DI] = f2bf(yv);
    }
  }
}

// ---------------- residual add + flip -> f32 f, f32 b, bf16 cat ----------
__global__ void addperm_k(const float* __restrict__ x, const float* __restrict__ mo,
    float* __restrict__ out_f, float* __restrict__ out_b,
    unsigned short* __restrict__ cat)
{
  size_t idx = (size_t)blockIdx.x*256 + threadIdx.x;
  if (idx >= (size_t)BLr*CM) return;
  int c = (int)(idx % CM);
  size_t r = idx / CM;               // b*LL + l
  int l = (int)(r % LL);
  int b = (int)(r / LL);
  int t = l / NN, nn = l % NN;
  int lpos = (TT-1-t)*NN + nn;
  float xv = x[idx];
  float fv = xv + mo[idx];
  float bv = xv + mo[((size_t)BLr + (size_t)b*LL + lpos)*CM + c];
  out_f[idx] = fv;
  out_b[idx] = bv;
  cat[r*(2*CM) + c]      = f2bf(fv);
  cat[r*(2*CM) + CM + c] = f2bf(bv);
}

// ---------------- gated mix -> bf16 --------------------------------------
__global__ void mix_k(const float* __restrict__ g, const float* __restrict__ f,
    const float* __restrict__ bo, unsigned short* __restrict__ m)
{
  size_t idx = (size_t)blockIdx.x*256 + threadIdx.x;
  if (idx >= (size_t)BLr*CM) return;
  float gg = sigmoidf_(g[idx]);
  m[idx] = f2bf(gg * f[idx] + (1.f - gg) * bo[idx]);
}

extern "C" void kernel_launch(void* const* d_in, const int* in_sizes, int n_in,
                              void* d_out, int out_size, void* d_ws, size_t ws_size,
                              hipStream_t stream)
{
  (void)in_sizes; (void)n_in; (void)out_size; (void)ws_size;
  const float* x      = (const float*)d_in[0];
  const float* norm_w = (const float*)d_in[1];
  const float* in_w   = (const float*)d_in[2];
  const float* conv_w = (const float*)d_in[3];
  const float* conv_b = (const float*)d_in[4];
  const float* xp_w   = (const float*)d_in[5];
  const float* dt_w   = (const float*)d_in[6];
  const float* dt_b   = (const float*)d_in[7];
  const float* A_log  = (const float*)d_in[8];
  const float* Dp     = (const float*)d_in[9];
  const float* out_w  = (const float*)d_in[10];
  const float* gate_w = (const float*)d_in[11];
  const float* gate_b = (const float*)d_in[12];
  const float* proj_w = (const float*)d_in[13];
  const float* proj_b = (const float*)d_in[14];
  float* out = (float*)d_out;
  char* wsb  = (char*)d_ws;

  // ---- workspace layout (byte offsets; peak ~115.9 MB) ----
  unsigned short* w_all   = (unsigned short*)(wsb + 0);          // 18,579,456 B
  unsigned short* in_w_b  = w_all;
  unsigned short* out_w_b = w_all + E0;
  unsigned short* gate_w_b= w_all + E1;
  unsigned short* proj_w_b= w_all + E2;
  unsigned short* xp_w_b  = w_all + E3;
  unsigned short* dt_w_b  = w_all + E4;
  float* xz    = (float*)(wsb + 18579456);    // 2*BLr*3072 fl (38.5 MB)
  float* ubuf  = (float*)(wsb + 57114624);    // 2*BLr*1536 fl (19.3 MB)
  float* xdbl  = (float*)(wsb + 76382208);    // 2*BLr*80 fl
  float* dtvb  = (float*)(wsb + 77385728);    // 2*BLr*1536 fl (19.3 MB), post-softplus
  unsigned short* y_b = (unsigned short*)(wsb + 96653312);  // 2*BLr*1536 bf16
  unsigned short* tmp = (unsigned short*)(wsb + 106287104); // 9,633,792 B scratch
  // post-scan reuse of xz region:
  float* mo    = (float*)(wsb + 18579456);    // 2*BLr*768 fl
  float* fbuf  = (float*)(wsb + 28213248);    // BLr*768 fl
  float* bbuf  = (float*)(wsb + 33030144);    // BLr*768 fl
  unsigned short* cat_b = (unsigned short*)(wsb + 37847040); // BLr*1536 bf16
  float* gbuf  = (float*)(wsb + 42663936);    // BLr*768 fl
  unsigned short* mix_b = (unsigned short*)(wsb + 47480832); // BLr*768 bf16

  unsigned short* xn_b   = tmp;   // 2*BLr*768 bf16, live until in_proj
  unsigned short* ub     = tmp;   // 2*BLr*1536 bf16, live conv->x_proj
  unsigned short* xdbl_b = tmp;   // 2*BLr*64 bf16, live dtcast->dt_proj
  // scan-phase reuse of tmp (xdbl_b dead after dt_proj): 3 x 3,145,728 B
  float* carry = (float*)(wsb + 106287104);
  float* Pmat  = (float*)(wsb + 106287104 + 3145728);
  float* h_in  = (float*)(wsb + 106287104 + 2*3145728);

  // 1. rmsnorm (both dirs) -> bf16
  rmsnorm_k<<<2*BLr, 256, 0, stream>>>(x, norm_w, xn_b);
  // 2. weight casts
  multicast_k<<<(E5 + 255)/256, 256, 0, stream>>>(
      in_w, out_w, gate_w, proj_w, xp_w, dt_w, w_all);
  // 3. in_proj
  gemm_mfma<<<dim3(3072/128, (BLr+127)/128, 2), 256, 0, stream>>>(
      xn_b, CM, (long long)BLr*CM, in_w_b, CM, (long long)2*DI*CM,
      xz, 2*DI, (long long)BLr*2*DI, BLr, 2*DI, CM, nullptr, 0, 0);
  // 4. causal dwconv + silu -> u (fp32) + ub (bf16)
  conv_silu_k<<<(int)(((size_t)2*BLr*DI + 255)/256), 256, 0, stream>>>(
      xz, conv_w, conv_b, ubuf, ub);
  // 5. x_proj -> xdbl fp32
  gemm_mfma<<<dim3(1, (BLr+127)/128, 2), 256, 0, stream>>>(
      ub, DI, (long long)BLr*DI, xp_w_b, DI, (long long)XD*DI,
      xdbl, XD, (long long)BLr*XD, BLr, XD, DI, nullptr, 0, 0);
  // 6. cast dt cols of xdbl -> bf16 padded to 64
  dtcast_k<<<(2*BLr*64 + 255)/256, 256, 0, stream>>>(xdbl, xdbl_b);
  // 7. dt_proj + bias + SOFTPLUS fused -> dtvb
  gemm_mfma<<<dim3(DI/128, (BLr+127)/128, 2), 256, 0, stream>>>(
      xdbl_b, 64, (long long)BLr*64, dt_w_b, 64, (long long)DI*64,
      dtvb, DI, (long long)BLr*DI, BLr, DI, 64, dt_b, DI, 1);
  // 8. chunked scan: A (carries) -> B (combine) -> C (outputs)
  scanA_k<<<2*BB*(DI/64)*GCH, 256, 0, stream>>>(
      dtvb, ubuf, xdbl, A_log, carry, Pmat);
  scanB_k<<<NST/256, 256, 0, stream>>>(carry, Pmat, h_in);
  scanC_k<<<2*BB*(DI/64)*GCH, 256, 0, stream>>>(
      dtvb, ubuf, xz, xdbl, A_log, Dp, h_in, y_b);
  // 9. out_proj -> mo fp32
  gemm_mfma<<<dim3(CM/128, (BLr+127)/128, 2), 256, 0, stream>>>(
      y_b, DI, (long long)BLr*DI, out_w_b, DI, (long long)CM*DI,
      mo, CM, (long long)BLr*CM, BLr, CM, DI, nullptr, 0, 0);
  // 10. residual + flip -> f, b (fp32), cat (bf16)
  addperm_k<<<(int)(((size_t)BLr*CM + 255)/256), 256, 0, stream>>>(
      x, mo, fbuf, bbuf, cat_b);
  // 11. gate linear
  gemm_mfma<<<dim3(CM/128, (BLr+127)/128, 1), 256, 0, stream>>>(
      cat_b, 2*CM, 0, gate_w_b, 2*CM, 0,
      gbuf, CM, 0, BLr, CM, 2*CM, gate_b, 0, 0);
  // 12. sigmoid mix -> bf16
  mix_k<<<(int)(((size_t)BLr*CM + 255)/256), 256, 0, stream>>>(
      gbuf, fbuf, bbuf, mix_b);
  // 13. final proj -> d_out (fp32 + bias)
  gemm_mfma<<<dim3(CM/128, (BLr+127)/128, 1), 256, 0, stream>>>(
      mix_b, CM, 0, proj_w_b, CM, 0,
      out, CM, 0, BLr, CM, CM, proj_b, 0, 0);
}

// Round 5
// 429.487 us; speedup vs baseline: 5.3755x; 1.1833x over previous
//
#include <hip/hip_runtime.h>
#include <cstdint>
#include <cstddef>

// Problem constants (BiMambaRefinerBlock)
#define BB 2
#define TT 4
#define NN 196
#define LL (TT*NN)        // 784
#define BLr (BB*LL)       // 1568 rows per direction
#define CM 768            // d_model
#define DI 1536           // d_inner
#define DS 16             // d_state
#define DTR 48            // dt_rank
#define XD 80             // dt_rank + 2*d_state
// chunked scan
#define GCH 16
#define LC (LL/GCH)       // 49
#define NST (2*BB*DI*DS)  // 98304 states

typedef short s16x8 __attribute__((ext_vector_type(8)));
typedef float f32x4 __attribute__((ext_vector_type(4)));

static __device__ __forceinline__ float sigmoidf_(float x) {
  return 1.f / (1.f + __expf(-x));
}
// fp32 -> bf16 (RNE)
static __device__ __forceinline__ unsigned short f2bf(float f) {
  unsigned int u = __float_as_uint(f);
  unsigned int r = (u + 0x7fffu + ((u >> 16) & 1u)) >> 16;
  return (unsigned short)r;
}
// async global->LDS, 16 bytes per lane; LDS dest must be uniform + lane*16
static __device__ __forceinline__ void gload_lds16(const void* g, void* l) {
  __builtin_amdgcn_global_load_lds(
      (const __attribute__((address_space(1))) void*)g,
      (__attribute__((address_space(3))) void*)l, 16, 0, 0);
}

// ---------------- RMSNorm -> bf16 (dir1 reads flipped-t source) ----------
__global__ __launch_bounds__(256) void rmsnorm_k(const float* __restrict__ x,
    const float* __restrict__ nw, unsigned short* __restrict__ xn)
{
  int blk = blockIdx.x;               // dir*BLr + b*LL + l
  int l   = blk % LL;
  int b   = (blk / LL) % BB;
  int dir = blk / (BB*LL);
  int lsrc = l;
  if (dir == 1) { int t = l / NN, n = l % NN; lsrc = (TT-1-t)*NN + n; }
  const float* xp = x + ((size_t)b*LL + lsrc)*CM;
  float s = 0.f;
  for (int c = threadIdx.x; c < CM; c += 256) { float v = xp[c]; s += v*v; }
  #pragma unroll
  for (int off = 32; off > 0; off >>= 1) s += __shfl_down(s, off);
  __shared__ float red[4];
  if ((threadIdx.x & 63) == 0) red[threadIdx.x >> 6] = s;
  __syncthreads();
  float tot = red[0] + red[1] + red[2] + red[3];
  float r = rsqrtf(tot * (1.f/CM) + 1e-5f);
  const float* w = nw + dir*CM;
  unsigned short* o = xn + (size_t)blk*CM;
  for (int c = threadIdx.x; c < CM; c += 256) o[c] = f2bf(xp[c] * r * w[c]);
}

// ---------------- weight casts (one dispatch, hardcoded segment map) ------
#define S_INW  4718592        // 2*3072*768
#define S_OUTW 2359296        // 2*768*1536
#define S_GATW 1179648        // 768*1536
#define S_PRJW 589824         // 768*768
#define S_XPW  245760         // 2*80*1536
#define S_DTW  196608         // 2*1536*64 (padded from 48)
#define E0 S_INW
#define E1 (E0 + S_OUTW)      // 7077888
#define E2 (E1 + S_GATW)      // 8257536
#define E3 (E2 + S_PRJW)      // 8847360
#define E4 (E3 + S_XPW)       // 9093120
#define E5 (E4 + S_DTW)       // 9289728
__global__ void multicast_k(const float* __restrict__ in_w,
    const float* __restrict__ out_w, const float* __restrict__ gate_w,
    const float* __restrict__ proj_w, const float* __restrict__ xp_w,
    const float* __restrict__ dt_w, unsigned short* __restrict__ dst)
{
  int i = blockIdx.x*256 + threadIdx.x;
  if (i >= E5) return;
  float v;
  if (i < E0)       v = in_w[i];
  else if (i < E1)  v = out_w[i - E0];
  else if (i < E2)  v = gate_w[i - E1];
  else if (i < E3)  v = proj_w[i - E2];
  else if (i < E4)  v = xp_w[i - E3];
  else {            // dt_w: pad K 48 -> 64
    int j = i - E4, r = j >> 6, c = j & 63;
    v = (c < 48) ? dt_w[r*48 + c] : 0.f;
  }
  dst[i] = f2bf(v);
}

// ---------------- bf16 MFMA GEMM: C[m,n] = sum_k A[m,k]*W[n,k] (+bias[n])
// 128m x BNn tile, BK=32, 4 waves. BN=128: 2x2 waves of 64x64. BN=64:
// 4x1 waves of 32x64. LDS slab layout [kgroup][row][8 bf16]; staged via
// global_load_lds width 16 (DMA, no VGPR round-trip). M-tail rows clamp
// the load address (duplicate row), epilogue masks the store.
// act==1: softplus epilogue (dt_proj).
template <int BN>
__global__ __launch_bounds__(256, 2) void gemm_mfma(
    const unsigned short* __restrict__ A, int lda, long long sA,
    const unsigned short* __restrict__ W, int ldw, long long sW,
    float* __restrict__ C, int ldc, long long sC,
    int M, int N, int K, const float* __restrict__ bias, long long sBias,
    int act)
{
  constexpr int MT = (BN == 128) ? 4 : 2;      // m mfma tiles per wave
  __shared__ short As[4*1024];
  __shared__ short Ws[4*BN*8];
  const int tid = threadIdx.x;
  const int z = blockIdx.z;
  A += (size_t)z * sA; W += (size_t)z * sW; C += (size_t)z * sC;
  if (bias) bias += (size_t)z * sBias;
  const int m0 = blockIdx.y*128, n0 = blockIdx.x*BN;
  const int wv = tid >> 6, lane = tid & 63;
  const int wm0 = (BN == 128) ? (wv >> 1)*64 : wv*32;   // wave m-origin
  const int wn  = (BN == 128) ? (wv & 1) : 0;           // wave n-half
  const int lm = lane & 15, g = lane >> 4;
  const int sc = tid >> 6, sr = tid & 63;   // staging: slab, row-in-64
  const f32x4 zero4 = {0.f,0.f,0.f,0.f};
  f32x4 acc[MT][4];
  #pragma unroll
  for (int i = 0; i < MT; ++i)
    #pragma unroll
    for (int j = 0; j < 4; ++j) acc[i][j] = zero4;

  for (int k0 = 0; k0 < K; k0 += 32) {
    // stage A: 128 rows x 32k as 4 slabs [k-group][row][8]
    #pragma unroll
    for (int e = 0; e < 2; ++e) {
      int m = 64*e + sr;
      int gm = m0 + m; if (gm >= M) gm = M - 1;
      gload_lds16(A + (size_t)gm*lda + k0 + 8*sc, &As[sc*1024 + m*8]);
    }
    // stage W: BN rows x 32k
    #pragma unroll
    for (int e = 0; e < BN/64; ++e) {
      int m = 64*e + sr;
      int gn = n0 + m; if (gn >= N) gn = N - 1;
      gload_lds16(W + (size_t)gn*ldw + k0 + 8*sc, &Ws[sc*(BN*8) + m*8]);
    }
    __syncthreads();
    s16x8 af[MT], bf[4];
    #pragma unroll
    for (int i = 0; i < MT; ++i)
      af[i] = *(const s16x8*)(&As[g*1024 + (wm0 + i*16 + lm)*8]);
    #pragma unroll
    for (int j = 0; j < 4; ++j)
      bf[j] = *(const s16x8*)(&Ws[g*(BN*8) + (wn*64 + j*16 + lm)*8]);
    #pragma unroll
    for (int i = 0; i < MT; ++i)
      #pragma unroll
      for (int j = 0; j < 4; ++j)
        acc[i][j] = __builtin_amdgcn_mfma_f32_16x16x32_bf16(af[i], bf[j], acc[i][j], 0, 0, 0);
    __syncthreads();
  }
  // epilogue: C/D layout col=lane&15, row=(lane>>4)*4+reg
  #pragma unroll
  for (int i = 0; i < MT; ++i) {
    int row = m0 + wm0 + i*16 + g*4;
    #pragma unroll
    for (int j = 0; j < 4; ++j) {
      int col = n0 + wn*64 + j*16 + lm;
      if (col >= N) continue;
      float bv = bias ? bias[col] : 0.f;
      #pragma unroll
      for (int r = 0; r < 4; ++r) {
        if (row + r >= M) continue;
        float v = acc[i][j][r] + bv;
        if (act) v = (v > 20.f) ? v : log1pf(__expf(v));
        C[(size_t)(row + r)*ldc + col] = v;
      }
    }
  }
}

// ---------------- x_proj split-K GEMM: partials over 8 K-segments ---------
// grid (8 ksplit, 13 mtiles, 2 dirs); N=80 (staged in a 128-wide tile).
__global__ __launch_bounds__(256, 2) void gemm_xproj(
    const unsigned short* __restrict__ ub, const unsigned short* __restrict__ xpw,
    float* __restrict__ part)
{
  __shared__ short As[4*1024];
  __shared__ short Ws[4*1024];
  const int tid = threadIdx.x;
  const int ks = blockIdx.x, mt = blockIdx.y, dir = blockIdx.z;
  const unsigned short* A = ub + (size_t)dir*BLr*DI;
  const unsigned short* W = xpw + (size_t)dir*XD*DI;
  const int m0 = mt*128, kb = ks*(DI/8);
  const int wv = tid >> 6, lane = tid & 63;
  const int wm0 = (wv >> 1)*64, wn = wv & 1;
  const int lm = lane & 15, g = lane >> 4;
  const int sc = tid >> 6, sr = tid & 63;
  const f32x4 zero4 = {0.f,0.f,0.f,0.f};
  f32x4 acc[4][4];
  #pragma unroll
  for (int i = 0; i < 4; ++i)
    #pragma unroll
    for (int j = 0; j < 4; ++j) acc[i][j] = zero4;

  for (int k0 = kb; k0 < kb + DI/8; k0 += 32) {
    #pragma unroll
    for (int e = 0; e < 2; ++e) {
      int m = 64*e + sr;
      int gm = m0 + m; if (gm >= BLr) gm = BLr - 1;
      int gn = m; if (gn >= XD) gn = XD - 1;
      gload_lds16(A + (size_t)gm*DI + k0 + 8*sc, &As[sc*1024 + m*8]);
      gload_lds16(W + (size_t)gn*DI + k0 + 8*sc, &Ws[sc*1024 + m*8]);
    }
    __syncthreads();
    s16x8 af[4], bf[4];
    #pragma unroll
    for (int i = 0; i < 4; ++i)
      af[i] = *(const s16x8*)(&As[g*1024 + (wm0 + i*16 + lm)*8]);
    #pragma unroll
    for (int j = 0; j < 4; ++j)
      bf[j] = *(const s16x8*)(&Ws[g*1024 + (wn*64 + j*16 + lm)*8]);
    #pragma unroll
    for (int i = 0; i < 4; ++i)
      #pragma unroll
      for (int j = 0; j < 4; ++j)
        acc[i][j] = __builtin_amdgcn_mfma_f32_16x16x32_bf16(af[i], bf[j], acc[i][j], 0, 0, 0);
    __syncthreads();
  }
  float* P = part + ((size_t)(dir*8 + ks)*BLr)*XD;
  #pragma unroll
  for (int i = 0; i < 4; ++i) {
    int row = m0 + wm0 + i*16 + g*4;
    #pragma unroll
    for (int j = 0; j < 4; ++j) {
      int col = wn*64 + j*16 + lm;
      if (col >= XD) continue;
      #pragma unroll
      for (int r = 0; r < 4; ++r)
        if (row + r < BLr) P[(size_t)(row + r)*XD + col] = acc[i][j][r];
    }
  }
}

// ---------------- reduce x_proj partials -> xdbl fp32 + dt cols bf16 ------
__global__ void xreduce_k(const float* __restrict__ part,
    float* __restrict__ xdbl, unsigned short* __restrict__ xdbl_b)
{
  int i = blockIdx.x*256 + threadIdx.x;     // over 2*BLr*80
  if (i >= 2*BLr*XD) return;
  int c = i % XD;
  int r = i / XD;                            // dir*BLr + row
  int dir = r / BLr, row = r % BLr;
  float s = 0.f;
  #pragma unroll
  for (int ks = 0; ks < 8; ++ks)
    s += part[((size_t)(dir*8 + ks)*BLr + row)*XD + c];
  xdbl[(size_t)r*XD + c] = s;
  if (c < DTR)      xdbl_b[(size_t)r*64 + c] = f2bf(s);
  else if (c < 64)  xdbl_b[(size_t)r*64 + c] = 0;
}

// ---------------- Causal depthwise conv (k=4) + SiLU -> fp32 u + bf16 ub --
__global__ __launch_bounds__(256) void conv_silu_k(const float* __restrict__ xz,
    const float* __restrict__ cw, const float* __restrict__ cb,
    float* __restrict__ u, unsigned short* __restrict__ ub)
{
  size_t idx = (size_t)blockIdx.x*256 + threadIdx.x;
  if (idx >= (size_t)2*BLr*DI) return;
  int di  = (int)(idx % DI);
  size_t r = idx / DI;               // dir*BLr + b*LL + l
  int l   = (int)(r % LL);
  int dir = (int)(r / (BB*LL));
  size_t rowbase = r - l;
  const float* w = cw + ((size_t)dir*DI + di)*4;
  float acc = cb[dir*DI + di];
  #pragma unroll
  for (int k = 0; k < 4; ++k) {
    int lp = l - 3 + k;
    if (lp >= 0) acc = fmaf(w[k], xz[(rowbase + lp)*(2*DI) + di], acc);
  }
  float v = acc * sigmoidf_(acc);
  u[idx]  = v;
  ub[idx] = f2bf(v);
}

// ---------------- chunked selective scan, 4 states (n-quad) per lane ------
// lane layout: tid = dl*4 + q; d = dchunk*64 + dl; states n = 4q..4q+3
// grid = 2*BB*(DI/64)*GCH = 1536 blocks; prefetch depth 2.
__global__ __launch_bounds__(256) void scanA_k(const float* __restrict__ dtv,
    const float* __restrict__ u, const float* __restrict__ xdbl,
    const float* __restrict__ A_log, float* __restrict__ carry,
    float* __restrict__ Pm)
{
  int bx = blockIdx.x;
  int g = bx & (GCH-1);
  int rest = bx / GCH;
  int dchunk = rest % (DI/64);
  int b   = (rest / (DI/64)) % BB;
  int dir = rest / ((DI/64)*BB);
  int tid = threadIdx.x;
  int dl = tid >> 2, q = tid & 3;
  int d = dchunk*64 + dl;
  size_t rb = ((size_t)dir*BB + b) * LL + (size_t)g*LC;
  const float* dtp = dtv + rb*DI + d;
  const float* up  = u   + rb*DI + d;
  const float* xB  = xdbl + rb*XD + DTR + 4*q;
  f32x4 al = *(const f32x4*)(A_log + ((size_t)dir*DI + d)*DS + 4*q);
  float Av[4];
  #pragma unroll
  for (int i = 0; i < 4; ++i) Av[i] = -__expf(al[i]);
  float h[4] = {0.f,0.f,0.f,0.f};
  float S = 0.f;
  float ndt[2], nu[2]; f32x4 nB[2];
  #pragma unroll
  for (int e = 0; e < 2; ++e) {
    ndt[e] = dtp[(size_t)e*DI];
    nu[e]  = up[(size_t)e*DI];
    nB[e]  = *(const f32x4*)(xB + (size_t)e*XD);
  }
  #pragma unroll 2
  for (int j = 0; j < LC; ++j) {
    int s = j & 1;
    float cdt = ndt[s], cu = nu[s];
    f32x4 cB = nB[s];
    int lp = j + 2;
    if (lp < LC) {
      ndt[s] = dtp[(size_t)lp*DI];
      nu[s]  = up[(size_t)lp*DI];
      nB[s]  = *(const f32x4*)(xB + (size_t)lp*XD);
    }
    float du = cdt * cu;
    S += cdt;
    #pragma unroll
    for (int i = 0; i < 4; ++i) {
      float dA = __expf(cdt * Av[i]);
      h[i] = fmaf(dA, h[i], du * cB[i]);
    }
  }
  size_t sid = (((size_t)(dir*BB + b)*DI + d)*DS + 4*q);
  f32x4 hc = {h[0], h[1], h[2], h[3]};
  f32x4 pc = {__expf(Av[0]*S), __expf(Av[1]*S), __expf(Av[2]*S), __expf(Av[3]*S)};
  *(f32x4*)(carry + (size_t)g*NST + sid) = hc;
  *(f32x4*)(Pm    + (size_t)g*NST + sid) = pc;
}

// Phase B: sequential combine over chunks; h_in overwrites carry in place.
__global__ __launch_bounds__(256) void scanB_k(float* __restrict__ carry,
    const float* __restrict__ Pm)
{
  int sid = blockIdx.x*256 + threadIdx.x;   // < NST
  float h = 0.f;
  #pragma unroll
  for (int g = 0; g < GCH; ++g) {
    float c = carry[(size_t)g*NST + sid];
    float p = Pm[(size_t)g*NST + sid];
    carry[(size_t)g*NST + sid] = h;         // h_in
    h = fmaf(p, h, c);
  }
}

// Phase C: re-scan chunk from h_in (in carry), reduce over n, -> y bf16
__global__ __launch_bounds__(256) void scanC_k(const float* __restrict__ dtv,
    const float* __restrict__ u, const float* __restrict__ xz,
    const float* __restrict__ xdbl, const float* __restrict__ A_log,
    const float* __restrict__ Dp, const float* __restrict__ h_in,
    unsigned short* __restrict__ y)
{
  int bx = blockIdx.x;
  int g = bx & (GCH-1);
  int rest = bx / GCH;
  int dchunk = rest % (DI/64);
  int b   = (rest / (DI/64)) % BB;
  int dir = rest / ((DI/64)*BB);
  int tid = threadIdx.x;
  int dl = tid >> 2, q = tid & 3;
  int d = dchunk*64 + dl;
  size_t rb = ((size_t)dir*BB + b) * LL + (size_t)g*LC;
  const float* dtp = dtv + rb*DI + d;
  const float* up  = u   + rb*DI + d;
  const float* zp  = xz  + rb*(2*DI) + DI + d;
  const float* xB  = xdbl + rb*XD + DTR + 4*q;
  const float* xC  = xB + DS;
  unsigned short* yp = y + rb*DI + d;
  f32x4 al = *(const f32x4*)(A_log + ((size_t)dir*DI + d)*DS + 4*q);
  float Av[4];
  #pragma unroll
  for (int i = 0; i < 4; ++i) Av[i] = -__expf(al[i]);
  float Dd = Dp[dir*DI + d];
  size_t sid = (((size_t)(dir*BB + b)*DI + d)*DS + 4*q);
  f32x4 h4 = *(const f32x4*)(h_in + (size_t)g*NST + sid);
  float h[4] = {h4[0], h4[1], h4[2], h4[3]};
  float ndt[2], nu[2], nz[2]; f32x4 nB[2], nC[2];
  #pragma unroll
  for (int e = 0; e < 2; ++e) {
    ndt[e] = dtp[(size_t)e*DI];
    nu[e]  = up[(size_t)e*DI];
    nz[e]  = zp[(size_t)e*(2*DI)];
    nB[e]  = *(const f32x4*)(xB + (size_t)e*XD);
    nC[e]  = *(const f32x4*)(xC + (size_t)e*XD);
  }
  #pragma unroll 2
  for (int j = 0; j < LC; ++j) {
    int s = j & 1;
    float cdt = ndt[s], cu = nu[s], cz = nz[s];
    f32x4 cB = nB[s], cC = nC[s];
    int lp = j + 2;
    if (lp < LC) {
      ndt[s] = dtp[(size_t)lp*DI];
      nu[s]  = up[(size_t)lp*DI];
      nz[s]  = zp[(size_t)lp*(2*DI)];
      nB[s]  = *(const f32x4*)(xB + (size_t)lp*XD);
      nC[s]  = *(const f32x4*)(xC + (size_t)lp*XD);
    }
    float du = cdt * cu;
    float acc = 0.f;
    #pragma unroll
    for (int i = 0; i < 4; ++i) {
      float dA = __expf(cdt * Av[i]);
      h[i] = fmaf(dA, h[i], du * cB[i]);
      acc = fmaf(h[i], cC[i], acc);
    }
    acc += __shfl_xor(acc, 1);
    acc += __shfl_xor(acc, 2);
    if (q == 0) {
      float yv = (acc + cu * Dd) * (cz * sigmoidf_(cz));
      yp[(size_t)j*DI] = f2bf(yv);
    }
  }
}

// ---------------- residual add + flip -> f32 f, f32 b, bf16 cat ----------
__global__ void addperm_k(const float* __restrict__ x, const float* __restrict__ mo,
    float* __restrict__ out_f, float* __restrict__ out_b,
    unsigned short* __restrict__ cat)
{
  size_t idx = (size_t)blockIdx.x*256 + threadIdx.x;
  if (idx >= (size_t)BLr*CM) return;
  int c = (int)(idx % CM);
  size_t r = idx / CM;               // b*LL + l
  int l = (int)(r % LL);
  int b = (int)(r / LL);
  int t = l / NN, nn = l % NN;
  int lpos = (TT-1-t)*NN + nn;
  float xv = x[idx];
  float fv = xv + mo[idx];
  float bv = xv + mo[((size_t)BLr + (size_t)b*LL + lpos)*CM + c];
  out_f[idx] = fv;
  out_b[idx] = bv;
  cat[r*(2*CM) + c]      = f2bf(fv);
  cat[r*(2*CM) + CM + c] = f2bf(bv);
}

// ---------------- gated mix -> bf16 --------------------------------------
__global__ void mix_k(const float* __restrict__ g, const float* __restrict__ f,
    const float* __restrict__ bo, unsigned short* __restrict__ m)
{
  size_t idx = (size_t)blockIdx.x*256 + threadIdx.x;
  if (idx >= (size_t)BLr*CM) return;
  float gg = sigmoidf_(g[idx]);
  m[idx] = f2bf(gg * f[idx] + (1.f - gg) * bo[idx]);
}

extern "C" void kernel_launch(void* const* d_in, const int* in_sizes, int n_in,
                              void* d_out, int out_size, void* d_ws, size_t ws_size,
                              hipStream_t stream)
{
  (void)in_sizes; (void)n_in; (void)out_size; (void)ws_size;
  const float* x      = (const float*)d_in[0];
  const float* norm_w = (const float*)d_in[1];
  const float* in_w   = (const float*)d_in[2];
  const float* conv_w = (const float*)d_in[3];
  const float* conv_b = (const float*)d_in[4];
  const float* xp_w   = (const float*)d_in[5];
  const float* dt_w   = (const float*)d_in[6];
  const float* dt_b   = (const float*)d_in[7];
  const float* A_log  = (const float*)d_in[8];
  const float* Dp     = (const float*)d_in[9];
  const float* out_w  = (const float*)d_in[10];
  const float* gate_w = (const float*)d_in[11];
  const float* gate_b = (const float*)d_in[12];
  const float* proj_w = (const float*)d_in[13];
  const float* proj_b = (const float*)d_in[14];
  float* out = (float*)d_out;
  char* wsb  = (char*)d_ws;

  // ---- workspace layout (byte offsets; peak ~115.9 MB, unchanged) ----
  unsigned short* w_all   = (unsigned short*)(wsb + 0);          // 18,579,456 B
  unsigned short* in_w_b  = w_all;          // dead after in_proj
  unsigned short* out_w_b = w_all + E0;
  unsigned short* gate_w_b= w_all + E1;
  unsigned short* proj_w_b= w_all + E2;
  unsigned short* xp_w_b  = w_all + E3;
  unsigned short* dt_w_b  = w_all + E4;
  float* xz    = (float*)(wsb + 18579456);    // 2*BLr*3072 fl (38.5 MB)
  float* ubuf  = (float*)(wsb + 57114624);    // 2*BLr*1536 fl (19.3 MB)
  float* xdbl  = (float*)(wsb + 76382208);    // 2*BLr*80 fl
  float* dtvb  = (float*)(wsb + 77385728);    // 2*BLr*1536 fl, post-softplus
  unsigned short* y_b = (unsigned short*)(wsb + 96653312);  // 2*BLr*1536 bf16
  unsigned short* tmp = (unsigned short*)(wsb + 106287104); // 9,633,792 B scratch
  // post-scan reuse of xz region:
  float* mo    = (float*)(wsb + 18579456);    // 2*BLr*768 fl
  float* fbuf  = (float*)(wsb + 28213248);    // BLr*768 fl
  float* bbuf  = (float*)(wsb + 33030144);    // BLr*768 fl
  unsigned short* cat_b = (unsigned short*)(wsb + 37847040); // BLr*1536 bf16
  float* gbuf  = (float*)(wsb + 42663936);    // BLr*768 fl
  unsigned short* mix_b = (unsigned short*)(wsb + 47480832); // BLr*768 bf16

  unsigned short* xn_b   = tmp;   // 2*BLr*768 bf16, live until in_proj
  unsigned short* ub     = tmp;   // 2*BLr*1536 bf16, live conv->x_proj
  unsigned short* xdbl_b = tmp;   // 2*BLr*64 bf16, live xreduce->dt_proj
  // in_w_b region reuse after in_proj:
  float* part  = (float*)(wsb + 0);            // 2*8*BLr*80 fl = 8.03 MB
  float* carry = (float*)(wsb + 0);            // GCH*NST fl = 6.29 MB (after xreduce)
  float* Pmat  = (float*)(wsb + 106287104 + 1048576);  // 6.29 MB in tmp tail

  // 1. rmsnorm (both dirs) -> bf16
  rmsnorm_k<<<2*BLr, 256, 0, stream>>>(x, norm_w, xn_b);
  // 2. weight casts
  multicast_k<<<(E5 + 255)/256, 256, 0, stream>>>(
      in_w, out_w, gate_w, proj_w, xp_w, dt_w, w_all);
  // 3. in_proj: (BLr,768)x(3072,768)^T -> xz
  gemm_mfma<128><<<dim3(3072/128, (BLr+127)/128, 2), 256, 0, stream>>>(
      xn_b, CM, (long long)BLr*CM, in_w_b, CM, (long long)2*DI*CM,
      xz, 2*DI, (long long)BLr*2*DI, BLr, 2*DI, CM, nullptr, 0, 0);
  // 4. causal dwconv + silu -> u (fp32) + ub (bf16)
  conv_silu_k<<<(int)(((size_t)2*BLr*DI + 255)/256), 256, 0, stream>>>(
      xz, conv_w, conv_b, ubuf, ub);
  // 5. x_proj split-K (8 x 13 x 2 = 208 blocks) -> partials
  gemm_xproj<<<dim3(8, (BLr+127)/128, 2), 256, 0, stream>>>(ub, xp_w_b, part);
  // 6. reduce partials -> xdbl fp32 + xdbl_b bf16 (dt cols, padded 64)
  xreduce_k<<<(2*BLr*XD + 255)/256, 256, 0, stream>>>(part, xdbl, xdbl_b);
  // 7. dt_proj + bias + softplus -> dtvb
  gemm_mfma<128><<<dim3(DI/128, (BLr+127)/128, 2), 256, 0, stream>>>(
      xdbl_b, 64, (long long)BLr*64, dt_w_b, 64, (long long)DI*64,
      dtvb, DI, (long long)BLr*DI, BLr, DI, 64, dt_b, DI, 1);
  // 8. chunked scan: A (carries) -> B (combine, in place) -> C (outputs)
  scanA_k<<<2*BB*(DI/64)*GCH, 256, 0, stream>>>(
      dtvb, ubuf, xdbl, A_log, carry, Pmat);
  scanB_k<<<NST/256, 256, 0, stream>>>(carry, Pmat);
  scanC_k<<<2*BB*(DI/64)*GCH, 256, 0, stream>>>(
      dtvb, ubuf, xz, xdbl, A_log, Dp, carry, y_b);
  // 9. out_proj: (BLr,1536)x(768,1536)^T -> mo (BN=64: 312 blocks)
  gemm_mfma<64><<<dim3(CM/64, (BLr+127)/128, 2), 256, 0, stream>>>(
      y_b, DI, (long long)BLr*DI, out_w_b, DI, (long long)CM*DI,
      mo, CM, (long long)BLr*CM, BLr, CM, DI, nullptr, 0, 0);
  // 10. residual + flip -> f, b (fp32), cat (bf16)
  addperm_k<<<(int)(((size_t)BLr*CM + 255)/256), 256, 0, stream>>>(
      x, mo, fbuf, bbuf, cat_b);
  // 11. gate linear (BN=64: 156 blocks)
  gemm_mfma<64><<<dim3(CM/64, (BLr+127)/128, 1), 256, 0, stream>>>(
      cat_b, 2*CM, 0, gate_w_b, 2*CM, 0,
      gbuf, CM, 0, BLr, CM, 2*CM, gate_b, 0, 0);
  // 12. sigmoid mix -> bf16
  mix_k<<<(int)(((size_t)BLr*CM + 255)/256), 256, 0, stream>>>(
      gbuf, fbuf, bbuf, mix_b);
  // 13. final proj -> d_out (fp32 + bias)
  gemm_mfma<64><<<dim3(CM/64, (BLr+127)/128, 1), 256, 0, stream>>>(
      mix_b, CM, 0, proj_w_b, CM, 0,
      out, CM, 0, BLr, CM, CM, proj_b, 0, 0);
}

// Round 6
// 392.542 us; speedup vs baseline: 5.8814x; 1.0941x over previous
//
#include <hip/hip_runtime.h>
#include <cstdint>
#include <cstddef>

// Problem constants (BiMambaRefinerBlock)
#define BB 2
#define TT 4
#define NN 196
#define LL (TT*NN)        // 784
#define BLr (BB*LL)       // 1568 rows per direction
#define CM 768            // d_model
#define DI 1536           // d_inner
#define DS 16             // d_state
#define DTR 48            // dt_rank
#define XD 80             // dt_rank + 2*d_state
// chunked scan
#define GCH 16
#define LC (LL/GCH)       // 49
#define NST (2*BB*DI*DS)  // 98304 states

typedef short s16x8 __attribute__((ext_vector_type(8)));
typedef float f32x4 __attribute__((ext_vector_type(4)));

static __device__ __forceinline__ float sigmoidf_(float x) {
  return 1.f / (1.f + __expf(-x));
}
// fp32 -> bf16 (RNE)
static __device__ __forceinline__ unsigned short f2bf(float f) {
  unsigned int u = __float_as_uint(f);
  unsigned int r = (u + 0x7fffu + ((u >> 16) & 1u)) >> 16;
  return (unsigned short)r;
}
static __device__ __forceinline__ float bf2f(unsigned short u) {
  return __uint_as_float(((unsigned int)u) << 16);
}
// async global->LDS, 16 bytes per lane; LDS dest must be uniform + lane*16
static __device__ __forceinline__ void gload_lds16(const void* g, void* l) {
  __builtin_amdgcn_global_load_lds(
      (const __attribute__((address_space(1))) void*)g,
      (__attribute__((address_space(3))) void*)l, 16, 0, 0);
}

// ---------------- RMSNorm -> bf16 (dir1 reads flipped-t source) ----------
__global__ __launch_bounds__(256) void rmsnorm_k(const float* __restrict__ x,
    const float* __restrict__ nw, unsigned short* __restrict__ xn)
{
  int blk = blockIdx.x;               // dir*BLr + b*LL + l
  int l   = blk % LL;
  int b   = (blk / LL) % BB;
  int dir = blk / (BB*LL);
  int lsrc = l;
  if (dir == 1) { int t = l / NN, n = l % NN; lsrc = (TT-1-t)*NN + n; }
  const float* xp = x + ((size_t)b*LL + lsrc)*CM;
  float s = 0.f;
  for (int c = threadIdx.x; c < CM; c += 256) { float v = xp[c]; s += v*v; }
  #pragma unroll
  for (int off = 32; off > 0; off >>= 1) s += __shfl_down(s, off);
  __shared__ float red[4];
  if ((threadIdx.x & 63) == 0) red[threadIdx.x >> 6] = s;
  __syncthreads();
  float tot = red[0] + red[1] + red[2] + red[3];
  float r = rsqrtf(tot * (1.f/CM) + 1e-5f);
  const float* w = nw + dir*CM;
  unsigned short* o = xn + (size_t)blk*CM;
  for (int c = threadIdx.x; c < CM; c += 256) o[c] = f2bf(xp[c] * r * w[c]);
}

// ---------------- weight casts (one dispatch, hardcoded segment map) ------
#define S_INW  4718592        // 2*3072*768
#define S_OUTW 2359296        // 2*768*1536
#define S_GATW 1179648        // 768*1536
#define S_PRJW 589824         // 768*768
#define S_XPW  245760         // 2*80*1536
#define S_DTW  196608         // 2*1536*64 (padded from 48)
#define E0 S_INW
#define E1 (E0 + S_OUTW)      // 7077888
#define E2 (E1 + S_GATW)      // 8257536
#define E3 (E2 + S_PRJW)      // 8847360
#define E4 (E3 + S_XPW)       // 9093120
#define E5 (E4 + S_DTW)       // 9289728
__global__ void multicast_k(const float* __restrict__ in_w,
    const float* __restrict__ out_w, const float* __restrict__ gate_w,
    const float* __restrict__ proj_w, const float* __restrict__ xp_w,
    const float* __restrict__ dt_w, unsigned short* __restrict__ dst)
{
  int i = blockIdx.x*256 + threadIdx.x;
  if (i >= E5) return;
  float v;
  if (i < E0)       v = in_w[i];
  else if (i < E1)  v = out_w[i - E0];
  else if (i < E2)  v = gate_w[i - E1];
  else if (i < E3)  v = proj_w[i - E2];
  else if (i < E4)  v = xp_w[i - E3];
  else {            // dt_w: pad K 48 -> 64
    int j = i - E4, r = j >> 6, c = j & 63;
    v = (c < 48) ? dt_w[r*48 + c] : 0.f;
  }
  dst[i] = f2bf(v);
}

// ---------------- shared MFMA GEMM core: BM x BN tile, BK=32, 4 waves ----
// wave tile (BM/2)x(BN/2); LDS slab layout [kgroup][row][8 bf16]; staged
// via global_load_lds width 16. M/N-tail rows clamp the load address.
template <int BM, int BN>
__device__ __forceinline__ void gemm_core(
    const unsigned short* __restrict__ A, int lda,
    const unsigned short* __restrict__ W, int ldw,
    int M, int N, int K, int m0, int n0,
    short* As, short* Ws, f32x4 (*acc)[BN/32])
{
  const int tid = threadIdx.x;
  const int wv = tid >> 6, lane = tid & 63;
  const int wm0 = (wv >> 1)*(BM/2), wn0 = (wv & 1)*(BN/2);
  const int lm = lane & 15, g = lane >> 4;
  const int sc = tid >> 6, sr = tid & 63;
  constexpr int MT = BM/32, NT = BN/32;
  for (int k0 = 0; k0 < K; k0 += 32) {
    #pragma unroll
    for (int e = 0; e < BM/64; ++e) {
      int m = 64*e + sr;
      int gm = m0 + m; if (gm >= M) gm = M - 1;
      gload_lds16(A + (size_t)gm*lda + k0 + 8*sc, &As[sc*(BM*8) + m*8]);
    }
    #pragma unroll
    for (int e = 0; e < BN/64; ++e) {
      int n = 64*e + sr;
      int gn = n0 + n; if (gn >= N) gn = N - 1;
      gload_lds16(W + (size_t)gn*ldw + k0 + 8*sc, &Ws[sc*(BN*8) + n*8]);
    }
    __syncthreads();
    s16x8 af[MT], bf[NT];
    #pragma unroll
    for (int i = 0; i < MT; ++i)
      af[i] = *(const s16x8*)(&As[g*(BM*8) + (wm0 + i*16 + lm)*8]);
    #pragma unroll
    for (int j = 0; j < NT; ++j)
      bf[j] = *(const s16x8*)(&Ws[g*(BN*8) + (wn0 + j*16 + lm)*8]);
    #pragma unroll
    for (int i = 0; i < MT; ++i)
      #pragma unroll
      for (int j = 0; j < NT; ++j)
        acc[i][j] = __builtin_amdgcn_mfma_f32_16x16x32_bf16(af[i], bf[j], acc[i][j], 0, 0, 0);
    __syncthreads();
  }
}

// ---------------- in_proj: (BLr,768)x(3072,768)^T -> xz bf16 -------------
__global__ __launch_bounds__(256, 4) void gemm_in_k(
    const unsigned short* __restrict__ xn, const unsigned short* __restrict__ w,
    unsigned short* __restrict__ xzout)
{
  __shared__ short As[4*64*8];
  __shared__ short Ws[4*128*8];
  const int dir = blockIdx.z;
  const unsigned short* A = xn + (size_t)dir*BLr*CM;
  const unsigned short* W = w  + (size_t)dir*2*DI*CM;
  unsigned short* C = xzout + (size_t)dir*BLr*2*DI;
  const int m0 = blockIdx.y*64, n0 = blockIdx.x*128;
  f32x4 acc[2][4];
  #pragma unroll
  for (int i = 0; i < 2; ++i)
    #pragma unroll
    for (int j = 0; j < 4; ++j) acc[i][j] = (f32x4){0.f,0.f,0.f,0.f};
  gemm_core<64,128>(A, CM, W, CM, BLr, 2*DI, CM, m0, n0, As, Ws, acc);
  const int tid = threadIdx.x, wv = tid >> 6, lane = tid & 63;
  const int wm0 = (wv >> 1)*32, wn0 = (wv & 1)*64;
  const int lm = lane & 15, g = lane >> 4;
  #pragma unroll
  for (int i = 0; i < 2; ++i) {
    int row = m0 + wm0 + i*16 + g*4;
    #pragma unroll
    for (int j = 0; j < 4; ++j) {
      int col = n0 + wn0 + j*16 + lm;
      #pragma unroll
      for (int r = 0; r < 4; ++r)
        if (row + r < BLr) C[(size_t)(row + r)*2*DI + col] = f2bf(acc[i][j][r]);
    }
  }
}

// ---------------- dt_proj: (BLr,64)x(1536,64)^T + bias + softplus --------
__global__ __launch_bounds__(256, 4) void gemm_dt_k(
    const unsigned short* __restrict__ xdblb, const unsigned short* __restrict__ w,
    const float* __restrict__ dtb, float* __restrict__ dtv)
{
  __shared__ short As[4*64*8];
  __shared__ short Ws[4*128*8];
  const int dir = blockIdx.z;
  const unsigned short* A = xdblb + (size_t)dir*BLr*64;
  const unsigned short* W = w + (size_t)dir*DI*64;
  float* C = dtv + (size_t)dir*BLr*DI;
  const float* bias = dtb + (size_t)dir*DI;
  const int m0 = blockIdx.y*64, n0 = blockIdx.x*128;
  f32x4 acc[2][4];
  #pragma unroll
  for (int i = 0; i < 2; ++i)
    #pragma unroll
    for (int j = 0; j < 4; ++j) acc[i][j] = (f32x4){0.f,0.f,0.f,0.f};
  gemm_core<64,128>(A, 64, W, 64, BLr, DI, 64, m0, n0, As, Ws, acc);
  const int tid = threadIdx.x, wv = tid >> 6, lane = tid & 63;
  const int wm0 = (wv >> 1)*32, wn0 = (wv & 1)*64;
  const int lm = lane & 15, g = lane >> 4;
  #pragma unroll
  for (int i = 0; i < 2; ++i) {
    int row = m0 + wm0 + i*16 + g*4;
    #pragma unroll
    for (int j = 0; j < 4; ++j) {
      int col = n0 + wn0 + j*16 + lm;
      float bv = bias[col];
      #pragma unroll
      for (int r = 0; r < 4; ++r) {
        if (row + r >= BLr) continue;
        float v = acc[i][j][r] + bv;
        v = (v > 20.f) ? v : log1pf(__expf(v));
        C[(size_t)(row + r)*DI + col] = v;
      }
    }
  }
}

// ---------------- out_proj + residual + flip + cat -----------------------
__global__ __launch_bounds__(256, 4) void gemm_outp_k(
    const unsigned short* __restrict__ yb, const unsigned short* __restrict__ w,
    const float* __restrict__ x, float* __restrict__ fbuf,
    float* __restrict__ bbuf, unsigned short* __restrict__ cat)
{
  __shared__ short As[4*64*8];
  __shared__ short Ws[4*64*8];
  const int dir = blockIdx.z;
  const unsigned short* A = yb + (size_t)dir*BLr*DI;
  const unsigned short* W = w + (size_t)dir*CM*DI;
  const int m0 = blockIdx.y*64, n0 = blockIdx.x*64;
  f32x4 acc[2][2];
  #pragma unroll
  for (int i = 0; i < 2; ++i)
    #pragma unroll
    for (int j = 0; j < 2; ++j) acc[i][j] = (f32x4){0.f,0.f,0.f,0.f};
  gemm_core<64,64>(A, DI, W, DI, BLr, CM, DI, m0, n0, As, Ws, acc);
  const int tid = threadIdx.x, wv = tid >> 6, lane = tid & 63;
  const int wm0 = (wv >> 1)*32, wn0 = (wv & 1)*32;
  const int lm = lane & 15, g = lane >> 4;
  #pragma unroll
  for (int i = 0; i < 2; ++i) {
    int row = m0 + wm0 + i*16 + g*4;
    #pragma unroll
    for (int j = 0; j < 2; ++j) {
      int col = n0 + wn0 + j*16 + lm;
      #pragma unroll
      for (int r = 0; r < 4; ++r) {
        int rr = row + r;
        if (rr >= BLr) continue;
        int rt = rr;
        if (dir == 1) {
          int l = rr % LL, b = rr / LL;
          int t = l / NN, nn = l % NN;
          rt = b*LL + (TT-1-t)*NN + nn;
        }
        float v = x[(size_t)rt*CM + col] + acc[i][j][r];
        if (dir == 0) {
          fbuf[(size_t)rt*CM + col] = v;
          cat[(size_t)rt*(2*CM) + col] = f2bf(v);
        } else {
          bbuf[(size_t)rt*CM + col] = v;
          cat[(size_t)rt*(2*CM) + CM + col] = f2bf(v);
        }
      }
    }
  }
}

// ---------------- gate GEMM + sigmoid mix -> mix_b bf16 ------------------
__global__ __launch_bounds__(256, 4) void gemm_gate_k(
    const unsigned short* __restrict__ cat, const unsigned short* __restrict__ w,
    const float* __restrict__ gb, const float* __restrict__ fbuf,
    const float* __restrict__ bbuf, unsigned short* __restrict__ mixb)
{
  __shared__ short As[4*64*8];
  __shared__ short Ws[4*64*8];
  const int m0 = blockIdx.y*64, n0 = blockIdx.x*64;
  f32x4 acc[2][2];
  #pragma unroll
  for (int i = 0; i < 2; ++i)
    #pragma unroll
    for (int j = 0; j < 2; ++j) acc[i][j] = (f32x4){0.f,0.f,0.f,0.f};
  gemm_core<64,64>(cat, 2*CM, w, 2*CM, BLr, CM, 2*CM, m0, n0, As, Ws, acc);
  const int tid = threadIdx.x, wv = tid >> 6, lane = tid & 63;
  const int wm0 = (wv >> 1)*32, wn0 = (wv & 1)*32;
  const int lm = lane & 15, g = lane >> 4;
  #pragma unroll
  for (int i = 0; i < 2; ++i) {
    int row = m0 + wm0 + i*16 + g*4;
    #pragma unroll
    for (int j = 0; j < 2; ++j) {
      int col = n0 + wn0 + j*16 + lm;
      float bv = gb[col];
      #pragma unroll
      for (int r = 0; r < 4; ++r) {
        int rr = row + r;
        if (rr >= BLr) continue;
        float gg = sigmoidf_(acc[i][j][r] + bv);
        float fv = fbuf[(size_t)rr*CM + col];
        float bo = bbuf[(size_t)rr*CM + col];
        mixb[(size_t)rr*CM + col] = f2bf(gg*fv + (1.f - gg)*bo);
      }
    }
  }
}

// ---------------- final proj -> d_out fp32 + bias ------------------------
__global__ __launch_bounds__(256, 4) void gemm_proj_k(
    const unsigned short* __restrict__ mixb, const unsigned short* __restrict__ w,
    const float* __restrict__ pb, float* __restrict__ out)
{
  __shared__ short As[4*64*8];
  __shared__ short Ws[4*64*8];
  const int m0 = blockIdx.y*64, n0 = blockIdx.x*64;
  f32x4 acc[2][2];
  #pragma unroll
  for (int i = 0; i < 2; ++i)
    #pragma unroll
    for (int j = 0; j < 2; ++j) acc[i][j] = (f32x4){0.f,0.f,0.f,0.f};
  gemm_core<64,64>(mixb, CM, w, CM, BLr, CM, CM, m0, n0, As, Ws, acc);
  const int tid = threadIdx.x, wv = tid >> 6, lane = tid & 63;
  const int wm0 = (wv >> 1)*32, wn0 = (wv & 1)*32;
  const int lm = lane & 15, g = lane >> 4;
  #pragma unroll
  for (int i = 0; i < 2; ++i) {
    int row = m0 + wm0 + i*16 + g*4;
    #pragma unroll
    for (int j = 0; j < 2; ++j) {
      int col = n0 + wn0 + j*16 + lm;
      float bv = pb[col];
      #pragma unroll
      for (int r = 0; r < 4; ++r)
        if (row + r < BLr) out[(size_t)(row + r)*CM + col] = acc[i][j][r] + bv;
    }
  }
}

// ---------------- x_proj split-K GEMM: partials over 8 K-segments ---------
__global__ __launch_bounds__(256, 2) void gemm_xproj(
    const unsigned short* __restrict__ ub, const unsigned short* __restrict__ xpw,
    float* __restrict__ part)
{
  __shared__ short As[4*1024];
  __shared__ short Ws[4*1024];
  const int tid = threadIdx.x;
  const int ks = blockIdx.x, mt = blockIdx.y, dir = blockIdx.z;
  const unsigned short* A = ub + (size_t)dir*BLr*DI;
  const unsigned short* W = xpw + (size_t)dir*XD*DI;
  const int m0 = mt*128, kb = ks*(DI/8);
  const int wv = tid >> 6, lane = tid & 63;
  const int wm0 = (wv >> 1)*64, wn = wv & 1;
  const int lm = lane & 15, g = lane >> 4;
  const int sc = tid >> 6, sr = tid & 63;
  f32x4 acc[4][4];
  #pragma unroll
  for (int i = 0; i < 4; ++i)
    #pragma unroll
    for (int j = 0; j < 4; ++j) acc[i][j] = (f32x4){0.f,0.f,0.f,0.f};

  for (int k0 = kb; k0 < kb + DI/8; k0 += 32) {
    #pragma unroll
    for (int e = 0; e < 2; ++e) {
      int m = 64*e + sr;
      int gm = m0 + m; if (gm >= BLr) gm = BLr - 1;
      int gn = m; if (gn >= XD) gn = XD - 1;
      gload_lds16(A + (size_t)gm*DI + k0 + 8*sc, &As[sc*1024 + m*8]);
      gload_lds16(W + (size_t)gn*DI + k0 + 8*sc, &Ws[sc*1024 + m*8]);
    }
    __syncthreads();
    s16x8 af[4], bf[4];
    #pragma unroll
    for (int i = 0; i < 4; ++i)
      af[i] = *(const s16x8*)(&As[g*1024 + (wm0 + i*16 + lm)*8]);
    #pragma unroll
    for (int j = 0; j < 4; ++j)
      bf[j] = *(const s16x8*)(&Ws[g*1024 + (wn*64 + j*16 + lm)*8]);
    #pragma unroll
    for (int i = 0; i < 4; ++i)
      #pragma unroll
      for (int j = 0; j < 4; ++j)
        acc[i][j] = __builtin_amdgcn_mfma_f32_16x16x32_bf16(af[i], bf[j], acc[i][j], 0, 0, 0);
    __syncthreads();
  }
  float* P = part + ((size_t)(dir*8 + ks)*BLr)*XD;
  #pragma unroll
  for (int i = 0; i < 4; ++i) {
    int row = m0 + wm0 + i*16 + g*4;
    #pragma unroll
    for (int j = 0; j < 4; ++j) {
      int col = wn*64 + j*16 + lm;
      if (col >= XD) continue;
      #pragma unroll
      for (int r = 0; r < 4; ++r)
        if (row + r < BLr) P[(size_t)(row + r)*XD + col] = acc[i][j][r];
    }
  }
}

// ---------------- reduce x_proj partials -> xdbl fp32 + dt cols bf16 ------
__global__ void xreduce_k(const float* __restrict__ part,
    float* __restrict__ xdbl, unsigned short* __restrict__ xdbl_b)
{
  int i = blockIdx.x*256 + threadIdx.x;     // over 2*BLr*80
  if (i >= 2*BLr*XD) return;
  int c = i % XD;
  int r = i / XD;                            // dir*BLr + row
  int dir = r / BLr, row = r % BLr;
  float s = 0.f;
  #pragma unroll
  for (int ks = 0; ks < 8; ++ks)
    s += part[((size_t)(dir*8 + ks)*BLr + row)*XD + c];
  xdbl[(size_t)r*XD + c] = s;
  if (c < DTR)      xdbl_b[(size_t)r*64 + c] = f2bf(s);
  else if (c < 64)  xdbl_b[(size_t)r*64 + c] = 0;
}

// ---------------- Causal depthwise conv (k=4) + SiLU ---------------------
// xz is bf16 now; outputs fp32 u + bf16 ub.
__global__ __launch_bounds__(256) void conv_silu_k(
    const unsigned short* __restrict__ xz, const float* __restrict__ cw,
    const float* __restrict__ cb, float* __restrict__ u,
    unsigned short* __restrict__ ub)
{
  size_t idx = (size_t)blockIdx.x*256 + threadIdx.x;
  if (idx >= (size_t)2*BLr*DI) return;
  int di  = (int)(idx % DI);
  size_t r = idx / DI;               // dir*BLr + b*LL + l
  int l   = (int)(r % LL);
  int dir = (int)(r / (BB*LL));
  size_t rowbase = r - l;
  const float* w = cw + ((size_t)dir*DI + di)*4;
  float acc = cb[dir*DI + di];
  #pragma unroll
  for (int k = 0; k < 4; ++k) {
    int lp = l - 3 + k;
    if (lp >= 0) acc = fmaf(w[k], bf2f(xz[(rowbase + lp)*(2*DI) + di]), acc);
  }
  float v = acc * sigmoidf_(acc);
  u[idx]  = v;
  ub[idx] = f2bf(v);
}

// ---------------- chunked selective scan, 4 states (n-quad) per lane ------
__global__ __launch_bounds__(256) void scanA_k(const float* __restrict__ dtv,
    const float* __restrict__ u, const float* __restrict__ xdbl,
    const float* __restrict__ A_log, float* __restrict__ carry,
    float* __restrict__ Pm)
{
  int bx = blockIdx.x;
  int g = bx & (GCH-1);
  int rest = bx / GCH;
  int dchunk = rest % (DI/64);
  int b   = (rest / (DI/64)) % BB;
  int dir = rest / ((DI/64)*BB);
  int tid = threadIdx.x;
  int dl = tid >> 2, q = tid & 3;
  int d = dchunk*64 + dl;
  size_t rb = ((size_t)dir*BB + b) * LL + (size_t)g*LC;
  const float* dtp = dtv + rb*DI + d;
  const float* up  = u   + rb*DI + d;
  const float* xB  = xdbl + rb*XD + DTR + 4*q;
  f32x4 al = *(const f32x4*)(A_log + ((size_t)dir*DI + d)*DS + 4*q);
  float Av[4];
  #pragma unroll
  for (int i = 0; i < 4; ++i) Av[i] = -__expf(al[i]);
  float h[4] = {0.f,0.f,0.f,0.f};
  float S = 0.f;
  float ndt[2], nu[2]; f32x4 nB[2];
  #pragma unroll
  for (int e = 0; e < 2; ++e) {
    ndt[e] = dtp[(size_t)e*DI];
    nu[e]  = up[(size_t)e*DI];
    nB[e]  = *(const f32x4*)(xB + (size_t)e*XD);
  }
  #pragma unroll 2
  for (int j = 0; j < LC; ++j) {
    int s = j & 1;
    float cdt = ndt[s], cu = nu[s];
    f32x4 cB = nB[s];
    int lp = j + 2;
    if (lp < LC) {
      ndt[s] = dtp[(size_t)lp*DI];
      nu[s]  = up[(size_t)lp*DI];
      nB[s]  = *(const f32x4*)(xB + (size_t)lp*XD);
    }
    float du = cdt * cu;
    S += cdt;
    #pragma unroll
    for (int i = 0; i < 4; ++i) {
      float dA = __expf(cdt * Av[i]);
      h[i] = fmaf(dA, h[i], du * cB[i]);
    }
  }
  size_t sid = (((size_t)(dir*BB + b)*DI + d)*DS + 4*q);
  f32x4 hc = {h[0], h[1], h[2], h[3]};
  f32x4 pc = {__expf(Av[0]*S), __expf(Av[1]*S), __expf(Av[2]*S), __expf(Av[3]*S)};
  *(f32x4*)(carry + (size_t)g*NST + sid) = hc;
  *(f32x4*)(Pm    + (size_t)g*NST + sid) = pc;
}

// Phase B: sequential combine over chunks; h_in overwrites carry in place.
__global__ __launch_bounds__(256) void scanB_k(float* __restrict__ carry,
    const float* __restrict__ Pm)
{
  int sid = blockIdx.x*256 + threadIdx.x;   // < NST
  float h = 0.f;
  #pragma unroll
  for (int g = 0; g < GCH; ++g) {
    float c = carry[(size_t)g*NST + sid];
    float p = Pm[(size_t)g*NST + sid];
    carry[(size_t)g*NST + sid] = h;         // h_in
    h = fmaf(p, h, c);
  }
}

// Phase C: re-scan chunk from h_in (in carry), reduce over n, -> y bf16
__global__ __launch_bounds__(256) void scanC_k(const float* __restrict__ dtv,
    const float* __restrict__ u, const unsigned short* __restrict__ xz,
    const float* __restrict__ xdbl, const float* __restrict__ A_log,
    const float* __restrict__ Dp, const float* __restrict__ h_in,
    unsigned short* __restrict__ y)
{
  int bx = blockIdx.x;
  int g = bx & (GCH-1);
  int rest = bx / GCH;
  int dchunk = rest % (DI/64);
  int b   = (rest / (DI/64)) % BB;
  int dir = rest / ((DI/64)*BB);
  int tid = threadIdx.x;
  int dl = tid >> 2, q = tid & 3;
  int d = dchunk*64 + dl;
  size_t rb = ((size_t)dir*BB + b) * LL + (size_t)g*LC;
  const float* dtp = dtv + rb*DI + d;
  const float* up  = u   + rb*DI + d;
  const unsigned short* zp = xz + rb*(2*DI) + DI + d;
  const float* xB  = xdbl + rb*XD + DTR + 4*q;
  const float* xC  = xB + DS;
  unsigned short* yp = y + rb*DI + d;
  f32x4 al = *(const f32x4*)(A_log + ((size_t)dir*DI + d)*DS + 4*q);
  float Av[4];
  #pragma unroll
  for (int i = 0; i < 4; ++i) Av[i] = -__expf(al[i]);
  float Dd = Dp[dir*DI + d];
  size_t sid = (((size_t)(dir*BB + b)*DI + d)*DS + 4*q);
  f32x4 h4 = *(const f32x4*)(h_in + (size_t)g*NST + sid);
  float h[4] = {h4[0], h4[1], h4[2], h4[3]};
  float ndt[2], nu[2], nz[2]; f32x4 nB[2], nC[2];
  #pragma unroll
  for (int e = 0; e < 2; ++e) {
    ndt[e] = dtp[(size_t)e*DI];
    nu[e]  = up[(size_t)e*DI];
    nz[e]  = bf2f(zp[(size_t)e*(2*DI)]);
    nB[e]  = *(const f32x4*)(xB + (size_t)e*XD);
    nC[e]  = *(const f32x4*)(xC + (size_t)e*XD);
  }
  #pragma unroll 2
  for (int j = 0; j < LC; ++j) {
    int s = j & 1;
    float cdt = ndt[s], cu = nu[s], cz = nz[s];
    f32x4 cB = nB[s], cC = nC[s];
    int lp = j + 2;
    if (lp < LC) {
      ndt[s] = dtp[(size_t)lp*DI];
      nu[s]  = up[(size_t)lp*DI];
      nz[s]  = bf2f(zp[(size_t)lp*(2*DI)]);
      nB[s]  = *(const f32x4*)(xB + (size_t)lp*XD);
      nC[s]  = *(const f32x4*)(xC + (size_t)lp*XD);
    }
    float du = cdt * cu;
    float acc = 0.f;
    #pragma unroll
    for (int i = 0; i < 4; ++i) {
      float dA = __expf(cdt * Av[i]);
      h[i] = fmaf(dA, h[i], du * cB[i]);
      acc = fmaf(h[i], cC[i], acc);
    }
    acc += __shfl_xor(acc, 1);
    acc += __shfl_xor(acc, 2);
    if (q == 0) {
      float yv = (acc + cu * Dd) * (cz * sigmoidf_(cz));
      yp[(size_t)j*DI] = f2bf(yv);
    }
  }
}

extern "C" void kernel_launch(void* const* d_in, const int* in_sizes, int n_in,
                              void* d_out, int out_size, void* d_ws, size_t ws_size,
                              hipStream_t stream)
{
  (void)in_sizes; (void)n_in; (void)out_size; (void)ws_size;
  const float* x      = (const float*)d_in[0];
  const float* norm_w = (const float*)d_in[1];
  const float* in_w   = (const float*)d_in[2];
  const float* conv_w = (const float*)d_in[3];
  const float* conv_b = (const float*)d_in[4];
  const float* xp_w   = (const float*)d_in[5];
  const float* dt_w   = (const float*)d_in[6];
  const float* dt_b   = (const float*)d_in[7];
  const float* A_log  = (const float*)d_in[8];
  const float* Dp     = (const float*)d_in[9];
  const float* out_w  = (const float*)d_in[10];
  const float* gate_w = (const float*)d_in[11];
  const float* gate_b = (const float*)d_in[12];
  const float* proj_w = (const float*)d_in[13];
  const float* proj_b = (const float*)d_in[14];
  float* out = (float*)d_out;
  char* wsb  = (char*)d_ws;

  // ---- workspace layout (byte offsets; peak ~118.3 MB) ----
  unsigned short* w_all   = (unsigned short*)(wsb + 0);   // 18,579,456 B
  unsigned short* in_w_b  = w_all;          // dead after in_proj
  unsigned short* out_w_b = w_all + E0;
  unsigned short* gate_w_b= w_all + E1;
  unsigned short* proj_w_b= w_all + E2;
  unsigned short* xp_w_b  = w_all + E3;
  unsigned short* dt_w_b  = w_all + E4;
  unsigned short* xz_b = (unsigned short*)(wsb + 18579456); // 2*BLr*3072 bf16 (19.3MB)
  float* ubuf  = (float*)(wsb + 37847040);    // 2*BLr*1536 fl (19.3MB)
  float* xdbl  = (float*)(wsb + 57114624);    // 2*BLr*80 fl (1.0MB)
  float* dtvb  = (float*)(wsb + 58118144);    // 2*BLr*1536 fl (19.3MB)
  unsigned short* y_b = (unsigned short*)(wsb + 77385728);  // 2*BLr*1536 bf16 (9.6MB)
  unsigned short* tmp = (unsigned short*)(wsb + 87019520);  // 9,633,792 B scratch
  float* fbuf  = (float*)(wsb + 96653312);    // BLr*768 fl (4.8MB)
  float* bbuf  = (float*)(wsb + 101470208);   // BLr*768 fl (4.8MB)
  unsigned short* cat_b = (unsigned short*)(wsb + 106287104); // BLr*1536 bf16 (4.8MB)
  unsigned short* mix_b = (unsigned short*)(wsb + 111104000); // BLr*768 bf16 (2.4MB)

  unsigned short* xn_b   = tmp;   // 2*BLr*768 bf16, live until in_proj
  unsigned short* ub     = tmp;   // 2*BLr*1536 bf16, live conv->x_proj
  unsigned short* xdbl_b = tmp;   // 2*BLr*64 bf16, live xreduce->dt_proj
  float* part  = (float*)(wsb + 0);             // 8.03MB, xproj->xreduce (in_w dead)
  float* carry = (float*)(wsb + 0);             // 6.29MB, scanA->scanC
  float* Pmat  = (float*)(wsb + 87019520 + 524288);  // 6.29MB in tmp tail

  // 1. rmsnorm (both dirs) -> bf16
  rmsnorm_k<<<2*BLr, 256, 0, stream>>>(x, norm_w, xn_b);
  // 2. weight casts
  multicast_k<<<(E5 + 255)/256, 256, 0, stream>>>(
      in_w, out_w, gate_w, proj_w, xp_w, dt_w, w_all);
  // 3. in_proj -> xz bf16 (64x128 tiles, 1200 blocks)
  gemm_in_k<<<dim3(3072/128, (BLr+63)/64, 2), 256, 0, stream>>>(
      xn_b, in_w_b, xz_b);
  // 4. causal dwconv + silu -> u (fp32) + ub (bf16)
  conv_silu_k<<<(int)(((size_t)2*BLr*DI + 255)/256), 256, 0, stream>>>(
      xz_b, conv_w, conv_b, ubuf, ub);
  // 5. x_proj split-K (208 blocks) -> partials
  gemm_xproj<<<dim3(8, (BLr+127)/128, 2), 256, 0, stream>>>(ub, xp_w_b, part);
  // 6. reduce partials -> xdbl fp32 + xdbl_b bf16
  xreduce_k<<<(2*BLr*XD + 255)/256, 256, 0, stream>>>(part, xdbl, xdbl_b);
  // 7. dt_proj + bias + softplus -> dtvb (600 blocks)
  gemm_dt_k<<<dim3(DI/128, (BLr+63)/64, 2), 256, 0, stream>>>(
      xdbl_b, dt_w_b, dt_b, dtvb);
  // 8. chunked scan: A -> B -> C
  scanA_k<<<2*BB*(DI/64)*GCH, 256, 0, stream>>>(
      dtvb, ubuf, xdbl, A_log, carry, Pmat);
  scanB_k<<<NST/256, 256, 0, stream>>>(carry, Pmat);
  scanC_k<<<2*BB*(DI/64)*GCH, 256, 0, stream>>>(
      dtvb, ubuf, xz_b, xdbl, A_log, Dp, carry, y_b);
  // 9. out_proj + residual + flip + cat (600 blocks)
  gemm_outp_k<<<dim3(CM/64, (BLr+63)/64, 2), 256, 0, stream>>>(
      y_b, out_w_b, x, fbuf, bbuf, cat_b);
  // 10. gate GEMM + sigmoid mix -> mix_b (300 blocks)
  gemm_gate_k<<<dim3(CM/64, (BLr+63)/64, 1), 256, 0, stream>>>(
      cat_b, gate_w_b, gate_b, fbuf, bbuf, mix_b);
  // 11. final proj -> d_out (300 blocks)
  gemm_proj_k<<<dim3(CM/64, (BLr+63)/64, 1), 256, 0, stream>>>(
      mix_b, proj_w_b, proj_b, out);
}

// Round 7
// 378.671 us; speedup vs baseline: 6.0968x; 1.0366x over previous
//
#include <hip/hip_runtime.h>
#include <cstdint>
#include <cstddef>

// Problem constants (BiMambaRefinerBlock)
#define BB 2
#define TT 4
#define NN 196
#define LL (TT*NN)        // 784
#define BLr (BB*LL)       // 1568 rows per direction
#define CM 768            // d_model
#define DI 1536           // d_inner
#define DS 16             // d_state
#define DTR 48            // dt_rank
#define XD 80             // dt_rank + 2*d_state
// chunked scan
#define GCH 16
#define LC (LL/GCH)       // 49
#define NST (2*BB*DI*DS)  // 98304 states

typedef short s16x8 __attribute__((ext_vector_type(8)));
typedef float f32x4 __attribute__((ext_vector_type(4)));

static __device__ __forceinline__ float sigmoidf_(float x) {
  return 1.f / (1.f + __expf(-x));
}
// fp32 -> bf16 (RNE)
static __device__ __forceinline__ unsigned short f2bf(float f) {
  unsigned int u = __float_as_uint(f);
  unsigned int r = (u + 0x7fffu + ((u >> 16) & 1u)) >> 16;
  return (unsigned short)r;
}
static __device__ __forceinline__ float bf2f(unsigned short u) {
  return __uint_as_float(((unsigned int)u) << 16);
}
// async global->LDS, 16 bytes per lane; LDS dest must be uniform + lane*16
static __device__ __forceinline__ void gload_lds16(const void* g, void* l) {
  __builtin_amdgcn_global_load_lds(
      (const __attribute__((address_space(1))) void*)g,
      (__attribute__((address_space(3))) void*)l, 16, 0, 0);
}

// ---------------- RMSNorm -> bf16 (dir1 reads flipped-t source) ----------
__global__ __launch_bounds__(256) void rmsnorm_k(const float* __restrict__ x,
    const float* __restrict__ nw, unsigned short* __restrict__ xn)
{
  int blk = blockIdx.x;               // dir*BLr + b*LL + l
  int l   = blk % LL;
  int b   = (blk / LL) % BB;
  int dir = blk / (BB*LL);
  int lsrc = l;
  if (dir == 1) { int t = l / NN, n = l % NN; lsrc = (TT-1-t)*NN + n; }
  const float* xp = x + ((size_t)b*LL + lsrc)*CM;
  float s = 0.f;
  for (int c = threadIdx.x; c < CM; c += 256) { float v = xp[c]; s += v*v; }
  #pragma unroll
  for (int off = 32; off > 0; off >>= 1) s += __shfl_down(s, off);
  __shared__ float red[4];
  if ((threadIdx.x & 63) == 0) red[threadIdx.x >> 6] = s;
  __syncthreads();
  float tot = red[0] + red[1] + red[2] + red[3];
  float r = rsqrtf(tot * (1.f/CM) + 1e-5f);
  const float* w = nw + dir*CM;
  unsigned short* o = xn + (size_t)blk*CM;
  for (int c = threadIdx.x; c < CM; c += 256) o[c] = f2bf(xp[c] * r * w[c]);
}

// ---------------- weight casts (one dispatch, hardcoded segment map) ------
#define S_INW  4718592        // 2*3072*768
#define S_OUTW 2359296        // 2*768*1536
#define S_GATW 1179648        // 768*1536
#define S_PRJW 589824         // 768*768
#define S_XPW  245760         // 2*80*1536
#define S_DTW  196608         // 2*1536*64 (padded from 48)
#define E0 S_INW
#define E1 (E0 + S_OUTW)      // 7077888
#define E2 (E1 + S_GATW)      // 8257536
#define E3 (E2 + S_PRJW)      // 8847360
#define E4 (E3 + S_XPW)       // 9093120
#define E5 (E4 + S_DTW)       // 9289728
__global__ void multicast_k(const float* __restrict__ in_w,
    const float* __restrict__ out_w, const float* __restrict__ gate_w,
    const float* __restrict__ proj_w, const float* __restrict__ xp_w,
    const float* __restrict__ dt_w, unsigned short* __restrict__ dst)
{
  int i = blockIdx.x*256 + threadIdx.x;
  if (i >= E5) return;
  float v;
  if (i < E0)       v = in_w[i];
  else if (i < E1)  v = out_w[i - E0];
  else if (i < E2)  v = gate_w[i - E1];
  else if (i < E3)  v = proj_w[i - E2];
  else if (i < E4)  v = xp_w[i - E3];
  else {            // dt_w: pad K 48 -> 64
    int j = i - E4, r = j >> 6, c = j & 63;
    v = (c < 48) ? dt_w[r*48 + c] : 0.f;
  }
  dst[i] = f2bf(v);
}

// ---------------- shared MFMA GEMM core: BM x BN tile, BK=64, 4 waves ----
// Staging: per wave-instruction 8 rows x 8 chunks (lane = row3|chunk3);
// each row's 64-k slice = 128 B = ONE full cache line -> fully coalesced.
// Global chunk XOR-swizzled by row (chs = ch ^ r8) so the fixed
// lds_base + lane*16 destination gives bank-balanced fragment reads
// (chunk p = (s*4+g) ^ (row&7)). LDS row stride 64 shorts (128 B).
// M/N-tail rows clamp the load address; epilogue masks stores.
template <int BM, int BN>
__device__ __forceinline__ void gemm_core(
    const unsigned short* __restrict__ A, int lda,
    const unsigned short* __restrict__ W, int ldw,
    int M, int N, int K, int m0, int n0,
    short* As, short* Ws, f32x4 (*acc)[BN/32])
{
  const int tid = threadIdx.x;
  const int wv = tid >> 6, lane = tid & 63;
  const int wm0 = (wv >> 1)*(BM/2), wn0 = (wv & 1)*(BN/2);
  const int lm = lane & 15, g = lane >> 4;
  const int r8 = lane >> 3, ch = lane & 7;
  const int chs = ch ^ r8;                  // swizzled source chunk
  constexpr int MT = BM/32, NT = BN/32;
  for (int k0 = 0; k0 < K; k0 += 64) {
    #pragma unroll
    for (int e = 0; e < BM/32; ++e) {
      int rb = e*32 + wv*8;                 // wave-uniform 8-row group base
      int gr = m0 + rb + r8; if (gr >= M) gr = M - 1;
      gload_lds16(A + (size_t)gr*lda + k0 + chs*8, &As[rb*64 + lane*8]);
    }
    #pragma unroll
    for (int e = 0; e < BN/32; ++e) {
      int rb = e*32 + wv*8;
      int gn = n0 + rb + r8; if (gn >= N) gn = N - 1;
      gload_lds16(W + (size_t)gn*ldw + k0 + chs*8, &Ws[rb*64 + lane*8]);
    }
    __syncthreads();
    #pragma unroll
    for (int s = 0; s < 2; ++s) {           // two 32-k MFMA steps
      s16x8 af[MT], bf[NT];
      #pragma unroll
      for (int i = 0; i < MT; ++i) {
        int R = wm0 + i*16 + lm;
        af[i] = *(const s16x8*)(&As[R*64 + (((s*4 + g) ^ (R & 7))*8)]);
      }
      #pragma unroll
      for (int j = 0; j < NT; ++j) {
        int Rn = wn0 + j*16 + lm;
        bf[j] = *(const s16x8*)(&Ws[Rn*64 + (((s*4 + g) ^ (Rn & 7))*8)]);
      }
      #pragma unroll
      for (int i = 0; i < MT; ++i)
        #pragma unroll
        for (int j = 0; j < NT; ++j)
          acc[i][j] = __builtin_amdgcn_mfma_f32_16x16x32_bf16(af[i], bf[j], acc[i][j], 0, 0, 0);
    }
    __syncthreads();
  }
}

// ---------------- in_proj: (BLr,768)x(3072,768)^T -> xz bf16 -------------
__global__ __launch_bounds__(256, 4) void gemm_in_k(
    const unsigned short* __restrict__ xn, const unsigned short* __restrict__ w,
    unsigned short* __restrict__ xzout)
{
  __shared__ short As[64*64];
  __shared__ short Ws[128*64];
  const int dir = blockIdx.z;
  const unsigned short* A = xn + (size_t)dir*BLr*CM;
  const unsigned short* W = w  + (size_t)dir*2*DI*CM;
  unsigned short* C = xzout + (size_t)dir*BLr*2*DI;
  const int m0 = blockIdx.y*64, n0 = blockIdx.x*128;
  f32x4 acc[2][4];
  #pragma unroll
  for (int i = 0; i < 2; ++i)
    #pragma unroll
    for (int j = 0; j < 4; ++j) acc[i][j] = (f32x4){0.f,0.f,0.f,0.f};
  gemm_core<64,128>(A, CM, W, CM, BLr, 2*DI, CM, m0, n0, As, Ws, acc);
  const int tid = threadIdx.x, wv = tid >> 6, lane = tid & 63;
  const int wm0 = (wv >> 1)*32, wn0 = (wv & 1)*64;
  const int lm = lane & 15, g = lane >> 4;
  #pragma unroll
  for (int i = 0; i < 2; ++i) {
    int row = m0 + wm0 + i*16 + g*4;
    #pragma unroll
    for (int j = 0; j < 4; ++j) {
      int col = n0 + wn0 + j*16 + lm;
      #pragma unroll
      for (int r = 0; r < 4; ++r)
        if (row + r < BLr) C[(size_t)(row + r)*2*DI + col] = f2bf(acc[i][j][r]);
    }
  }
}

// ---------------- dt_proj: (BLr,64)x(1536,64)^T + bias + softplus --------
__global__ __launch_bounds__(256, 4) void gemm_dt_k(
    const unsigned short* __restrict__ xdblb, const unsigned short* __restrict__ w,
    const float* __restrict__ dtb, float* __restrict__ dtv)
{
  __shared__ short As[64*64];
  __shared__ short Ws[128*64];
  const int dir = blockIdx.z;
  const unsigned short* A = xdblb + (size_t)dir*BLr*64;
  const unsigned short* W = w + (size_t)dir*DI*64;
  float* C = dtv + (size_t)dir*BLr*DI;
  const float* bias = dtb + (size_t)dir*DI;
  const int m0 = blockIdx.y*64, n0 = blockIdx.x*128;
  f32x4 acc[2][4];
  #pragma unroll
  for (int i = 0; i < 2; ++i)
    #pragma unroll
    for (int j = 0; j < 4; ++j) acc[i][j] = (f32x4){0.f,0.f,0.f,0.f};
  gemm_core<64,128>(A, 64, W, 64, BLr, DI, 64, m0, n0, As, Ws, acc);
  const int tid = threadIdx.x, wv = tid >> 6, lane = tid & 63;
  const int wm0 = (wv >> 1)*32, wn0 = (wv & 1)*64;
  const int lm = lane & 15, g = lane >> 4;
  #pragma unroll
  for (int i = 0; i < 2; ++i) {
    int row = m0 + wm0 + i*16 + g*4;
    #pragma unroll
    for (int j = 0; j < 4; ++j) {
      int col = n0 + wn0 + j*16 + lm;
      float bv = bias[col];
      #pragma unroll
      for (int r = 0; r < 4; ++r) {
        if (row + r >= BLr) continue;
        float v = acc[i][j][r] + bv;
        v = (v > 20.f) ? v : log1pf(__expf(v));
        C[(size_t)(row + r)*DI + col] = v;
      }
    }
  }
}

// ---------------- out_proj + residual + flip + cat -----------------------
__global__ __launch_bounds__(256, 4) void gemm_outp_k(
    const unsigned short* __restrict__ yb, const unsigned short* __restrict__ w,
    const float* __restrict__ x, float* __restrict__ fbuf,
    float* __restrict__ bbuf, unsigned short* __restrict__ cat)
{
  __shared__ short As[64*64];
  __shared__ short Ws[64*64];
  const int dir = blockIdx.z;
  const unsigned short* A = yb + (size_t)dir*BLr*DI;
  const unsigned short* W = w + (size_t)dir*CM*DI;
  const int m0 = blockIdx.y*64, n0 = blockIdx.x*64;
  f32x4 acc[2][2];
  #pragma unroll
  for (int i = 0; i < 2; ++i)
    #pragma unroll
    for (int j = 0; j < 2; ++j) acc[i][j] = (f32x4){0.f,0.f,0.f,0.f};
  gemm_core<64,64>(A, DI, W, DI, BLr, CM, DI, m0, n0, As, Ws, acc);
  const int tid = threadIdx.x, wv = tid >> 6, lane = tid & 63;
  const int wm0 = (wv >> 1)*32, wn0 = (wv & 1)*32;
  const int lm = lane & 15, g = lane >> 4;
  #pragma unroll
  for (int i = 0; i < 2; ++i) {
    int row = m0 + wm0 + i*16 + g*4;
    #pragma unroll
    for (int j = 0; j < 2; ++j) {
      int col = n0 + wn0 + j*16 + lm;
      #pragma unroll
      for (int r = 0; r < 4; ++r) {
        int rr = row + r;
        if (rr >= BLr) continue;
        int rt = rr;
        if (dir == 1) {
          int l = rr % LL, b = rr / LL;
          int t = l / NN, nn = l % NN;
          rt = b*LL + (TT-1-t)*NN + nn;
        }
        float v = x[(size_t)rt*CM + col] + acc[i][j][r];
        if (dir == 0) {
          fbuf[(size_t)rt*CM + col] = v;
          cat[(size_t)rt*(2*CM) + col] = f2bf(v);
        } else {
          bbuf[(size_t)rt*CM + col] = v;
          cat[(size_t)rt*(2*CM) + CM + col] = f2bf(v);
        }
      }
    }
  }
}

// ---------------- gate GEMM + sigmoid mix -> mix_b bf16 ------------------
__global__ __launch_bounds__(256, 4) void gemm_gate_k(
    const unsigned short* __restrict__ cat, const unsigned short* __restrict__ w,
    const float* __restrict__ gb, const float* __restrict__ fbuf,
    const float* __restrict__ bbuf, unsigned short* __restrict__ mixb)
{
  __shared__ short As[64*64];
  __shared__ short Ws[64*64];
  const int m0 = blockIdx.y*64, n0 = blockIdx.x*64;
  f32x4 acc[2][2];
  #pragma unroll
  for (int i = 0; i < 2; ++i)
    #pragma unroll
    for (int j = 0; j < 2; ++j) acc[i][j] = (f32x4){0.f,0.f,0.f,0.f};
  gemm_core<64,64>(cat, 2*CM, w, 2*CM, BLr, CM, 2*CM, m0, n0, As, Ws, acc);
  const int tid = threadIdx.x, wv = tid >> 6, lane = tid & 63;
  const int wm0 = (wv >> 1)*32, wn0 = (wv & 1)*32;
  const int lm = lane & 15, g = lane >> 4;
  #pragma unroll
  for (int i = 0; i < 2; ++i) {
    int row = m0 + wm0 + i*16 + g*4;
    #pragma unroll
    for (int j = 0; j < 2; ++j) {
      int col = n0 + wn0 + j*16 + lm;
      float bv = gb[col];
      #pragma unroll
      for (int r = 0; r < 4; ++r) {
        int rr = row + r;
        if (rr >= BLr) continue;
        float gg = sigmoidf_(acc[i][j][r] + bv);
        float fv = fbuf[(size_t)rr*CM + col];
        float bo = bbuf[(size_t)rr*CM + col];
        mixb[(size_t)rr*CM + col] = f2bf(gg*fv + (1.f - gg)*bo);
      }
    }
  }
}

// ---------------- final proj -> d_out fp32 + bias ------------------------
__global__ __launch_bounds__(256, 4) void gemm_proj_k(
    const unsigned short* __restrict__ mixb, const unsigned short* __restrict__ w,
    const float* __restrict__ pb, float* __restrict__ out)
{
  __shared__ short As[64*64];
  __shared__ short Ws[64*64];
  const int m0 = blockIdx.y*64, n0 = blockIdx.x*64;
  f32x4 acc[2][2];
  #pragma unroll
  for (int i = 0; i < 2; ++i)
    #pragma unroll
    for (int j = 0; j < 2; ++j) acc[i][j] = (f32x4){0.f,0.f,0.f,0.f};
  gemm_core<64,64>(mixb, CM, w, CM, BLr, CM, CM, m0, n0, As, Ws, acc);
  const int tid = threadIdx.x, wv = tid >> 6, lane = tid & 63;
  const int wm0 = (wv >> 1)*32, wn0 = (wv & 1)*32;
  const int lm = lane & 15, g = lane >> 4;
  #pragma unroll
  for (int i = 0; i < 2; ++i) {
    int row = m0 + wm0 + i*16 + g*4;
    #pragma unroll
    for (int j = 0; j < 2; ++j) {
      int col = n0 + wn0 + j*16 + lm;
      float bv = pb[col];
      #pragma unroll
      for (int r = 0; r < 4; ++r)
        if (row + r < BLr) out[(size_t)(row + r)*CM + col] = acc[i][j][r] + bv;
    }
  }
}

// ---------------- x_proj split-K GEMM on the shared core ------------------
// grid (8 ksplit, 13 mtiles, 2 dirs); K-slice 192, N=80 in a 128 tile.
__global__ __launch_bounds__(256, 2) void gemm_xproj(
    const unsigned short* __restrict__ ub, const unsigned short* __restrict__ xpw,
    float* __restrict__ part)
{
  __shared__ short As[128*64];
  __shared__ short Ws[128*64];
  const int ks = blockIdx.x, mt = blockIdx.y, dir = blockIdx.z;
  const unsigned short* A = ub + (size_t)dir*BLr*DI + ks*(DI/8);
  const unsigned short* W = xpw + (size_t)dir*XD*DI + ks*(DI/8);
  const int m0 = mt*128;
  f32x4 acc[4][4];
  #pragma unroll
  for (int i = 0; i < 4; ++i)
    #pragma unroll
    for (int j = 0; j < 4; ++j) acc[i][j] = (f32x4){0.f,0.f,0.f,0.f};
  gemm_core<128,128>(A, DI, W, DI, BLr, XD, DI/8, m0, 0, As, Ws, acc);
  const int tid = threadIdx.x, wv = tid >> 6, lane = tid & 63;
  const int wm0 = (wv >> 1)*64, wn0 = (wv & 1)*64;
  const int lm = lane & 15, g = lane >> 4;
  float* P = part + ((size_t)(dir*8 + ks)*BLr)*XD;
  #pragma unroll
  for (int i = 0; i < 4; ++i) {
    int row = m0 + wm0 + i*16 + g*4;
    #pragma unroll
    for (int j = 0; j < 4; ++j) {
      int col = wn0 + j*16 + lm;
      if (col >= XD) continue;
      #pragma unroll
      for (int r = 0; r < 4; ++r)
        if (row + r < BLr) P[(size_t)(row + r)*XD + col] = acc[i][j][r];
    }
  }
}

// ---------------- reduce x_proj partials -> xdbl fp32 + dt cols bf16 ------
__global__ void xreduce_k(const float* __restrict__ part,
    float* __restrict__ xdbl, unsigned short* __restrict__ xdbl_b)
{
  int i = blockIdx.x*256 + threadIdx.x;     // over 2*BLr*80
  if (i >= 2*BLr*XD) return;
  int c = i % XD;
  int r = i / XD;                            // dir*BLr + row
  int dir = r / BLr, row = r % BLr;
  float s = 0.f;
  #pragma unroll
  for (int ks = 0; ks < 8; ++ks)
    s += part[((size_t)(dir*8 + ks)*BLr + row)*XD + c];
  xdbl[(size_t)r*XD + c] = s;
  if (c < DTR)      xdbl_b[(size_t)r*64 + c] = f2bf(s);
  else if (c < 64)  xdbl_b[(size_t)r*64 + c] = 0;
}

// ---------------- Causal depthwise conv (k=4) + SiLU ---------------------
__global__ __launch_bounds__(256) void conv_silu_k(
    const unsigned short* __restrict__ xz, const float* __restrict__ cw,
    const float* __restrict__ cb, float* __restrict__ u,
    unsigned short* __restrict__ ub)
{
  size_t idx = (size_t)blockIdx.x*256 + threadIdx.x;
  if (idx >= (size_t)2*BLr*DI) return;
  int di  = (int)(idx % DI);
  size_t r = idx / DI;               // dir*BLr + b*LL + l
  int l   = (int)(r % LL);
  int dir = (int)(r / (BB*LL));
  size_t rowbase = r - l;
  const float* w = cw + ((size_t)dir*DI + di)*4;
  float acc = cb[dir*DI + di];
  #pragma unroll
  for (int k = 0; k < 4; ++k) {
    int lp = l - 3 + k;
    if (lp >= 0) acc = fmaf(w[k], bf2f(xz[(rowbase + lp)*(2*DI) + di]), acc);
  }
  float v = acc * sigmoidf_(acc);
  u[idx]  = v;
  ub[idx] = f2bf(v);
}

// ---------------- chunked selective scan, 4 states (n-quad) per lane ------
__global__ __launch_bounds__(256) void scanA_k(const float* __restrict__ dtv,
    const float* __restrict__ u, const float* __restrict__ xdbl,
    const float* __restrict__ A_log, float* __restrict__ carry,
    float* __restrict__ Pm)
{
  int bx = blockIdx.x;
  int g = bx & (GCH-1);
  int rest = bx / GCH;
  int dchunk = rest % (DI/64);
  int b   = (rest / (DI/64)) % BB;
  int dir = rest / ((DI/64)*BB);
  int tid = threadIdx.x;
  int dl = tid >> 2, q = tid & 3;
  int d = dchunk*64 + dl;
  size_t rb = ((size_t)dir*BB + b) * LL + (size_t)g*LC;
  const float* dtp = dtv + rb*DI + d;
  const float* up  = u   + rb*DI + d;
  const float* xB  = xdbl + rb*XD + DTR + 4*q;
  f32x4 al = *(const f32x4*)(A_log + ((size_t)dir*DI + d)*DS + 4*q);
  float Av[4];
  #pragma unroll
  for (int i = 0; i < 4; ++i) Av[i] = -__expf(al[i]);
  float h[4] = {0.f,0.f,0.f,0.f};
  float S = 0.f;
  float ndt[2], nu[2]; f32x4 nB[2];
  #pragma unroll
  for (int e = 0; e < 2; ++e) {
    ndt[e] = dtp[(size_t)e*DI];
    nu[e]  = up[(size_t)e*DI];
    nB[e]  = *(const f32x4*)(xB + (size_t)e*XD);
  }
  #pragma unroll 2
  for (int j = 0; j < LC; ++j) {
    int s = j & 1;
    float cdt = ndt[s], cu = nu[s];
    f32x4 cB = nB[s];
    int lp = j + 2;
    if (lp < LC) {
      ndt[s] = dtp[(size_t)lp*DI];
      nu[s]  = up[(size_t)lp*DI];
      nB[s]  = *(const f32x4*)(xB + (size_t)lp*XD);
    }
    float du = cdt * cu;
    S += cdt;
    #pragma unroll
    for (int i = 0; i < 4; ++i) {
      float dA = __expf(cdt * Av[i]);
      h[i] = fmaf(dA, h[i], du * cB[i]);
    }
  }
  size_t sid = (((size_t)(dir*BB + b)*DI + d)*DS + 4*q);
  f32x4 hc = {h[0], h[1], h[2], h[3]};
  f32x4 pc = {__expf(Av[0]*S), __expf(Av[1]*S), __expf(Av[2]*S), __expf(Av[3]*S)};
  *(f32x4*)(carry + (size_t)g*NST + sid) = hc;
  *(f32x4*)(Pm    + (size_t)g*NST + sid) = pc;
}

// Phase B: sequential combine over chunks; h_in overwrites carry in place.
__global__ __launch_bounds__(256) void scanB_k(float* __restrict__ carry,
    const float* __restrict__ Pm)
{
  int sid = blockIdx.x*256 + threadIdx.x;   // < NST
  float h = 0.f;
  #pragma unroll
  for (int g = 0; g < GCH; ++g) {
    float c = carry[(size_t)g*NST + sid];
    float p = Pm[(size_t)g*NST + sid];
    carry[(size_t)g*NST + sid] = h;         // h_in
    h = fmaf(p, h, c);
  }
}

// Phase C: re-scan chunk from h_in (in carry), reduce over n, -> y bf16
__global__ __launch_bounds__(256) void scanC_k(const float* __restrict__ dtv,
    const float* __restrict__ u, const unsigned short* __restrict__ xz,
    const float* __restrict__ xdbl, const float* __restrict__ A_log,
    const float* __restrict__ Dp, const float* __restrict__ h_in,
    unsigned short* __restrict__ y)
{
  int bx = blockIdx.x;
  int g = bx & (GCH-1);
  int rest = bx / GCH;
  int dchunk = rest % (DI/64);
  int b   = (rest / (DI/64)) % BB;
  int dir = rest / ((DI/64)*BB);
  int tid = threadIdx.x;
  int dl = tid >> 2, q = tid & 3;
  int d = dchunk*64 + dl;
  size_t rb = ((size_t)dir*BB + b) * LL + (size_t)g*LC;
  const float* dtp = dtv + rb*DI + d;
  const float* up  = u   + rb*DI + d;
  const unsigned short* zp = xz + rb*(2*DI) + DI + d;
  const float* xB  = xdbl + rb*XD + DTR + 4*q;
  const float* xC  = xB + DS;
  unsigned short* yp = y + rb*DI + d;
  f32x4 al = *(const f32x4*)(A_log + ((size_t)dir*DI + d)*DS + 4*q);
  float Av[4];
  #pragma unroll
  for (int i = 0; i < 4; ++i) Av[i] = -__expf(al[i]);
  float Dd = Dp[dir*DI + d];
  size_t sid = (((size_t)(dir*BB + b)*DI + d)*DS + 4*q);
  f32x4 h4 = *(const f32x4*)(h_in + (size_t)g*NST + sid);
  float h[4] = {h4[0], h4[1], h4[2], h4[3]};
  float ndt[2], nu[2], nz[2]; f32x4 nB[2], nC[2];
  #pragma unroll
  for (int e = 0; e < 2; ++e) {
    ndt[e] = dtp[(size_t)e*DI];
    nu[e]  = up[(size_t)e*DI];
    nz[e]  = bf2f(zp[(size_t)e*(2*DI)]);
    nB[e]  = *(const f32x4*)(xB + (size_t)e*XD);
    nC[e]  = *(const f32x4*)(xC + (size_t)e*XD);
  }
  #pragma unroll 2
  for (int j = 0; j < LC; ++j) {
    int s = j & 1;
    float cdt = ndt[s], cu = nu[s], cz = nz[s];
    f32x4 cB = nB[s], cC = nC[s];
    int lp = j + 2;
    if (lp < LC) {
      ndt[s] = dtp[(size_t)lp*DI];
      nu[s]  = up[(size_t)lp*DI];
      nz[s]  = bf2f(zp[(size_t)lp*(2*DI)]);
      nB[s]  = *(const f32x4*)(xB + (size_t)lp*XD);
      nC[s]  = *(const f32x4*)(xC + (size_t)lp*XD);
    }
    float du = cdt * cu;
    float acc = 0.f;
    #pragma unroll
    for (int i = 0; i < 4; ++i) {
      float dA = __expf(cdt * Av[i]);
      h[i] = fmaf(dA, h[i], du * cB[i]);
      acc = fmaf(h[i], cC[i], acc);
    }
    acc += __shfl_xor(acc, 1);
    acc += __shfl_xor(acc, 2);
    if (q == 0) {
      float yv = (acc + cu * Dd) * (cz * sigmoidf_(cz));
      yp[(size_t)j*DI] = f2bf(yv);
    }
  }
}

extern "C" void kernel_launch(void* const* d_in, const int* in_sizes, int n_in,
                              void* d_out, int out_size, void* d_ws, size_t ws_size,
                              hipStream_t stream)
{
  (void)in_sizes; (void)n_in; (void)out_size; (void)ws_size;
  const float* x      = (const float*)d_in[0];
  const float* norm_w = (const float*)d_in[1];
  const float* in_w   = (const float*)d_in[2];
  const float* conv_w = (const float*)d_in[3];
  const float* conv_b = (const float*)d_in[4];
  const float* xp_w   = (const float*)d_in[5];
  const float* dt_w   = (const float*)d_in[6];
  const float* dt_b   = (const float*)d_in[7];
  const float* A_log  = (const float*)d_in[8];
  const float* Dp     = (const float*)d_in[9];
  const float* out_w  = (const float*)d_in[10];
  const float* gate_w = (const float*)d_in[11];
  const float* gate_b = (const float*)d_in[12];
  const float* proj_w = (const float*)d_in[13];
  const float* proj_b = (const float*)d_in[14];
  float* out = (float*)d_out;
  char* wsb  = (char*)d_ws;

  // ---- workspace layout (byte offsets; peak ~118.3 MB) ----
  unsigned short* w_all   = (unsigned short*)(wsb + 0);   // 18,579,456 B
  unsigned short* in_w_b  = w_all;          // dead after in_proj
  unsigned short* out_w_b = w_all + E0;
  unsigned short* gate_w_b= w_all + E1;
  unsigned short* proj_w_b= w_all + E2;
  unsigned short* xp_w_b  = w_all + E3;
  unsigned short* dt_w_b  = w_all + E4;
  unsigned short* xz_b = (unsigned short*)(wsb + 18579456); // 2*BLr*3072 bf16 (19.3MB)
  float* ubuf  = (float*)(wsb + 37847040);    // 2*BLr*1536 fl (19.3MB)
  float* xdbl  = (float*)(wsb + 57114624);    // 2*BLr*80 fl (1.0MB)
  float* dtvb  = (float*)(wsb + 58118144);    // 2*BLr*1536 fl (19.3MB)
  unsigned short* y_b = (unsigned short*)(wsb + 77385728);  // 2*BLr*1536 bf16 (9.6MB)
  unsigned short* tmp = (unsigned short*)(wsb + 87019520);  // 9,633,792 B scratch
  float* fbuf  = (float*)(wsb + 96653312);    // BLr*768 fl (4.8MB)
  float* bbuf  = (float*)(wsb + 101470208);   // BLr*768 fl (4.8MB)
  unsigned short* cat_b = (unsigned short*)(wsb + 106287104); // BLr*1536 bf16 (4.8MB)
  unsigned short* mix_b = (unsigned short*)(wsb + 111104000); // BLr*768 bf16 (2.4MB)

  unsigned short* xn_b   = tmp;   // 2*BLr*768 bf16, live until in_proj
  unsigned short* ub     = tmp;   // 2*BLr*1536 bf16, live conv->x_proj
  unsigned short* xdbl_b = tmp;   // 2*BLr*64 bf16, live xreduce->dt_proj
  float* part  = (float*)(wsb + 0);             // 8.03MB, xproj->xreduce (in_w dead)
  float* carry = (float*)(wsb + 0);             // 6.29MB, scanA->scanC
  float* Pmat  = (float*)(wsb + 87019520 + 524288);  // 6.29MB in tmp tail

  // 1. rmsnorm (both dirs) -> bf16
  rmsnorm_k<<<2*BLr, 256, 0, stream>>>(x, norm_w, xn_b);
  // 2. weight casts
  multicast_k<<<(E5 + 255)/256, 256, 0, stream>>>(
      in_w, out_w, gate_w, proj_w, xp_w, dt_w, w_all);
  // 3. in_proj -> xz bf16 (64x128 tiles, 1200 blocks)
  gemm_in_k<<<dim3(3072/128, (BLr+63)/64, 2), 256, 0, stream>>>(
      xn_b, in_w_b, xz_b);
  // 4. causal dwconv + silu -> u (fp32) + ub (bf16)
  conv_silu_k<<<(int)(((size_t)2*BLr*DI + 255)/256), 256, 0, stream>>>(
      xz_b, conv_w, conv_b, ubuf, ub);
  // 5. x_proj split-K (208 blocks) -> partials
  gemm_xproj<<<dim3(8, (BLr+127)/128, 2), 256, 0, stream>>>(ub, xp_w_b, part);
  // 6. reduce partials -> xdbl fp32 + xdbl_b bf16
  xreduce_k<<<(2*BLr*XD + 255)/256, 256, 0, stream>>>(part, xdbl, xdbl_b);
  // 7. dt_proj + bias + softplus -> dtvb (600 blocks)
  gemm_dt_k<<<dim3(DI/128, (BLr+63)/64, 2), 256, 0, stream>>>(
      xdbl_b, dt_w_b, dt_b, dtvb);
  // 8. chunked scan: A -> B -> C
  scanA_k<<<2*BB*(DI/64)*GCH, 256, 0, stream>>>(
      dtvb, ubuf, xdbl, A_log, carry, Pmat);
  scanB_k<<<NST/256, 256, 0, stream>>>(carry, Pmat);
  scanC_k<<<2*BB*(DI/64)*GCH, 256, 0, stream>>>(
      dtvb, ubuf, xz_b, xdbl, A_log, Dp, carry, y_b);
  // 9. out_proj + residual + flip + cat (600 blocks)
  gemm_outp_k<<<dim3(CM/64, (BLr+63)/64, 2), 256, 0, stream>>>(
      y_b, out_w_b, x, fbuf, bbuf, cat_b);
  // 10. gate GEMM + sigmoid mix -> mix_b (300 blocks)
  gemm_gate_k<<<dim3(CM/64, (BLr+63)/64, 1), 256, 0, stream>>>(
      cat_b, gate_w_b, gate_b, fbuf, bbuf, mix_b);
  // 11. final proj -> d_out (300 blocks)
  gemm_proj_k<<<dim3(CM/64, (BLr+63)/64, 1), 256, 0, stream>>>(
      mix_b, proj_w_b, proj_b, out);
}

// Round 8
// 308.850 us; speedup vs baseline: 7.4751x; 1.2261x over previous
//
#include <hip/hip_runtime.h>
#include <cstdint>
#include <cstddef>

// Problem constants (BiMambaRefinerBlock)
#define BB 2
#define TT 4
#define NN 196
#define LL (TT*NN)        // 784
#define BLr (BB*LL)       // 1568 rows per direction
#define CM 768            // d_model
#define DI 1536           // d_inner
#define DS 16             // d_state
#define DTR 48            // dt_rank
#define XD 80             // dt_rank + 2*d_state
// chunked scan
#define GCH 16
#define LC (LL/GCH)       // 49
#define NST (2*BB*DI*DS)  // 98304 states

typedef short s16x8 __attribute__((ext_vector_type(8)));
typedef float f32x4 __attribute__((ext_vector_type(4)));

static __device__ __forceinline__ float sigmoidf_(float x) {
  return 1.f / (1.f + __expf(-x));
}
// fp32 -> bf16 (RNE)
static __device__ __forceinline__ unsigned short f2bf(float f) {
  unsigned int u = __float_as_uint(f);
  unsigned int r = (u + 0x7fffu + ((u >> 16) & 1u)) >> 16;
  return (unsigned short)r;
}
static __device__ __forceinline__ float bf2f(unsigned short u) {
  return __uint_as_float(((unsigned int)u) << 16);
}
// fast softplus: native exp/log; error ~1e-7 absolute (harmless vs 5.75e-2)
static __device__ __forceinline__ float softplusf_(float v) {
  return (v > 20.f) ? v : __logf(1.f + __expf(v));
}
// async global->LDS, 16 bytes per lane; LDS dest must be uniform + lane*16
static __device__ __forceinline__ void gload_lds16(const void* g, void* l) {
  __builtin_amdgcn_global_load_lds(
      (const __attribute__((address_space(1))) void*)g,
      (__attribute__((address_space(3))) void*)l, 16, 0, 0);
}

// ---------------- RMSNorm -> bf16 (dir1 reads flipped-t source) ----------
__global__ __launch_bounds__(256) void rmsnorm_k(const float* __restrict__ x,
    const float* __restrict__ nw, unsigned short* __restrict__ xn)
{
  int blk = blockIdx.x;               // dir*BLr + b*LL + l
  int l   = blk % LL;
  int b   = (blk / LL) % BB;
  int dir = blk / (BB*LL);
  int lsrc = l;
  if (dir == 1) { int t = l / NN, n = l % NN; lsrc = (TT-1-t)*NN + n; }
  const float* xp = x + ((size_t)b*LL + lsrc)*CM;
  float s = 0.f;
  for (int c = threadIdx.x; c < CM; c += 256) { float v = xp[c]; s += v*v; }
  #pragma unroll
  for (int off = 32; off > 0; off >>= 1) s += __shfl_down(s, off);
  __shared__ float red[4];
  if ((threadIdx.x & 63) == 0) red[threadIdx.x >> 6] = s;
  __syncthreads();
  float tot = red[0] + red[1] + red[2] + red[3];
  float r = rsqrtf(tot * (1.f/CM) + 1e-5f);
  const float* w = nw + dir*CM;
  unsigned short* o = xn + (size_t)blk*CM;
  for (int c = threadIdx.x; c < CM; c += 256) o[c] = f2bf(xp[c] * r * w[c]);
}

// ---------------- weight casts (one dispatch, hardcoded segment map) ------
#define S_INW  4718592        // 2*3072*768
#define S_OUTW 2359296        // 2*768*1536
#define S_GATW 1179648        // 768*1536
#define S_PRJW 589824         // 768*768
#define S_XPW  245760         // 2*80*1536
#define S_DTW  196608         // 2*1536*64 (padded from 48)
#define E0 S_INW
#define E1 (E0 + S_OUTW)      // 7077888
#define E2 (E1 + S_GATW)      // 8257536
#define E3 (E2 + S_PRJW)      // 8847360
#define E4 (E3 + S_XPW)       // 9093120
#define E5 (E4 + S_DTW)       // 9289728
__global__ void multicast_k(const float* __restrict__ in_w,
    const float* __restrict__ out_w, const float* __restrict__ gate_w,
    const float* __restrict__ proj_w, const float* __restrict__ xp_w,
    const float* __restrict__ dt_w, unsigned short* __restrict__ dst)
{
  int i = blockIdx.x*256 + threadIdx.x;
  if (i >= E5) return;
  float v;
  if (i < E0)       v = in_w[i];
  else if (i < E1)  v = out_w[i - E0];
  else if (i < E2)  v = gate_w[i - E1];
  else if (i < E3)  v = proj_w[i - E2];
  else if (i < E4)  v = xp_w[i - E3];
  else {            // dt_w: pad K 48 -> 64
    int j = i - E4, r = j >> 6, c = j & 63;
    v = (c < 48) ? dt_w[r*48 + c] : 0.f;
  }
  dst[i] = f2bf(v);
}

// ---------------- shared MFMA GEMM core: BM x BN tile, BK=64, 4 waves ----
// Staging: per wave-instruction 8 rows x 8 chunks (lane = row3|chunk3);
// each row's 64-k slice = 128 B = one full cache line -> fully coalesced.
// Global chunk XOR-swizzled by row (chs = ch ^ r8); fragment reads use
// chunk p = (s*4+g) ^ (row&7). LDS row stride 64 shorts (128 B).
template <int BM, int BN>
__device__ __forceinline__ void gemm_core(
    const unsigned short* __restrict__ A, int lda,
    const unsigned short* __restrict__ W, int ldw,
    int M, int N, int K, int m0, int n0,
    short* As, short* Ws, f32x4 (*acc)[BN/32])
{
  const int tid = threadIdx.x;
  const int wv = tid >> 6, lane = tid & 63;
  const int wm0 = (wv >> 1)*(BM/2), wn0 = (wv & 1)*(BN/2);
  const int lm = lane & 15, g = lane >> 4;
  const int r8 = lane >> 3, ch = lane & 7;
  const int chs = ch ^ r8;                  // swizzled source chunk
  constexpr int MT = BM/32, NT = BN/32;
  for (int k0 = 0; k0 < K; k0 += 64) {
    #pragma unroll
    for (int e = 0; e < BM/32; ++e) {
      int rb = e*32 + wv*8;                 // wave-uniform 8-row group base
      int gr = m0 + rb + r8; if (gr >= M) gr = M - 1;
      gload_lds16(A + (size_t)gr*lda + k0 + chs*8, &As[rb*64 + lane*8]);
    }
    #pragma unroll
    for (int e = 0; e < BN/32; ++e) {
      int rb = e*32 + wv*8;
      int gn = n0 + rb + r8; if (gn >= N) gn = N - 1;
      gload_lds16(W + (size_t)gn*ldw + k0 + chs*8, &Ws[rb*64 + lane*8]);
    }
    __syncthreads();
    #pragma unroll
    for (int s = 0; s < 2; ++s) {           // two 32-k MFMA steps
      s16x8 af[MT], bf[NT];
      #pragma unroll
      for (int i = 0; i < MT; ++i) {
        int R = wm0 + i*16 + lm;
        af[i] = *(const s16x8*)(&As[R*64 + (((s*4 + g) ^ (R & 7))*8)]);
      }
      #pragma unroll
      for (int j = 0; j < NT; ++j) {
        int Rn = wn0 + j*16 + lm;
        bf[j] = *(const s16x8*)(&Ws[Rn*64 + (((s*4 + g) ^ (Rn & 7))*8)]);
      }
      #pragma unroll
      for (int i = 0; i < MT; ++i)
        #pragma unroll
        for (int j = 0; j < NT; ++j)
          acc[i][j] = __builtin_amdgcn_mfma_f32_16x16x32_bf16(af[i], bf[j], acc[i][j], 0, 0, 0);
    }
    __syncthreads();
  }
}

// ---------------- in_proj: (BLr,768)x(3072,768)^T -> xz bf16 -------------
__global__ __launch_bounds__(256, 4) void gemm_in_k(
    const unsigned short* __restrict__ xn, const unsigned short* __restrict__ w,
    unsigned short* __restrict__ xzout)
{
  __shared__ short As[64*64];
  __shared__ short Ws[128*64];
  const int dir = blockIdx.z;
  const unsigned short* A = xn + (size_t)dir*BLr*CM;
  const unsigned short* W = w  + (size_t)dir*2*DI*CM;
  unsigned short* C = xzout + (size_t)dir*BLr*2*DI;
  const int m0 = blockIdx.y*64, n0 = blockIdx.x*128;
  f32x4 acc[2][4];
  #pragma unroll
  for (int i = 0; i < 2; ++i)
    #pragma unroll
    for (int j = 0; j < 4; ++j) acc[i][j] = (f32x4){0.f,0.f,0.f,0.f};
  gemm_core<64,128>(A, CM, W, CM, BLr, 2*DI, CM, m0, n0, As, Ws, acc);
  const int tid = threadIdx.x, wv = tid >> 6, lane = tid & 63;
  const int wm0 = (wv >> 1)*32, wn0 = (wv & 1)*64;
  const int lm = lane & 15, g = lane >> 4;
  #pragma unroll
  for (int i = 0; i < 2; ++i) {
    int row = m0 + wm0 + i*16 + g*4;
    #pragma unroll
    for (int j = 0; j < 4; ++j) {
      int col = n0 + wn0 + j*16 + lm;
      #pragma unroll
      for (int r = 0; r < 4; ++r)
        if (row + r < BLr) C[(size_t)(row + r)*2*DI + col] = f2bf(acc[i][j][r]);
    }
  }
}

// ---------------- dt_proj: (BLr,64)x(1536,64)^T + bias + fast softplus ----
__global__ __launch_bounds__(256, 4) void gemm_dt_k(
    const unsigned short* __restrict__ xdblb, const unsigned short* __restrict__ w,
    const float* __restrict__ dtb, float* __restrict__ dtv)
{
  __shared__ short As[64*64];
  __shared__ short Ws[128*64];
  const int dir = blockIdx.z;
  const unsigned short* A = xdblb + (size_t)dir*BLr*64;
  const unsigned short* W = w + (size_t)dir*DI*64;
  float* C = dtv + (size_t)dir*BLr*DI;
  const float* bias = dtb + (size_t)dir*DI;
  const int m0 = blockIdx.y*64, n0 = blockIdx.x*128;
  f32x4 acc[2][4];
  #pragma unroll
  for (int i = 0; i < 2; ++i)
    #pragma unroll
    for (int j = 0; j < 4; ++j) acc[i][j] = (f32x4){0.f,0.f,0.f,0.f};
  gemm_core<64,128>(A, 64, W, 64, BLr, DI, 64, m0, n0, As, Ws, acc);
  const int tid = threadIdx.x, wv = tid >> 6, lane = tid & 63;
  const int wm0 = (wv >> 1)*32, wn0 = (wv & 1)*64;
  const int lm = lane & 15, g = lane >> 4;
  #pragma unroll
  for (int i = 0; i < 2; ++i) {
    int row = m0 + wm0 + i*16 + g*4;
    #pragma unroll
    for (int j = 0; j < 4; ++j) {
      int col = n0 + wn0 + j*16 + lm;
      float bv = bias[col];
      #pragma unroll
      for (int r = 0; r < 4; ++r) {
        if (row + r >= BLr) continue;
        C[(size_t)(row + r)*DI + col] = softplusf_(acc[i][j][r] + bv);
      }
    }
  }
}

// ---------------- out_proj + residual + flip + cat -----------------------
__global__ __launch_bounds__(256, 4) void gemm_outp_k(
    const unsigned short* __restrict__ yb, const unsigned short* __restrict__ w,
    const float* __restrict__ x, float* __restrict__ fbuf,
    float* __restrict__ bbuf, unsigned short* __restrict__ cat)
{
  __shared__ short As[64*64];
  __shared__ short Ws[64*64];
  const int dir = blockIdx.z;
  const unsigned short* A = yb + (size_t)dir*BLr*DI;
  const unsigned short* W = w + (size_t)dir*CM*DI;
  const int m0 = blockIdx.y*64, n0 = blockIdx.x*64;
  f32x4 acc[2][2];
  #pragma unroll
  for (int i = 0; i < 2; ++i)
    #pragma unroll
    for (int j = 0; j < 2; ++j) acc[i][j] = (f32x4){0.f,0.f,0.f,0.f};
  gemm_core<64,64>(A, DI, W, DI, BLr, CM, DI, m0, n0, As, Ws, acc);
  const int tid = threadIdx.x, wv = tid >> 6, lane = tid & 63;
  const int wm0 = (wv >> 1)*32, wn0 = (wv & 1)*32;
  const int lm = lane & 15, g = lane >> 4;
  #pragma unroll
  for (int i = 0; i < 2; ++i) {
    int row = m0 + wm0 + i*16 + g*4;
    #pragma unroll
    for (int j = 0; j < 2; ++j) {
      int col = n0 + wn0 + j*16 + lm;
      #pragma unroll
      for (int r = 0; r < 4; ++r) {
        int rr = row + r;
        if (rr >= BLr) continue;
        int rt = rr;
        if (dir == 1) {
          int l = rr % LL, b = rr / LL;
          int t = l / NN, nn = l % NN;
          rt = b*LL + (TT-1-t)*NN + nn;
        }
        float v = x[(size_t)rt*CM + col] + acc[i][j][r];
        if (dir == 0) {
          fbuf[(size_t)rt*CM + col] = v;
          cat[(size_t)rt*(2*CM) + col] = f2bf(v);
        } else {
          bbuf[(size_t)rt*CM + col] = v;
          cat[(size_t)rt*(2*CM) + CM + col] = f2bf(v);
        }
      }
    }
  }
}

// ---------------- gate GEMM + sigmoid mix -> mix_b bf16 ------------------
__global__ __launch_bounds__(256, 4) void gemm_gate_k(
    const unsigned short* __restrict__ cat, const unsigned short* __restrict__ w,
    const float* __restrict__ gb, const float* __restrict__ fbuf,
    const float* __restrict__ bbuf, unsigned short* __restrict__ mixb)
{
  __shared__ short As[64*64];
  __shared__ short Ws[64*64];
  const int m0 = blockIdx.y*64, n0 = blockIdx.x*64;
  f32x4 acc[2][2];
  #pragma unroll
  for (int i = 0; i < 2; ++i)
    #pragma unroll
    for (int j = 0; j < 2; ++j) acc[i][j] = (f32x4){0.f,0.f,0.f,0.f};
  gemm_core<64,64>(cat, 2*CM, w, 2*CM, BLr, CM, 2*CM, m0, n0, As, Ws, acc);
  const int tid = threadIdx.x, wv = tid >> 6, lane = tid & 63;
  const int wm0 = (wv >> 1)*32, wn0 = (wv & 1)*32;
  const int lm = lane & 15, g = lane >> 4;
  #pragma unroll
  for (int i = 0; i < 2; ++i) {
    int row = m0 + wm0 + i*16 + g*4;
    #pragma unroll
    for (int j = 0; j < 2; ++j) {
      int col = n0 + wn0 + j*16 + lm;
      float bv = gb[col];
      #pragma unroll
      for (int r = 0; r < 4; ++r) {
        int rr = row + r;
        if (rr >= BLr) continue;
        float gg = sigmoidf_(acc[i][j][r] + bv);
        float fv = fbuf[(size_t)rr*CM + col];
        float bo = bbuf[(size_t)rr*CM + col];
        mixb[(size_t)rr*CM + col] = f2bf(gg*fv + (1.f - gg)*bo);
      }
    }
  }
}

// ---------------- final proj -> d_out fp32 + bias ------------------------
__global__ __launch_bounds__(256, 4) void gemm_proj_k(
    const unsigned short* __restrict__ mixb, const unsigned short* __restrict__ w,
    const float* __restrict__ pb, float* __restrict__ out)
{
  __shared__ short As[64*64];
  __shared__ short Ws[64*64];
  const int m0 = blockIdx.y*64, n0 = blockIdx.x*64;
  f32x4 acc[2][2];
  #pragma unroll
  for (int i = 0; i < 2; ++i)
    #pragma unroll
    for (int j = 0; j < 2; ++j) acc[i][j] = (f32x4){0.f,0.f,0.f,0.f};
  gemm_core<64,64>(mixb, CM, w, CM, BLr, CM, CM, m0, n0, As, Ws, acc);
  const int tid = threadIdx.x, wv = tid >> 6, lane = tid & 63;
  const int wm0 = (wv >> 1)*32, wn0 = (wv & 1)*32;
  const int lm = lane & 15, g = lane >> 4;
  #pragma unroll
  for (int i = 0; i < 2; ++i) {
    int row = m0 + wm0 + i*16 + g*4;
    #pragma unroll
    for (int j = 0; j < 2; ++j) {
      int col = n0 + wn0 + j*16 + lm;
      float bv = pb[col];
      #pragma unroll
      for (int r = 0; r < 4; ++r)
        if (row + r < BLr) out[(size_t)(row + r)*CM + col] = acc[i][j][r] + bv;
    }
  }
}

// ---------------- x_proj split-K GEMM on the shared core ------------------
__global__ __launch_bounds__(256, 2) void gemm_xproj(
    const unsigned short* __restrict__ ub, const unsigned short* __restrict__ xpw,
    float* __restrict__ part)
{
  __shared__ short As[128*64];
  __shared__ short Ws[128*64];
  const int ks = blockIdx.x, mt = blockIdx.y, dir = blockIdx.z;
  const unsigned short* A = ub + (size_t)dir*BLr*DI + ks*(DI/8);
  const unsigned short* W = xpw + (size_t)dir*XD*DI + ks*(DI/8);
  const int m0 = mt*128;
  f32x4 acc[4][4];
  #pragma unroll
  for (int i = 0; i < 4; ++i)
    #pragma unroll
    for (int j = 0; j < 4; ++j) acc[i][j] = (f32x4){0.f,0.f,0.f,0.f};
  gemm_core<128,128>(A, DI, W, DI, BLr, XD, DI/8, m0, 0, As, Ws, acc);
  const int tid = threadIdx.x, wv = tid >> 6, lane = tid & 63;
  const int wm0 = (wv >> 1)*64, wn0 = (wv & 1)*64;
  const int lm = lane & 15, g = lane >> 4;
  float* P = part + ((size_t)(dir*8 + ks)*BLr)*XD;
  #pragma unroll
  for (int i = 0; i < 4; ++i) {
    int row = m0 + wm0 + i*16 + g*4;
    #pragma unroll
    for (int j = 0; j < 4; ++j) {
      int col = wn0 + j*16 + lm;
      if (col >= XD) continue;
      #pragma unroll
      for (int r = 0; r < 4; ++r)
        if (row + r < BLr) P[(size_t)(row + r)*XD + col] = acc[i][j][r];
    }
  }
}

// ---------------- reduce x_proj partials -> xdbl fp32 + dt cols bf16 ------
__global__ void xreduce_k(const float* __restrict__ part,
    float* __restrict__ xdbl, unsigned short* __restrict__ xdbl_b)
{
  int i = blockIdx.x*256 + threadIdx.x;     // over 2*BLr*80
  if (i >= 2*BLr*XD) return;
  int c = i % XD;
  int r = i / XD;                            // dir*BLr + row
  int dir = r / BLr, row = r % BLr;
  float s = 0.f;
  #pragma unroll
  for (int ks = 0; ks < 8; ++ks)
    s += part[((size_t)(dir*8 + ks)*BLr + row)*XD + c];
  xdbl[(size_t)r*XD + c] = s;
  if (c < DTR)      xdbl_b[(size_t)r*64 + c] = f2bf(s);
  else if (c < 64)  xdbl_b[(size_t)r*64 + c] = 0;
}

// ---------------- Causal depthwise conv (k=4) + SiLU -> bf16 ub only -----
__global__ __launch_bounds__(256) void conv_silu_k(
    const unsigned short* __restrict__ xz, const float* __restrict__ cw,
    const float* __restrict__ cb, unsigned short* __restrict__ ub)
{
  size_t idx = (size_t)blockIdx.x*256 + threadIdx.x;
  if (idx >= (size_t)2*BLr*DI) return;
  int di  = (int)(idx % DI);
  size_t r = idx / DI;               // dir*BLr + b*LL + l
  int l   = (int)(r % LL);
  int dir = (int)(r / (BB*LL));
  size_t rowbase = r - l;
  const float* w = cw + ((size_t)dir*DI + di)*4;
  float acc = cb[dir*DI + di];
  #pragma unroll
  for (int k = 0; k < 4; ++k) {
    int lp = l - 3 + k;
    if (lp >= 0) acc = fmaf(w[k], bf2f(xz[(rowbase + lp)*(2*DI) + di]), acc);
  }
  float v = acc * sigmoidf_(acc);
  ub[idx] = f2bf(v);
}

// ---------------- chunked selective scan, 4 states (n-quad) per lane ------
__global__ __launch_bounds__(256) void scanA_k(const float* __restrict__ dtv,
    const unsigned short* __restrict__ u, const float* __restrict__ xdbl,
    const float* __restrict__ A_log, float* __restrict__ carry,
    float* __restrict__ Pm)
{
  int bx = blockIdx.x;
  int g = bx & (GCH-1);
  int rest = bx / GCH;
  int dchunk = rest % (DI/64);
  int b   = (rest / (DI/64)) % BB;
  int dir = rest / ((DI/64)*BB);
  int tid = threadIdx.x;
  int dl = tid >> 2, q = tid & 3;
  int d = dchunk*64 + dl;
  size_t rb = ((size_t)dir*BB + b) * LL + (size_t)g*LC;
  const float* dtp = dtv + rb*DI + d;
  const unsigned short* up = u + rb*DI + d;
  const float* xB  = xdbl + rb*XD + DTR + 4*q;
  f32x4 al = *(const f32x4*)(A_log + ((size_t)dir*DI + d)*DS + 4*q);
  float Av[4];
  #pragma unroll
  for (int i = 0; i < 4; ++i) Av[i] = -__expf(al[i]);
  float h[4] = {0.f,0.f,0.f,0.f};
  float S = 0.f;
  float ndt[2], nu[2]; f32x4 nB[2];
  #pragma unroll
  for (int e = 0; e < 2; ++e) {
    ndt[e] = dtp[(size_t)e*DI];
    nu[e]  = bf2f(up[(size_t)e*DI]);
    nB[e]  = *(const f32x4*)(xB + (size_t)e*XD);
  }
  #pragma unroll 2
  for (int j = 0; j < LC; ++j) {
    int s = j & 1;
    float cdt = ndt[s], cu = nu[s];
    f32x4 cB = nB[s];
    int lp = j + 2;
    if (lp < LC) {
      ndt[s] = dtp[(size_t)lp*DI];
      nu[s]  = bf2f(up[(size_t)lp*DI]);
      nB[s]  = *(const f32x4*)(xB + (size_t)lp*XD);
    }
    float du = cdt * cu;
    S += cdt;
    #pragma unroll
    for (int i = 0; i < 4; ++i) {
      float dA = __expf(cdt * Av[i]);
      h[i] = fmaf(dA, h[i], du * cB[i]);
    }
  }
  size_t sid = (((size_t)(dir*BB + b)*DI + d)*DS + 4*q);
  f32x4 hc = {h[0], h[1], h[2], h[3]};
  f32x4 pc = {__expf(Av[0]*S), __expf(Av[1]*S), __expf(Av[2]*S), __expf(Av[3]*S)};
  *(f32x4*)(carry + (size_t)g*NST + sid) = hc;
  *(f32x4*)(Pm    + (size_t)g*NST + sid) = pc;
}

// Phase B: sequential combine over chunks; h_in overwrites carry in place.
__global__ __launch_bounds__(256) void scanB_k(float* __restrict__ carry,
    const float* __restrict__ Pm)
{
  int sid = blockIdx.x*256 + threadIdx.x;   // < NST
  float h = 0.f;
  #pragma unroll
  for (int g = 0; g < GCH; ++g) {
    float c = carry[(size_t)g*NST + sid];
    float p = Pm[(size_t)g*NST + sid];
    carry[(size_t)g*NST + sid] = h;         // h_in
    h = fmaf(p, h, c);
  }
}

// Phase C: re-scan chunk from h_in (in carry), reduce over n, -> y bf16
__global__ __launch_bounds__(256) void scanC_k(const float* __restrict__ dtv,
    const unsigned short* __restrict__ u, const unsigned short* __restrict__ xz,
    const float* __restrict__ xdbl, const float* __restrict__ A_log,
    const float* __restrict__ Dp, const float* __restrict__ h_in,
    unsigned short* __restrict__ y)
{
  int bx = blockIdx.x;
  int g = bx & (GCH-1);
  int rest = bx / GCH;
  int dchunk = rest % (DI/64);
  int b   = (rest / (DI/64)) % BB;
  int dir = rest / ((DI/64)*BB);
  int tid = threadIdx.x;
  int dl = tid >> 2, q = tid & 3;
  int d = dchunk*64 + dl;
  size_t rb = ((size_t)dir*BB + b) * LL + (size_t)g*LC;
  const float* dtp = dtv + rb*DI + d;
  const unsigned short* up = u + rb*DI + d;
  const unsigned short* zp = xz + rb*(2*DI) + DI + d;
  const float* xB  = xdbl + rb*XD + DTR + 4*q;
  const float* xC  = xB + DS;
  unsigned short* yp = y + rb*DI + d;
  f32x4 al = *(const f32x4*)(A_log + ((size_t)dir*DI + d)*DS + 4*q);
  float Av[4];
  #pragma unroll
  for (int i = 0; i < 4; ++i) Av[i] = -__expf(al[i]);
  float Dd = Dp[dir*DI + d];
  size_t sid = (((size_t)(dir*BB + b)*DI + d)*DS + 4*q);
  f32x4 h4 = *(const f32x4*)(h_in + (size_t)g*NST + sid);
  float h[4] = {h4[0], h4[1], h4[2], h4[3]};
  float ndt[2], nu[2], nz[2]; f32x4 nB[2], nC[2];
  #pragma unroll
  for (int e = 0; e < 2; ++e) {
    ndt[e] = dtp[(size_t)e*DI];
    nu[e]  = bf2f(up[(size_t)e*DI]);
    nz[e]  = bf2f(zp[(size_t)e*(2*DI)]);
    nB[e]  = *(const f32x4*)(xB + (size_t)e*XD);
    nC[e]  = *(const f32x4*)(xC + (size_t)e*XD);
  }
  #pragma unroll 2
  for (int j = 0; j < LC; ++j) {
    int s = j & 1;
    float cdt = ndt[s], cu = nu[s], cz = nz[s];
    f32x4 cB = nB[s], cC = nC[s];
    int lp = j + 2;
    if (lp < LC) {
      ndt[s] = dtp[(size_t)lp*DI];
      nu[s]  = bf2f(up[(size_t)lp*DI]);
      nz[s]  = bf2f(zp[(size_t)lp*(2*DI)]);
      nB[s]  = *(const f32x4*)(xB + (size_t)lp*XD);
      nC[s]  = *(const f32x4*)(xC + (size_t)lp*XD);
    }
    float du = cdt * cu;
    float acc = 0.f;
    #pragma unroll
    for (int i = 0; i < 4; ++i) {
      float dA = __expf(cdt * Av[i]);
      h[i] = fmaf(dA, h[i], du * cB[i]);
      acc = fmaf(h[i], cC[i], acc);
    }
    acc += __shfl_xor(acc, 1);
    acc += __shfl_xor(acc, 2);
    if (q == 0) {
      float yv = (acc + cu * Dd) * (cz * sigmoidf_(cz));
      yp[(size_t)j*DI] = f2bf(yv);
    }
  }
}

extern "C" void kernel_launch(void* const* d_in, const int* in_sizes, int n_in,
                              void* d_out, int out_size, void* d_ws, size_t ws_size,
                              hipStream_t stream)
{
  (void)in_sizes; (void)n_in; (void)out_size; (void)ws_size;
  const float* x      = (const float*)d_in[0];
  const float* norm_w = (const float*)d_in[1];
  const float* in_w   = (const float*)d_in[2];
  const float* conv_w = (const float*)d_in[3];
  const float* conv_b = (const float*)d_in[4];
  const float* xp_w   = (const float*)d_in[5];
  const float* dt_w   = (const float*)d_in[6];
  const float* dt_b   = (const float*)d_in[7];
  const float* A_log  = (const float*)d_in[8];
  const float* Dp     = (const float*)d_in[9];
  const float* out_w  = (const float*)d_in[10];
  const float* gate_w = (const float*)d_in[11];
  const float* gate_b = (const float*)d_in[12];
  const float* proj_w = (const float*)d_in[13];
  const float* proj_b = (const float*)d_in[14];
  float* out = (float*)d_out;
  char* wsb  = (char*)d_ws;

  // ---- workspace layout (byte offsets) ----
  unsigned short* w_all   = (unsigned short*)(wsb + 0);   // 18,579,456 B
  unsigned short* in_w_b  = w_all;          // dead after in_proj
  unsigned short* out_w_b = w_all + E0;
  unsigned short* gate_w_b= w_all + E1;
  unsigned short* proj_w_b= w_all + E2;
  unsigned short* xp_w_b  = w_all + E3;
  unsigned short* dt_w_b  = w_all + E4;
  unsigned short* xz_b = (unsigned short*)(wsb + 18579456); // 2*BLr*3072 bf16 (19.3MB)
  unsigned short* ub   = (unsigned short*)(wsb + 37847040); // 2*BLr*1536 bf16 (9.6MB), live conv->scanC
  float* xdbl  = (float*)(wsb + 57114624);    // 2*BLr*80 fl (1.0MB)
  float* dtvb  = (float*)(wsb + 58118144);    // 2*BLr*1536 fl (19.3MB)
  unsigned short* y_b = (unsigned short*)(wsb + 77385728);  // 2*BLr*1536 bf16 (9.6MB)
  unsigned short* tmp = (unsigned short*)(wsb + 87019520);  // 9,633,792 B scratch
  float* fbuf  = (float*)(wsb + 96653312);    // BLr*768 fl (4.8MB)
  float* bbuf  = (float*)(wsb + 101470208);   // BLr*768 fl (4.8MB)
  unsigned short* cat_b = (unsigned short*)(wsb + 106287104); // BLr*1536 bf16 (4.8MB)
  unsigned short* mix_b = (unsigned short*)(wsb + 111104000); // BLr*768 bf16 (2.4MB)

  unsigned short* xn_b   = tmp;   // 2*BLr*768 bf16, live until in_proj
  unsigned short* xdbl_b = tmp;   // 2*BLr*64 bf16 (401KB), live xreduce->dt_proj
  float* part  = (float*)(wsb + 0);             // 8.03MB, xproj->xreduce (in_w dead)
  float* carry = (float*)(wsb + 0);             // 6.29MB, scanA->scanC
  float* Pmat  = (float*)(wsb + 87019520 + 524288);  // 6.29MB in tmp tail (after xdbl_b)

  // 1. rmsnorm (both dirs) -> bf16
  rmsnorm_k<<<2*BLr, 256, 0, stream>>>(x, norm_w, xn_b);
  // 2. weight casts
  multicast_k<<<(E5 + 255)/256, 256, 0, stream>>>(
      in_w, out_w, gate_w, proj_w, xp_w, dt_w, w_all);
  // 3. in_proj -> xz bf16 (1200 blocks)
  gemm_in_k<<<dim3(3072/128, (BLr+63)/64, 2), 256, 0, stream>>>(
      xn_b, in_w_b, xz_b);
  // 4. causal dwconv + silu -> ub (bf16 only)
  conv_silu_k<<<(int)(((size_t)2*BLr*DI + 255)/256), 256, 0, stream>>>(
      xz_b, conv_w, conv_b, ub);
  // 5. x_proj split-K (208 blocks) -> partials
  gemm_xproj<<<dim3(8, (BLr+127)/128, 2), 256, 0, stream>>>(ub, xp_w_b, part);
  // 6. reduce partials -> xdbl fp32 + xdbl_b bf16
  xreduce_k<<<(2*BLr*XD + 255)/256, 256, 0, stream>>>(part, xdbl, xdbl_b);
  // 7. dt_proj + bias + fast softplus -> dtvb (600 blocks)
  gemm_dt_k<<<dim3(DI/128, (BLr+63)/64, 2), 256, 0, stream>>>(
      xdbl_b, dt_w_b, dt_b, dtvb);
  // 8. chunked scan: A -> B -> C
  scanA_k<<<2*BB*(DI/64)*GCH, 256, 0, stream>>>(
      dtvb, ub, xdbl, A_log, carry, Pmat);
  scanB_k<<<NST/256, 256, 0, stream>>>(carry, Pmat);
  scanC_k<<<2*BB*(DI/64)*GCH, 256, 0, stream>>>(
      dtvb, ub, xz_b, xdbl, A_log, Dp, carry, y_b);
  // 9. out_proj + residual + flip + cat (600 blocks)
  gemm_outp_k<<<dim3(CM/64, (BLr+63)/64, 2), 256, 0, stream>>>(
      y_b, out_w_b, x, fbuf, bbuf, cat_b);
  // 10. gate GEMM + sigmoid mix -> mix_b (300 blocks)
  gemm_gate_k<<<dim3(CM/64, (BLr+63)/64, 1), 256, 0, stream>>>(
      cat_b, gate_w_b, gate_b, fbuf, bbuf, mix_b);
  // 11. final proj -> d_out (300 blocks)
  gemm_proj_k<<<dim3(CM/64, (BLr+63)/64, 1), 256, 0, stream>>>(
      mix_b, proj_w_b, proj_b, out);
}